// Round 11
// baseline (817.327 us; speedup 1.0000x reference)
//
#include <hip/hip_runtime.h>
#include <cstdint>
#include <cstddef>

#define NPTS 4096
#define BATCH 16

typedef unsigned int uint32;
typedef unsigned long long u64;
typedef unsigned short u16;

typedef __attribute__((ext_vector_type(8))) short short8;
typedef __attribute__((ext_vector_type(16))) float float16;

__device__ __forceinline__ u16 f2bf(float f) {
  uint32 u = __float_as_uint(f);
  u = (u + 0x7fffu + ((u >> 16) & 1u)) >> 16;
  return (u16)u;
}
__device__ __forceinline__ float bf2f(u16 h) {
  return __uint_as_float(((uint32)h) << 16);
}

// ---------------- fp32 1x1-conv GEMM — used ONLY for conv7 (value path).
__global__ __launch_bounds__(256) void conv_gemm(
    const float* __restrict__ act, const float* __restrict__ wt,
    const float* __restrict__ rowbias, const float* __restrict__ obias,
    const float* __restrict__ inScale, const float* __restrict__ inShift,
    float* __restrict__ out, float* __restrict__ partials, int C, int O)
{
  __shared__ float As[16][68];
  __shared__ float Ws[16][68];
  __shared__ float redS[64][17];
  __shared__ float redQ[64][17];
  const int b  = blockIdx.z;
  const int o0 = blockIdx.y * 64;
  const int n0 = blockIdx.x * 64;
  const int t  = threadIdx.x;
  const int tx = t & 15, ty = t >> 4;
  float acc[4][4] = {};
  const float* actb = act + ((size_t)b * C) * NPTS;

  for (int k0 = 0; k0 < C; k0 += 16) {
    const int r  = ty;
    const int cs = tx * 4;
    const int k  = k0 + r;
    float4 av = make_float4(0.f, 0.f, 0.f, 0.f);
    if (k < C) {
      av = *(const float4*)(actb + (size_t)k * NPTS + n0 + cs);
      if (inScale) {
        const float scv = inScale[k], shv = inShift[k];
        av.x = fmaxf(fmaf(av.x, scv, shv), 0.f);
        av.y = fmaxf(fmaf(av.y, scv, shv), 0.f);
        av.z = fmaxf(fmaf(av.z, scv, shv), 0.f);
        av.w = fmaxf(fmaf(av.w, scv, shv), 0.f);
      }
    }
    *(float4*)&As[r][cs] = av;

    float4 wv = make_float4(0.f, 0.f, 0.f, 0.f);
    if (k < C) {
      const float* wp = wt + (size_t)k * O;
      const int o = o0 + cs;
      if (o + 3 < O) {
        wv = *(const float4*)&wp[o];
      } else {
        float tmp[4] = {0.f, 0.f, 0.f, 0.f};
        for (int j = 0; j < 4; ++j) if (o + j < O) tmp[j] = wp[o + j];
        wv = make_float4(tmp[0], tmp[1], tmp[2], tmp[3]);
      }
    }
    *(float4*)&Ws[r][cs] = wv;
    __syncthreads();

    const int kmax = (C - k0 < 16) ? (C - k0) : 16;
    for (int kk = 0; kk < kmax; ++kk) {
      float4 a = *(float4*)&As[kk][tx * 4];
      float4 w = *(float4*)&Ws[kk][ty * 4];
      acc[0][0] += w.x * a.x; acc[0][1] += w.x * a.y; acc[0][2] += w.x * a.z; acc[0][3] += w.x * a.w;
      acc[1][0] += w.y * a.x; acc[1][1] += w.y * a.y; acc[1][2] += w.y * a.z; acc[1][3] += w.y * a.w;
      acc[2][0] += w.z * a.x; acc[2][1] += w.z * a.y; acc[2][2] += w.z * a.z; acc[2][3] += w.z * a.w;
      acc[3][0] += w.w * a.x; acc[3][1] += w.w * a.y; acc[3][2] += w.w * a.z; acc[3][3] += w.w * a.w;
    }
    __syncthreads();
  }

  float s[4], q[4];
  for (int i = 0; i < 4; ++i) {
    const int o = o0 + ty * 4 + i;
    s[i] = 0.f; q[i] = 0.f;
    if (o >= O) continue;
    float base = 0.f;
    if (rowbias) base  = rowbias[(size_t)b * O + o];
    if (obias)   base += obias[o];
    float4 v = make_float4(acc[i][0] + base, acc[i][1] + base, acc[i][2] + base, acc[i][3] + base);
    *(float4*)&out[((size_t)b * O + o) * NPTS + n0 + tx * 4] = v;
    s[i] = v.x + v.y + v.z + v.w;
    q[i] = v.x * v.x + v.y * v.y + v.z * v.z + v.w * v.w;
  }

  if (partials) {
    for (int i = 0; i < 4; ++i) { redS[ty * 4 + i][tx] = s[i]; redQ[ty * 4 + i][tx] = q[i]; }
    __syncthreads();
    if (t < 64) {
      float a = 0.f;
      for (int j = 0; j < 16; ++j) a += redS[t][j];
      partials[((size_t)b * O + o0 + t) * 64 + blockIdx.x] = a;
    } else if (t < 128) {
      float a = 0.f;
      for (int j = 0; j < 16; ++j) a += redQ[t - 64][j];
      partials[(size_t)BATCH * O * 64 + ((size_t)b * O + o0 + t - 64) * 64 + blockIdx.x] = a;
    }
  }
}

// ================= rank-exact chain =================
// conv1,conv2 in f64 (VALU). conv3 in fp32 via split-bf16 MFMA (error ~4e-6).
// topk gets ~top-40 fp32 candidates (DPP wave-max tournament on index-embedded
// u32 keys), then a small f64 RERANK recomputes the 40 candidate values exactly
// from f64 h2 and emits the top-32 by masked-f64 key. True top-32 is inside
// the candidate set with large margin, so the final output is exact.

// ---- conv1 (C=4): writes raw h1 fp32 (for conv4 value path) + f64 BN1 partials
__global__ __launch_bounds__(256) void conv1_f64(const float* __restrict__ x,
                                                 const float* __restrict__ w1,
                                                 float* __restrict__ h1f,
                                                 double* __restrict__ psd) {
  const int c = blockIdx.x, b = blockIdx.y;
  const double wa = (double)w1[c * 4 + 0], wb = (double)w1[c * 4 + 1];
  const double wc = (double)w1[c * 4 + 2], wd = (double)w1[c * 4 + 3];
  const float* xb = x + (size_t)b * 4 * NPTS;
  float* dst = h1f + ((size_t)b * 64 + c) * NPTS;
  double s = 0.0, q = 0.0;
  for (int n = threadIdx.x; n < NPTS; n += 256) {
    double v = wa * (double)xb[n] + wb * (double)xb[NPTS + n]
             + wc * (double)xb[2 * NPTS + n] + wd * (double)xb[3 * NPTS + n];
    dst[n] = (float)v;
    s += v; q += v * v;
  }
  __shared__ double ls[4], lq[4];
  for (int off = 32; off; off >>= 1) { s += __shfl_down(s, off, 64); q += __shfl_down(q, off, 64); }
  const int wid = threadIdx.x >> 6;
  if ((threadIdx.x & 63) == 0) { ls[wid] = s; lq[wid] = q; }
  __syncthreads();
  if (threadIdx.x == 0) {
    s = ls[0] + ls[1] + ls[2] + ls[3];
    q = lq[0] + lq[1] + lq[2] + lq[3];
    psd[(size_t)c * 16 + b] = s;
    psd[(size_t)64 * 16 + (size_t)c * 16 + b] = q;
  }
}

// ---- generic f64 BN finalize: fixed-order chunked reduction (deterministic)
__global__ __launch_bounds__(256) void bn_finalize_f64(const double* __restrict__ psd,
                                                       const float* __restrict__ g,
                                                       const float* __restrict__ be,
                                                       double* __restrict__ scd, double* __restrict__ shd,
                                                       float* __restrict__ scf, float* __restrict__ shf,
                                                       int NT) {
  const int c = blockIdx.x;
  const int t = threadIdx.x;
  const double* p2 = psd + (size_t)gridDim.x * NT;
  const int k = (NT + 255) / 256;
  double s = 0.0, q = 0.0;
  for (int i = t * k; i < (t + 1) * k && i < NT; ++i) {
    s += psd[(size_t)c * NT + i];
    q += p2[(size_t)c * NT + i];
  }
  __shared__ double ss[256], qq[256];
  ss[t] = s; qq[t] = q;
  __syncthreads();
  if (t == 0) {
    double S = 0.0, Q = 0.0;
    for (int i = 0; i < 256; ++i) { S += ss[i]; Q += qq[i]; }
    const double m   = S * (1.0 / 65536.0);
    const double var = Q * (1.0 / 65536.0) - m * m;
    const double sc  = (double)g[c] / sqrt(var + 1e-5);
    const double sh  = (double)be[c] - m * sc;
    if (scd) { scd[c] = sc; shd[c] = sh; }
    scf[c] = (float)sc;
    shf[c] = (float)sh;
  }
}

// ---- pack fp32 weights (O x C) -> f64 transposed (C x O) for coalesced staging
__global__ __launch_bounds__(256) void pack_wtf64(const float* __restrict__ src,
                                                  double* __restrict__ dst,
                                                  int O, int C) {
  int i = blockIdx.x * 256 + threadIdx.x;
  if (i >= O * C) return;
  int c = i / O, o = i - c * O;
  dst[(size_t)c * O + o] = (double)src[(size_t)o * C + c];
}

// ---- conv2 VALU f64: 128o x 64n tile; also emits fp32 copy h2f for conv3 MFMA.
__global__ __launch_bounds__(256) void conv2_f64v(
    const float* __restrict__ x, const float* __restrict__ w1,
    const double* __restrict__ w2t,   // (64c x 128o) f64
    const double* __restrict__ scd1, const double* __restrict__ shd1,
    double* __restrict__ h2d, float* __restrict__ h2f, double* __restrict__ psd)
{
  __shared__ double Bs[64][65];     // h1 tile (c1 x n), bn1+relu
  __shared__ double Ws[16][132];    // w2 chunk (k x o)
  const int nb = blockIdx.x, b = blockIdx.y;
  const int n0 = nb * 64;
  const int t = threadIdx.x;
  const float* xb = x + (size_t)b * 4 * NPTS + n0;
  for (int i = t; i < 64 * 64; i += 256) {
    const int c1 = i >> 6, n = i & 63;
    double v = (double)w1[c1 * 4 + 0] * (double)xb[n]
             + (double)w1[c1 * 4 + 1] * (double)xb[NPTS + n]
             + (double)w1[c1 * 4 + 2] * (double)xb[2 * NPTS + n]
             + (double)w1[c1 * 4 + 3] * (double)xb[3 * NPTS + n];
    v = v * scd1[c1] + shd1[c1];
    Bs[c1][n] = v > 0.0 ? v : 0.0;
  }
  const int tx = t & 15, ty = t >> 4;   // n = n0 + tx + 16j ; o = ty*8 .. +7
  double acc[8][4] = {};
  for (int ch = 0; ch < 4; ++ch) {
    __syncthreads();
    {
      const int r = t >> 4, oo = (t & 15) * 8;
      const double* srcw = w2t + (size_t)(ch * 16 + r) * 128 + oo;
#pragma unroll
      for (int j = 0; j < 8; ++j) Ws[r][oo + j] = srcw[j];
    }
    __syncthreads();
#pragma unroll
    for (int kk = 0; kk < 16; ++kk) {
      double a[8], bv[4];
#pragma unroll
      for (int j = 0; j < 8; ++j) a[j] = Ws[kk][ty * 8 + j];
#pragma unroll
      for (int j = 0; j < 4; ++j) bv[j] = Bs[ch * 16 + kk][tx + 16 * j];
#pragma unroll
      for (int i = 0; i < 8; ++i)
#pragma unroll
        for (int j = 0; j < 4; ++j) acc[i][j] = fma(a[i], bv[j], acc[i][j]);
    }
  }
  const size_t hb = (size_t)b * 128 * NPTS;
#pragma unroll
  for (int i = 0; i < 8; ++i) {
    const int o = ty * 8 + i;
    double s = 0.0, q = 0.0;
#pragma unroll
    for (int j = 0; j < 4; ++j) {
      const double v = acc[i][j];
      h2d[hb + (size_t)o * NPTS + n0 + tx + 16 * j] = v;
      h2f[hb + (size_t)o * NPTS + n0 + tx + 16 * j] = (float)v;
      s += v; q += v * v;
    }
#pragma unroll
    for (int m = 1; m < 16; m <<= 1) { s += __shfl_xor(s, m, 64); q += __shfl_xor(q, m, 64); }
    if (tx == 0) {
      psd[(size_t)o * 1024 + b * 64 + nb] = s;
      psd[(size_t)128 * 1024 + (size_t)o * 1024 + b * 64 + nb] = q;
    }
  }
}

// ---------------- pack weights (O,Ctot) fp32 -> hi/lo bf16 A-frag order
__global__ __launch_bounds__(256) void pack_wmfma(const float* __restrict__ src,
                                                  u16* __restrict__ ph, u16* __restrict__ pl,
                                                  int O, int Ctot, int cOff, int Csub) {
  int i = blockIdx.x * 256 + threadIdx.x;
  if (i >= O * Csub) return;
  const int KS = Csub >> 4;
  int j    = i & 7;
  int lj   = (i >> 3) & 63;
  int mtks = i >> 9;
  int ks   = mtks % KS;
  int mt   = mtks / KS;
  int o = mt * 32 + (lj & 31);
  int c = ks * 16 + (lj >> 5) * 8 + j;
  float v = src[(size_t)o * Ctot + cOff + c];
  u16 h = f2bf(v);
  ph[i] = h;
  pl[i] = f2bf(v - bf2f(h));
}

// ---------------- MFMA 1x1-conv GEMM (conv3/4/5/6): split-bf16, dbuf LDS.
__global__ __launch_bounds__(256) void conv_mfma(
    const float* __restrict__ act, const u16* __restrict__ wh, const u16* __restrict__ wl,
    const float* __restrict__ rowbias,
    const float* __restrict__ inScale, const float* __restrict__ inShift,
    float* __restrict__ out, float* __restrict__ ps, int C, int O)
{
  __shared__ u16 Bh[2][4096];
  __shared__ u16 Bl[2][4096];
  const int b  = blockIdx.z;
  const int o0 = blockIdx.y * 128;
  const int n0 = blockIdx.x * 128;
  const int t  = threadIdx.x;
  const int l  = t & 63, wva = t >> 6;
  const int mt = blockIdx.y * 4 + wva;
  const int KS = C >> 4;
  const int NCH = C >> 5;
  const float* actb = act + ((size_t)b * C) * NPTS;

  float16 acc[4];
#pragma unroll
  for (int ns = 0; ns < 4; ++ns)
#pragma unroll
    for (int r = 0; r < 16; ++r) acc[ns][r] = 0.f;

  const int cq = t >> 5;
  const int nq = t & 31;
  const int nn = n0 + nq * 4;
  const int ksl = cq >> 2, oct = (cq >> 1) & 1, j0 = (cq & 1) * 4;

  float va[4][4];
  float4 scv = make_float4(1.f,1.f,1.f,1.f), shv = make_float4(0.f,0.f,0.f,0.f);

  auto loadChunk = [&](int ch) {
    const int cb = ch * 32 + cq * 4;
#pragma unroll
    for (int i2 = 0; i2 < 4; ++i2) {
      float4 v4 = *(const float4*)(actb + (size_t)(cb + i2) * NPTS + nn);
      va[i2][0] = v4.x; va[i2][1] = v4.y; va[i2][2] = v4.z; va[i2][3] = v4.w;
    }
    if (inScale) {
      scv = *(const float4*)&inScale[cb];
      shv = *(const float4*)&inShift[cb];
    }
  };
  auto applyBN = [&]() {
    if (!inScale) return;
#pragma unroll
    for (int d = 0; d < 4; ++d) {
      va[0][d] = fmaxf(fmaf(va[0][d], scv.x, shv.x), 0.f);
      va[1][d] = fmaxf(fmaf(va[1][d], scv.y, shv.y), 0.f);
      va[2][d] = fmaxf(fmaf(va[2][d], scv.z, shv.z), 0.f);
      va[3][d] = fmaxf(fmaf(va[3][d], scv.w, shv.w), 0.f);
    }
  };
  auto convWrite = [&](int buf) {
#pragma unroll
    for (int d = 0; d < 4; ++d) {
      const int nrel = nq * 4 + d;
      const int ns = nrel >> 5, li = nrel & 31;
      u16 h0 = f2bf(va[0][d]), h1 = f2bf(va[1][d]), h2 = f2bf(va[2][d]), h3 = f2bf(va[3][d]);
      u16 q0 = f2bf(va[0][d] - bf2f(h0));
      u16 q1 = f2bf(va[1][d] - bf2f(h1));
      u16 q2 = f2bf(va[2][d] - bf2f(h2));
      u16 q3 = f2bf(va[3][d] - bf2f(h3));
      const int idx = ((ksl * 4 + ns) * 64 + oct * 32 + li) * 8 + j0;
      *(ushort4*)&Bh[buf][idx] = make_ushort4(h0, h1, h2, h3);
      *(ushort4*)&Bl[buf][idx] = make_ushort4(q0, q1, q2, q3);
    }
  };

  loadChunk(0);
  applyBN();
  convWrite(0);
  __syncthreads();

  for (int ch = 0; ch < NCH; ++ch) {
    const size_t abase = (((size_t)mt * KS + ch * 2) * 64 + (size_t)l) * 8;
    short8 AH0 = *(const short8*)(wh + abase);
    short8 AH1 = *(const short8*)(wh + abase + 512);
    short8 AL0 = *(const short8*)(wl + abase);
    short8 AL1 = *(const short8*)(wl + abase + 512);
    const bool more = (ch + 1 < NCH);
    if (more) loadChunk(ch + 1);

    const u16* bh = Bh[ch & 1];
    const u16* bl = Bl[ch & 1];
#pragma unroll
    for (int ns = 0; ns < 4; ++ns) {
      short8 BH0 = *(const short8*)&bh[((0 * 4 + ns) * 64 + l) * 8];
      short8 BL0 = *(const short8*)&bl[((0 * 4 + ns) * 64 + l) * 8];
      acc[ns] = __builtin_amdgcn_mfma_f32_32x32x16_bf16(AL0, BH0, acc[ns], 0, 0, 0);
      acc[ns] = __builtin_amdgcn_mfma_f32_32x32x16_bf16(AH0, BL0, acc[ns], 0, 0, 0);
      acc[ns] = __builtin_amdgcn_mfma_f32_32x32x16_bf16(AH0, BH0, acc[ns], 0, 0, 0);
      short8 BH1 = *(const short8*)&bh[((4 + ns) * 64 + l) * 8];
      short8 BL1 = *(const short8*)&bl[((4 + ns) * 64 + l) * 8];
      acc[ns] = __builtin_amdgcn_mfma_f32_32x32x16_bf16(AL1, BH1, acc[ns], 0, 0, 0);
      acc[ns] = __builtin_amdgcn_mfma_f32_32x32x16_bf16(AH1, BL1, acc[ns], 0, 0, 0);
      acc[ns] = __builtin_amdgcn_mfma_f32_32x32x16_bf16(AH1, BH1, acc[ns], 0, 0, 0);
    }
    if (more) { applyBN(); convWrite((ch + 1) & 1); }
    __syncthreads();
  }

  const int col = l & 31, half = l >> 5;
  float sv[16], sq[16];
#pragma unroll
  for (int r = 0; r < 16; ++r) {
    const int o = o0 + wva * 32 + (r & 3) + 8 * (r >> 2) + 4 * half;
    const float base = rowbias ? rowbias[(size_t)b * O + o] : 0.f;
    float s = 0.f, q = 0.f;
#pragma unroll
    for (int ns = 0; ns < 4; ++ns) {
      float val = acc[ns][r] + base;
      out[((size_t)b * O + o) * NPTS + n0 + ns * 32 + col] = val;
      s += val; q += val * val;
    }
    sv[r] = s; sq[r] = q;
  }
  if (ps) {
#pragma unroll
    for (int r = 0; r < 16; ++r) {
#pragma unroll
      for (int m = 1; m < 32; m <<= 1) {
        sv[r] += __shfl_xor(sv[r], m, 64);
        sq[r] += __shfl_xor(sq[r], m, 64);
      }
    }
    if (col == 0) {
#pragma unroll
      for (int r = 0; r < 16; ++r) {
        const int o = o0 + wva * 32 + (r & 3) + 8 * (r >> 2) + 4 * half;
        ps[((size_t)b * O + o) * 32 + blockIdx.x] = sv[r];
        ps[(size_t)BATCH * O * 32 + ((size_t)b * O + o) * 32 + blockIdx.x] = sq[r];
      }
    }
  }
}

// ---------------- BN finalize (fp32)
__global__ __launch_bounds__(256) void bn_finalize(const float* __restrict__ ps,
                                                   const float* __restrict__ g, const float* __restrict__ be,
                                                   float* __restrict__ scale, float* __restrict__ shift,
                                                   int O, int NT) {
  const int c = blockIdx.x;
  const int total = BATCH * NT;
  const float* p2 = ps + (size_t)BATCH * O * NT;
  const int t = threadIdx.x;
  float s = 0.f, q = 0.f;
  for (int e = t; e < total; e += 256) {
    const int b = e / NT, nt = e - b * NT;
    const size_t a = ((size_t)b * O + c) * NT + nt;
    s += ps[a];
    q += p2[a];
  }
#pragma unroll
  for (int m = 32; m; m >>= 1) {
    s += __shfl_down(s, m, 64);
    q += __shfl_down(q, m, 64);
  }
  __shared__ float lsS[4], lsQ[4];
  const int wid = t >> 6;
  if ((t & 63) == 0) { lsS[wid] = s; lsQ[wid] = q; }
  __syncthreads();
  if (t == 0) {
    s = lsS[0] + lsS[1] + lsS[2] + lsS[3];
    q = lsQ[0] + lsQ[1] + lsQ[2] + lsQ[3];
    const float inv = 1.f / 65536.f;
    float m   = s * inv;
    float var = q * inv - m * m;
    float sc  = g[c] * rsqrtf(var + 1e-5f);
    scale[c] = sc;
    shift[c] = be[c] - m * sc;
  }
}

// ---------------- DPP wave64 max (no LDS/bpermute): result broadcast via readlane
__device__ __forceinline__ int wave_max_i32(int v) {
  v = max(v, __builtin_amdgcn_update_dpp(v, v, 0x111, 0xf, 0xf, false)); // row_shr:1
  v = max(v, __builtin_amdgcn_update_dpp(v, v, 0x112, 0xf, 0xf, false)); // row_shr:2
  v = max(v, __builtin_amdgcn_update_dpp(v, v, 0x114, 0xf, 0xf, false)); // row_shr:4
  v = max(v, __builtin_amdgcn_update_dpp(v, v, 0x118, 0xf, 0xf, false)); // row_shr:8
  v = max(v, __builtin_amdgcn_update_dpp(v, v, 0x142, 0xa, 0xf, false)); // row_bcast:15
  v = max(v, __builtin_amdgcn_update_dpp(v, v, 0x143, 0xc, 0xf, false)); // row_bcast:31
  return __builtin_amdgcn_readlane(v, 63);
}

// ---------------- ~top-40 fp32 candidates per (b,c): per-lane bitonic-sorted
// queue of index-embedded keys + DPP wave-max tournament (zero DS ops in loop).
#define NCAND 40
__global__ __launch_bounds__(256) void topk40_f32(const float* __restrict__ h3,
                                                  int* __restrict__ cand) {
  __shared__ u64 wl[4][NCAND];
  const int c = blockIdx.x, b = blockIdx.y;
  const float* src = h3 + ((size_t)b * 256 + c) * NPTS;
  const int t = threadIdx.x;
  const int l = t & 63, w = t >> 6;
  const int base = w * 1024;

  // load + pack keys (flipped for signed compare: sign-xor makes i32 order == u32 order)
  int k[16];
#pragma unroll
  for (int s = 0; s < 16; ++s) {
    const int loc = s * 64 + l;
    uint32 u = __float_as_uint(src[base + loc]);
    uint32 m32 = ((int)u < 0) ? ~u : (u | 0x80000000u);
    uint32 packed = (m32 & ~0x3FFu) | (uint32)(1023 - loc);
    k[s] = (int)(packed ^ 0x80000000u);
  }

  // bitonic sort ascending: k[15] = lane max
#pragma unroll
  for (int kk = 2; kk <= 16; kk <<= 1) {
#pragma unroll
    for (int j = kk >> 1; j > 0; j >>= 1) {
#pragma unroll
      for (int i = 0; i < 16; ++i) {
        const int ij = i ^ j;
        if (ij > i) {
          const bool up = ((i & kk) == 0);
          const int a = k[i], bb = k[ij];
          const bool sw = up ? (a > bb) : (a < bb);
          k[i]  = sw ? bb : a;
          k[ij] = sw ? a : bb;
        }
      }
    }
  }

  // 40 rounds: DPP wave-max of k[15]; unique winner shifts its queue
  for (int r = 0; r < NCAND; ++r) {
    const int m = wave_max_i32(k[15]);
    if (k[15] == m) {
      const uint32 m32 = (uint32)m ^ 0x80000000u;
      const int loc = 1023 - (int)(m32 & 0x3FFu);
      const int ri = base + loc;
      wl[w][r] = ((u64)m32 << 32) | (u64)(4095 - ri);
#pragma unroll
      for (int s = 15; s > 0; --s) k[s] = k[s - 1];
      k[0] = (int)0x80000000;  // -inf sentinel
    }
  }
  __syncthreads();

  // lanes 0-3 of wave 0: 4-way merge of the sorted per-wave u64 lists
  if (t < 4) {
    int* dst = cand + ((size_t)b * 256 + c) * NCAND;
    int cp = 0;
    u64 cv = wl[t][0];
    for (int r = 0; r < NCAND; ++r) {
      u64 mv = cv;
      u64 ov;
      ov = __shfl_xor((unsigned long long)mv, 1, 64); if (ov > mv) mv = ov;
      ov = __shfl_xor((unsigned long long)mv, 2, 64); if (ov > mv) mv = ov;
      if (t == 0) dst[r] = 4095 - (int)(mv & 0xFFFu);
      if (mv == cv) {
        ++cp;
        cv = (cp < NCAND) ? wl[t][cp] : 0;
      }
    }
  }
}

// ---------------- transpose h2d (b,c2,n) -> h2T (b,n,c2) f64 (for rerank gathers)
__global__ __launch_bounds__(256) void transpose_h2(const double* __restrict__ h2d,
                                                    double* __restrict__ h2T) {
  __shared__ double tile[32][33];
  const int b = blockIdx.z;
  const int n0 = blockIdx.x * 32, c0 = blockIdx.y * 32;
  const int tx = threadIdx.x & 31, ty = threadIdx.x >> 5;
  const double* src = h2d + (size_t)b * 128 * NPTS;
  for (int j = 0; j < 4; ++j)
    tile[ty + j * 8][tx] = src[(size_t)(c0 + ty + j * 8) * NPTS + n0 + tx];
  __syncthreads();
  double* dst = h2T + (size_t)b * NPTS * 128;
  for (int j = 0; j < 4; ++j)
    dst[(size_t)(n0 + ty + j * 8) * 128 + c0 + tx] = tile[tx][ty + j * 8];
}

// ---------------- f64 rerank: exact h3 values for the 40 candidates, emit
// top-32 by masked-f64 key (same semantics as the full-f64 build).
__global__ __launch_bounds__(64) void rerank_f64(const double* __restrict__ h2T,
                                                 const float* __restrict__ w3,
                                                 const double* __restrict__ scd2,
                                                 const double* __restrict__ shd2,
                                                 const int* __restrict__ cand,
                                                 int* __restrict__ idxp) {
  __shared__ u64 keys[NCAND];
  const int o = blockIdx.x, b = blockIdx.y;
  const int l = threadIdx.x;
  const double wA = (double)w3[(size_t)o * 128 + l];
  const double wB = (double)w3[(size_t)o * 128 + l + 64];
  const double sA = scd2[l],      hA = shd2[l];
  const double sB = scd2[l + 64], hB = shd2[l + 64];
  const int* cd = cand + ((size_t)b * 256 + o) * NCAND;
  const double* hb = h2T + (size_t)b * NPTS * 128;
  for (int kk = 0; kk < NCAND; ++kk) {
    const int n = cd[kk];
    const double* col = hb + (size_t)n * 128;
    double va = col[l] * sA + hA;       va = va > 0.0 ? va : 0.0;
    double vb = col[l + 64] * sB + hB;  vb = vb > 0.0 ? vb : 0.0;
    double p = wA * va + wB * vb;
#pragma unroll
    for (int off = 32; off; off >>= 1) p += __shfl_down(p, off, 64);
    if (l == 0) {
      u64 u = (u64)__double_as_longlong(p);
      u64 m = ((long long)u < 0) ? ~u : (u | 0x8000000000000000ULL);
      m = (m & ~0xFFFULL) | (u64)(4095 - n);
      keys[kk] = m;
    }
  }
  __syncthreads();
  u64 kv = (l < NCAND) ? keys[l] : 0;
  int* dst = idxp + ((size_t)b * 256 + o) * 32;
  for (int r = 0; r < 32; ++r) {
    u64 m = kv;
#pragma unroll
    for (int off = 1; off < 64; off <<= 1) {
      u64 o2 = __shfl_xor((unsigned long long)m, off, 64);
      if (o2 > m) m = o2;
    }
    if (l == 0) dst[r] = 4095 - (int)(m & 0xFFFULL);
    if (m == kv) kv = 0;   // keys unique -> winner invalidates itself
  }
}

// ---------------- transpose h3f (B,C,N fp32) -> h3T (B,N,C fp32), applying BN3
__global__ __launch_bounds__(256) void transpose_h3f(const float* __restrict__ h3,
                                                     float* __restrict__ h3T,
                                                     const float* __restrict__ sc,
                                                     const float* __restrict__ sh) {
  __shared__ float tile[32][33];
  const int b = blockIdx.z;
  const int n0 = blockIdx.x * 32, c0 = blockIdx.y * 32;
  const int tx = threadIdx.x & 31, ty = threadIdx.x >> 5;
  const float* src = h3 + (size_t)b * 256 * NPTS;
  for (int j = 0; j < 4; ++j)
    tile[ty + j * 8][tx] = src[(size_t)(c0 + ty + j * 8) * NPTS + n0 + tx];
  __syncthreads();
  float* dst = h3T + (size_t)b * NPTS * 256;
  const float scv = sc[c0 + tx], shv = sh[c0 + tx];
  for (int j = 0; j < 4; ++j)
    dst[(size_t)(n0 + ty + j * 8) * 256 + c0 + tx] = fmaf(tile[tx][ty + j * 8], scv, shv);
}

// ---------------- fused: w8 (o,c,w) -> hi/lo bf16 directly in MFMA A-frag order
__global__ __launch_bounds__(256) void transpack_w8(const float* __restrict__ w8,
                                                    u16* __restrict__ w8h, u16* __restrict__ w8l) {
  __shared__ float tile[64][65];
  const int m0 = blockIdx.x * 64, w0 = blockIdx.y * 64;
  const int tx = threadIdx.x & 63, ty = threadIdx.x >> 6;
#pragma unroll
  for (int j = 0; j < 16; ++j)
    tile[ty + j * 4][tx] = w8[(size_t)(m0 + ty + j * 4) * 256 + w0 + tx];
  __syncthreads();
  const int m = m0 + tx;
  const int o = m >> 8, c = m & 255;
  const int mt = (o >> 5) & 7;
  const int lane = (o & 31) + ((c >> 3) & 1) * 32;
  const int ks = (c >> 4) & 15;
  const int jj = c & 7;
#pragma unroll
  for (int j = 0; j < 16; ++j) {
    const int w = w0 + ty + j * 4;
    float v = tile[tx][ty + j * 4];
    size_t f = ((((size_t)w * 8 + mt) * 16 + ks) * 64 + lane) * 8 + jj;
    u16 h = f2bf(v);
    w8h[f] = h;
    w8l[f] = f2bf(v - bf2f(h));
  }
}

// ---------------- conv8 via MFMA: 64 w-groups of 4 (2 blocks/CU), ks-XOR G swizzle
#define Y8N (BATCH * 256 * 32)
#define NWG 64
#define WPG 4
__global__ __launch_bounds__(256, 1) void conv8_mfma(
    const float* __restrict__ h3T, const u16* __restrict__ w8h,
    const u16* __restrict__ w8l, const int* __restrict__ idxp,
    float* __restrict__ y8p)
{
  __shared__ u16 G[2][8192];
  const int wg = blockIdx.x;
  const int oq = blockIdx.y;
  const int bg = blockIdx.z;
  const int t  = threadIdx.x;
  const int l  = t & 63, wv = t >> 6;
  const int mt = oq * 4 + wv;

  float16 accH[4], accL[4];
  for (int i = 0; i < 4; ++i)
    for (int r = 0; r < 16; ++r) { accH[i][r] = 0.f; accL[i][r] = 0.f; }

  short8 ah[16], al[16];
  const int hrow  = t >> 3;
  const int cbase = (t & 7) * 32;
  float4 g4[8];

  auto issueG = [&](int step) {
    int wi = step >> 2, bi = step & 3;
    int w = wg * WPG + wi;
    int b = bg * 4 + bi;
    int n = idxp[((size_t)b * 256 + w) * 32 + hrow];
    const float* src = h3T + ((size_t)b * NPTS + n) * 256 + cbase;
#pragma unroll
    for (int j = 0; j < 8; ++j) g4[j] = *(const float4*)&src[j * 4];
  };
  auto writeG = [&](int buf) {
#pragma unroll
    for (int a = 0; a < 4; ++a) {
      int c8 = (cbase >> 3) + a;
      int ks = c8 >> 1;
      int lp = (hrow + (c8 & 1) * 32) ^ (ks & 7);   // ks-XOR bank swizzle
      float4 v0 = g4[a * 2], v1 = g4[a * 2 + 1];
      uint32 u0 = (uint32)f2bf(v0.x) | ((uint32)f2bf(v0.y) << 16);
      uint32 u1 = (uint32)f2bf(v0.z) | ((uint32)f2bf(v0.w) << 16);
      uint32 u2 = (uint32)f2bf(v1.x) | ((uint32)f2bf(v1.y) << 16);
      uint32 u3 = (uint32)f2bf(v1.z) | ((uint32)f2bf(v1.w) << 16);
      *(uint4*)&G[buf][((size_t)ks * 64 + lp) * 8] = make_uint4(u0, u1, u2, u3);
    }
  };

  issueG(0); writeG(0);
  __syncthreads();

  for (int wi = 0; wi < WPG; ++wi) {
    const int w = wg * WPG + wi;
    {
      const size_t base = (((size_t)w * 8 + mt) * 16) * 512 + (size_t)l * 8;
#pragma unroll
      for (int ks = 0; ks < 16; ++ks) {
        ah[ks] = *(const short8*)(w8h + base + ks * 512);
        al[ks] = *(const short8*)(w8l + base + ks * 512);
      }
    }
#pragma unroll
    for (int bi = 0; bi < 4; ++bi) {
      const int step = wi * 4 + bi;
      const int cur = bi & 1;
      if (step < WPG * 4 - 1) issueG(step + 1);
      const u16* Gc = G[cur];
#pragma unroll
      for (int ks = 0; ks < 16; ++ks) {
        short8 bf = *(const short8*)&Gc[((size_t)ks * 64 + (l ^ (ks & 7))) * 8];
        accH[bi] = __builtin_amdgcn_mfma_f32_32x32x16_bf16(ah[ks], bf, accH[bi], 0, 0, 0);
        accL[bi] = __builtin_amdgcn_mfma_f32_32x32x16_bf16(al[ks], bf, accL[bi], 0, 0, 0);
      }
      if (step < WPG * 4 - 1) writeG(1 - cur);
      __syncthreads();
    }
  }

  const int h = l & 31;
  const int rbase = oq * 128 + wv * 32 + 4 * (l >> 5);
#pragma unroll
  for (int bi = 0; bi < 4; ++bi) {
    int b = bg * 4 + bi;
    float* dst = y8p + ((size_t)(wg * BATCH + b) * 256) * 32;
#pragma unroll
    for (int r = 0; r < 16; ++r) {
      int o = rbase + (r & 3) + 8 * (r >> 2);
      dst[(size_t)o * 32 + h] = accH[bi][r] + accL[bi][r];
    }
  }
}

// ---------------- y8 = b8 + fixed-order sum of NWG w-group partials
__global__ __launch_bounds__(256) void y8_reduce(const float* __restrict__ y8p,
                                                 const float* __restrict__ b8,
                                                 float* __restrict__ y8) {
  int i = blockIdx.x * 256 + threadIdx.x;
  float s = b8[(i >> 5) & 255];
#pragma unroll
  for (int p = 0; p < NWG; ++p) s += y8p[(size_t)p * Y8N + i];
  y8[i] = s;
}

// ---------------- conv9
__global__ __launch_bounds__(256) void conv9_kernel(const float* __restrict__ y8,
                                                    const float* __restrict__ w9,
                                                    const float* __restrict__ b9,
                                                    float* __restrict__ y9) {
  const int o = blockIdx.x, b = blockIdx.y;
  const float* yb = y8 + (size_t)b * 8192;
  const float* wo = w9 + (size_t)o * 8192;
  float s = 0.f;
  for (int i = threadIdx.x * 4; i < 8192; i += 1024) {
    float4 v = *(const float4*)&yb[i];
    float4 u = *(const float4*)&wo[i];
    s += v.x * u.x + v.y * u.y + v.z * u.z + v.w * u.w;
  }
  for (int off = 32; off; off >>= 1) s += __shfl_down(s, off, 64);
  __shared__ float ls[4];
  const int wid = threadIdx.x >> 6;
  if ((threadIdx.x & 63) == 0) ls[wid] = s;
  __syncthreads();
  if (threadIdx.x == 0) y9[(size_t)b * 256 + o] = ls[0] + ls[1] + ls[2] + ls[3] + b9[o];
}

// ---------------- cvec[b,o] = sum_c w4[o,c] * y9[b,c]
__global__ __launch_bounds__(256) void cvec_kernel(const float* __restrict__ y9,
                                                   const float* __restrict__ w4,
                                                   float* __restrict__ cvec) {
  int tid = blockIdx.x * 256 + threadIdx.x;
  if (tid >= BATCH * 512) return;
  const int b = tid >> 9, o = tid & 511;
  const float* row = w4 + (size_t)o * 320;
  const float* yb  = y9 + (size_t)b * 256;
  float s = 0.f;
  for (int c = 0; c < 256; c += 4) {
    float4 u = *(const float4*)&row[c];
    s += u.x * yb[c] + u.y * yb[c + 1] + u.z * yb[c + 2] + u.w * yb[c + 3];
  }
  cvec[(size_t)b * 512 + o] = s;
}

// ---------------- small weight transpose (fp32 conv7 path)
__global__ __launch_bounds__(256) void transpose_w(const float* __restrict__ src,
                                                   float* __restrict__ dst,
                                                   int O, int Ctot, int cOff, int Csub) {
  int i = blockIdx.x * 256 + threadIdx.x;
  if (i >= O * Csub) return;
  int c = i / O, o = i - c * O;
  dst[(size_t)c * O + o] = src[(size_t)o * Ctot + cOff + c];
}

// ---------------- final tanh
__global__ __launch_bounds__(256) void tanh_out(const float* __restrict__ raw,
                                                float* __restrict__ out) {
  int i = blockIdx.x * 256 + threadIdx.x;
  if (i < BATCH * 3 * NPTS) out[i] = tanhf(raw[i]);
}

extern "C" void kernel_launch(void* const* d_in, const int* in_sizes, int n_in,
                              void* d_out, int out_size, void* d_ws, size_t ws_size,
                              hipStream_t stream) {
  (void)in_sizes; (void)n_in; (void)ws_size; (void)out_size;
  const float* x   = (const float*)d_in[0];
  const float* w1  = (const float*)d_in[1];
  const float* g1  = (const float*)d_in[3];
  const float* be1 = (const float*)d_in[4];
  const float* w2  = (const float*)d_in[5];
  const float* g2  = (const float*)d_in[7];
  const float* be2 = (const float*)d_in[8];
  const float* w3  = (const float*)d_in[9];
  const float* g3  = (const float*)d_in[11];
  const float* be3 = (const float*)d_in[12];
  const float* w4  = (const float*)d_in[13];
  const float* g4  = (const float*)d_in[15];
  const float* be4 = (const float*)d_in[16];
  const float* w5  = (const float*)d_in[17];
  const float* g5  = (const float*)d_in[19];
  const float* be5 = (const float*)d_in[20];
  const float* w6  = (const float*)d_in[21];
  const float* g6  = (const float*)d_in[23];
  const float* be6 = (const float*)d_in[24];
  const float* w7  = (const float*)d_in[25];
  const float* b7  = (const float*)d_in[26];
  const float* w8  = (const float*)d_in[27];
  const float* b8  = (const float*)d_in[28];
  const float* w9  = (const float*)d_in[29];
  const float* b9  = (const float*)d_in[30];

  char* ws = (char*)d_ws;
  size_t off = 0;
  auto alloc = [&](size_t bytes) -> void* {
    void* p = ws + off;
    off += (bytes + 255) & ~(size_t)255;
    return p;
  };
  float* Q1  = (float*)alloc((size_t)BATCH * 64  * NPTS * 4);  // h1f (conv1->conv4), then raw7
  float* Q2  = (float*)alloc((size_t)BATCH * 128 * NPTS * 4);  // y8p (64 partials) -> h4 head -> h6
  float* Q3  = (float*)alloc((size_t)BATCH * 256 * NPTS * 4);  // h2d (f64 64MB) -> h3T -> h4 mid
  float* Q4  = (float*)alloc((size_t)BATCH * 256 * NPTS * 4);  // h3f (fp32) -> w8h/w8l -> h4 tail
  float* Q5  = (float*)alloc((size_t)BATCH * 256 * NPTS * 4);  // h2f (fp32) -> h2T (f64) -> h5
  int*   idx  = (int*)alloc((size_t)BATCH * 256 * 32 * 4);
  int*   cand = (int*)alloc((size_t)BATCH * 256 * NCAND * 4);
  float* y8   = (float*)alloc((size_t)Y8N * 4);
  float* y9   = (float*)alloc((size_t)BATCH * 256 * 4);
  float* cvec = (float*)alloc((size_t)BATCH * 512 * 4);
  float* ps   = (float*)alloc((size_t)2 * BATCH * 512 * 32 * 4);   // fp32 BN partials (NT=32)
  double* psd = (double*)alloc((size_t)2 * 256 * 1024 * 8);        // f64 BN partials
  float* scb  = (float*)alloc((size_t)6 * 1024 * 4);
  double* scdb = (double*)alloc((size_t)1024 * 8);                 // f64 BN consts
  float* w7t  = (float*)alloc(128 * 3 * 4);
  u16* ph3 = (u16*)alloc(256 * 128 * 2);  u16* pl3 = (u16*)alloc(256 * 128 * 2);
  u16* ph4 = (u16*)alloc(512 * 64  * 2);  u16* pl4 = (u16*)alloc(512 * 64  * 2);
  u16* ph5 = (u16*)alloc(256 * 512 * 2);  u16* pl5 = (u16*)alloc(256 * 512 * 2);
  u16* ph6 = (u16*)alloc(128 * 256 * 2);  u16* pl6 = (u16*)alloc(128 * 256 * 2);
  double* w2t = (double*)alloc((size_t)64 * 128 * 8);   // (c x o) f64

  double* h2d = (double*)Q3;                  // f64, alive until transpose_h2
  float*  h2f = (float*)Q5;                   // fp32 copy, dies after conv3 MFMA
  double* h2T = (double*)Q5;                  // f64 (b,n,c), overwrites dead h2f
  float*  h3f = Q4;                           // fp32 raw h3, dies after transpose_h3f
  u16*   w8h = (u16*)Q4;                      // after h3f dies
  u16*   w8l = (u16*)Q4 + (size_t)16777216;
  float* y8p = Q2;                            // 64 partials = exactly Q2; dead before h4
  float* h4  = Q2;                            // 134 MB spans Q2 + Q3 + Q4 head
  float* h5  = Q5;                            // after h2T dies (rerank done)
  float* h6  = Q2;

  float* sc[6]; float* sh[6];
  for (int i = 0; i < 6; ++i) { sc[i] = scb + i * 1024; sh[i] = scb + i * 1024 + 512; }
  double* scd1 = scdb;        double* shd1 = scdb + 64;
  double* scd2 = scdb + 128;  double* shd2 = scdb + 256;

  // ---- weight preprocessing
  transpose_w<<<(128 * 3 + 255) / 256, 256, 0, stream>>>(w7, w7t, 3, 128, 0, 128);
  pack_wmfma<<<(256 * 128 + 255) / 256, 256, 0, stream>>>(w3, ph3, pl3, 256, 128, 0,   128);
  pack_wmfma<<<(512 * 64  + 255) / 256, 256, 0, stream>>>(w4, ph4, pl4, 512, 320, 256, 64);
  pack_wmfma<<<(256 * 512 + 255) / 256, 256, 0, stream>>>(w5, ph5, pl5, 256, 512, 0,   512);
  pack_wmfma<<<(128 * 256 + 255) / 256, 256, 0, stream>>>(w6, ph6, pl6, 128, 256, 0,   256);
  pack_wtf64<<<(128 * 64 + 255) / 256,  256, 0, stream>>>(w2, w2t, 128, 64);

  // ---- rank chain: conv1,conv2 f64; conv3 fp32 MFMA
  conv1_f64<<<dim3(64, BATCH), 256, 0, stream>>>(x, w1, Q1, psd);
  bn_finalize_f64<<<64, 256, 0, stream>>>(psd, g1, be1, scd1, shd1, sc[0], sh[0], 16);
  conv2_f64v<<<dim3(64, BATCH), 256, 0, stream>>>(x, w1, w2t, scd1, shd1, h2d, h2f, psd);
  bn_finalize_f64<<<128, 256, 0, stream>>>(psd, g2, be2, scd2, shd2, sc[1], sh[1], 1024);
  conv_mfma<<<dim3(32, 2, BATCH), 256, 0, stream>>>(h2f, ph3, pl3, nullptr, sc[1], sh[1], h3f, ps, 128, 256);
  bn_finalize<<<256, 256, 0, stream>>>(ps, g3, be3, sc[2], sh[2], 256, 32);

  // ---- softpool: fp32 top-40 candidates -> f64 rerank -> exact top-32
  topk40_f32<<<dim3(256, BATCH), 256, 0, stream>>>(h3f, cand);
  transpose_h2<<<dim3(NPTS / 32, 4, BATCH), 256, 0, stream>>>(h2d, h2T);
  rerank_f64<<<dim3(256, BATCH), 64, 0, stream>>>(h2T, w3, scd2, shd2, cand, idx);
  transpose_h3f<<<dim3(NPTS / 32, 8, BATCH), 256, 0, stream>>>(h3f, Q3, sc[2], sh[2]);

  // ---- w8 pack AFTER h3f is dead (reuses Q4)
  transpack_w8<<<dim3(1024, 4), 256, 0, stream>>>(w8, w8h, w8l);

  // ---- conv8 -> conv9 -> cvec
  conv8_mfma<<<dim3(NWG, 2, 4), 256, 0, stream>>>(Q3, w8h, w8l, idx, y8p);
  y8_reduce<<<Y8N / 256, 256, 0, stream>>>(y8p, b8, y8);
  conv9_kernel<<<dim3(256, BATCH), 256, 0, stream>>>(y8, w9, b9, y9);
  cvec_kernel<<<(BATCH * 512 + 255) / 256, 256, 0, stream>>>(y9, w4, cvec);

  // ---- conv4 (MFMA dbuf, rowbias=cvec, input h1 raw + BN1+relu)
  conv_mfma<<<dim3(32, 4, BATCH), 256, 0, stream>>>(Q1, ph4, pl4, cvec, sc[0], sh[0], h4, ps, 64, 512);
  bn_finalize<<<512, 256, 0, stream>>>(ps, g4, be4, sc[3], sh[3], 512, 32);
  // ---- conv5 (MFMA dbuf)
  conv_mfma<<<dim3(32, 2, BATCH), 256, 0, stream>>>(h4, ph5, pl5, nullptr, sc[3], sh[3], h5, ps, 512, 256);
  bn_finalize<<<256, 256, 0, stream>>>(ps, g5, be5, sc[4], sh[4], 256, 32);
  // ---- conv6 (MFMA dbuf)
  conv_mfma<<<dim3(32, 1, BATCH), 256, 0, stream>>>(h5, ph6, pl6, nullptr, sc[4], sh[4], h6, ps, 256, 128);
  bn_finalize<<<128, 256, 0, stream>>>(ps, g6, be6, sc[5], sh[5], 128, 32);
  // ---- conv7 (fp32, +b7, fused BN6+relu) -> tanh
  conv_gemm<<<dim3(64, 1, BATCH), 256, 0, stream>>>(h6, w7t, nullptr, b7, sc[5], sh[5], Q1, nullptr, 128, 3);
  tanh_out<<<(BATCH * 3 * NPTS) / 256, 256, 0, stream>>>(Q1, (float*)d_out);
}

// Round 12
// 793.286 us; speedup vs baseline: 1.0303x; 1.0303x over previous
//
#include <hip/hip_runtime.h>
#include <cstdint>
#include <cstddef>

#define NPTS 4096
#define BATCH 16

typedef unsigned int uint32;
typedef unsigned long long u64;
typedef unsigned short u16;

typedef __attribute__((ext_vector_type(8))) short short8;
typedef __attribute__((ext_vector_type(16))) float float16;

__device__ __forceinline__ u16 f2bf(float f) {
  uint32 u = __float_as_uint(f);
  u = (u + 0x7fffu + ((u >> 16) & 1u)) >> 16;
  return (u16)u;
}
__device__ __forceinline__ float bf2f(u16 h) {
  return __uint_as_float(((uint32)h) << 16);
}

// ---------------- fp32 1x1-conv GEMM — used ONLY for conv7 (value path).
__global__ __launch_bounds__(256) void conv_gemm(
    const float* __restrict__ act, const float* __restrict__ wt,
    const float* __restrict__ rowbias, const float* __restrict__ obias,
    const float* __restrict__ inScale, const float* __restrict__ inShift,
    float* __restrict__ out, float* __restrict__ partials, int C, int O)
{
  __shared__ float As[16][68];
  __shared__ float Ws[16][68];
  __shared__ float redS[64][17];
  __shared__ float redQ[64][17];
  const int b  = blockIdx.z;
  const int o0 = blockIdx.y * 64;
  const int n0 = blockIdx.x * 64;
  const int t  = threadIdx.x;
  const int tx = t & 15, ty = t >> 4;
  float acc[4][4] = {};
  const float* actb = act + ((size_t)b * C) * NPTS;

  for (int k0 = 0; k0 < C; k0 += 16) {
    const int r  = ty;
    const int cs = tx * 4;
    const int k  = k0 + r;
    float4 av = make_float4(0.f, 0.f, 0.f, 0.f);
    if (k < C) {
      av = *(const float4*)(actb + (size_t)k * NPTS + n0 + cs);
      if (inScale) {
        const float scv = inScale[k], shv = inShift[k];
        av.x = fmaxf(fmaf(av.x, scv, shv), 0.f);
        av.y = fmaxf(fmaf(av.y, scv, shv), 0.f);
        av.z = fmaxf(fmaf(av.z, scv, shv), 0.f);
        av.w = fmaxf(fmaf(av.w, scv, shv), 0.f);
      }
    }
    *(float4*)&As[r][cs] = av;

    float4 wv = make_float4(0.f, 0.f, 0.f, 0.f);
    if (k < C) {
      const float* wp = wt + (size_t)k * O;
      const int o = o0 + cs;
      if (o + 3 < O) {
        wv = *(const float4*)&wp[o];
      } else {
        float tmp[4] = {0.f, 0.f, 0.f, 0.f};
        for (int j = 0; j < 4; ++j) if (o + j < O) tmp[j] = wp[o + j];
        wv = make_float4(tmp[0], tmp[1], tmp[2], tmp[3]);
      }
    }
    *(float4*)&Ws[r][cs] = wv;
    __syncthreads();

    const int kmax = (C - k0 < 16) ? (C - k0) : 16;
    for (int kk = 0; kk < kmax; ++kk) {
      float4 a = *(float4*)&As[kk][tx * 4];
      float4 w = *(float4*)&Ws[kk][ty * 4];
      acc[0][0] += w.x * a.x; acc[0][1] += w.x * a.y; acc[0][2] += w.x * a.z; acc[0][3] += w.x * a.w;
      acc[1][0] += w.y * a.x; acc[1][1] += w.y * a.y; acc[1][2] += w.y * a.z; acc[1][3] += w.y * a.w;
      acc[2][0] += w.z * a.x; acc[2][1] += w.z * a.y; acc[2][2] += w.z * a.z; acc[2][3] += w.z * a.w;
      acc[3][0] += w.w * a.x; acc[3][1] += w.w * a.y; acc[3][2] += w.w * a.z; acc[3][3] += w.w * a.w;
    }
    __syncthreads();
  }

  float s[4], q[4];
  for (int i = 0; i < 4; ++i) {
    const int o = o0 + ty * 4 + i;
    s[i] = 0.f; q[i] = 0.f;
    if (o >= O) continue;
    float base = 0.f;
    if (rowbias) base  = rowbias[(size_t)b * O + o];
    if (obias)   base += obias[o];
    float4 v = make_float4(acc[i][0] + base, acc[i][1] + base, acc[i][2] + base, acc[i][3] + base);
    *(float4*)&out[((size_t)b * O + o) * NPTS + n0 + tx * 4] = v;
    s[i] = v.x + v.y + v.z + v.w;
    q[i] = v.x * v.x + v.y * v.y + v.z * v.z + v.w * v.w;
  }

  if (partials) {
    for (int i = 0; i < 4; ++i) { redS[ty * 4 + i][tx] = s[i]; redQ[ty * 4 + i][tx] = q[i]; }
    __syncthreads();
    if (t < 64) {
      float a = 0.f;
      for (int j = 0; j < 16; ++j) a += redS[t][j];
      partials[((size_t)b * O + o0 + t) * 64 + blockIdx.x] = a;
    } else if (t < 128) {
      float a = 0.f;
      for (int j = 0; j < 16; ++j) a += redQ[t - 64][j];
      partials[(size_t)BATCH * O * 64 + ((size_t)b * O + o0 + t - 64) * 64 + blockIdx.x] = a;
    }
  }
}

// ================= rank-exact chain =================
// conv1,conv2 in f64 (VALU). conv3 in fp32 via split-bf16 MFMA (error ~4e-6).
// topk gets ~top-40 fp32 candidates (DPP wave-max tournament on index-embedded
// u32 keys), then a small f64 RERANK recomputes the 40 candidate values exactly
// from f64 h2 and emits the top-32 by masked-f64 key. True top-32 is inside
// the candidate set with large margin, so the final output is exact.

// ---- conv1 (C=4): writes raw h1 fp32 (for conv4 value path) + f64 BN1 partials
__global__ __launch_bounds__(256) void conv1_f64(const float* __restrict__ x,
                                                 const float* __restrict__ w1,
                                                 float* __restrict__ h1f,
                                                 double* __restrict__ psd) {
  const int c = blockIdx.x, b = blockIdx.y;
  const double wa = (double)w1[c * 4 + 0], wb = (double)w1[c * 4 + 1];
  const double wc = (double)w1[c * 4 + 2], wd = (double)w1[c * 4 + 3];
  const float* xb = x + (size_t)b * 4 * NPTS;
  float* dst = h1f + ((size_t)b * 64 + c) * NPTS;
  double s = 0.0, q = 0.0;
  for (int n = threadIdx.x; n < NPTS; n += 256) {
    double v = wa * (double)xb[n] + wb * (double)xb[NPTS + n]
             + wc * (double)xb[2 * NPTS + n] + wd * (double)xb[3 * NPTS + n];
    dst[n] = (float)v;
    s += v; q += v * v;
  }
  __shared__ double ls[4], lq[4];
  for (int off = 32; off; off >>= 1) { s += __shfl_down(s, off, 64); q += __shfl_down(q, off, 64); }
  const int wid = threadIdx.x >> 6;
  if ((threadIdx.x & 63) == 0) { ls[wid] = s; lq[wid] = q; }
  __syncthreads();
  if (threadIdx.x == 0) {
    s = ls[0] + ls[1] + ls[2] + ls[3];
    q = lq[0] + lq[1] + lq[2] + lq[3];
    psd[(size_t)c * 16 + b] = s;
    psd[(size_t)64 * 16 + (size_t)c * 16 + b] = q;
  }
}

// ---- generic f64 BN finalize: fixed-order chunked reduction (deterministic)
__global__ __launch_bounds__(256) void bn_finalize_f64(const double* __restrict__ psd,
                                                       const float* __restrict__ g,
                                                       const float* __restrict__ be,
                                                       double* __restrict__ scd, double* __restrict__ shd,
                                                       float* __restrict__ scf, float* __restrict__ shf,
                                                       int NT) {
  const int c = blockIdx.x;
  const int t = threadIdx.x;
  const double* p2 = psd + (size_t)gridDim.x * NT;
  const int k = (NT + 255) / 256;
  double s = 0.0, q = 0.0;
  for (int i = t * k; i < (t + 1) * k && i < NT; ++i) {
    s += psd[(size_t)c * NT + i];
    q += p2[(size_t)c * NT + i];
  }
  __shared__ double ss[256], qq[256];
  ss[t] = s; qq[t] = q;
  __syncthreads();
  if (t == 0) {
    double S = 0.0, Q = 0.0;
    for (int i = 0; i < 256; ++i) { S += ss[i]; Q += qq[i]; }
    const double m   = S * (1.0 / 65536.0);
    const double var = Q * (1.0 / 65536.0) - m * m;
    const double sc  = (double)g[c] / sqrt(var + 1e-5);
    const double sh  = (double)be[c] - m * sc;
    if (scd) { scd[c] = sc; shd[c] = sh; }
    scf[c] = (float)sc;
    shf[c] = (float)sh;
  }
}

// ---- pack fp32 weights (O x C) -> f64 transposed (C x O) for coalesced staging
__global__ __launch_bounds__(256) void pack_wtf64(const float* __restrict__ src,
                                                  double* __restrict__ dst,
                                                  int O, int C) {
  int i = blockIdx.x * 256 + threadIdx.x;
  if (i >= O * C) return;
  int c = i / O, o = i - c * O;
  dst[(size_t)c * O + o] = (double)src[(size_t)o * C + c];
}

// ---- conv2 VALU f64: 128o x 64n tile; also emits fp32 copy h2f for conv3 MFMA.
__global__ __launch_bounds__(256) void conv2_f64v(
    const float* __restrict__ x, const float* __restrict__ w1,
    const double* __restrict__ w2t,   // (64c x 128o) f64
    const double* __restrict__ scd1, const double* __restrict__ shd1,
    double* __restrict__ h2d, float* __restrict__ h2f, double* __restrict__ psd)
{
  __shared__ double Bs[64][65];     // h1 tile (c1 x n), bn1+relu
  __shared__ double Ws[16][132];    // w2 chunk (k x o)
  const int nb = blockIdx.x, b = blockIdx.y;
  const int n0 = nb * 64;
  const int t = threadIdx.x;
  const float* xb = x + (size_t)b * 4 * NPTS + n0;
  for (int i = t; i < 64 * 64; i += 256) {
    const int c1 = i >> 6, n = i & 63;
    double v = (double)w1[c1 * 4 + 0] * (double)xb[n]
             + (double)w1[c1 * 4 + 1] * (double)xb[NPTS + n]
             + (double)w1[c1 * 4 + 2] * (double)xb[2 * NPTS + n]
             + (double)w1[c1 * 4 + 3] * (double)xb[3 * NPTS + n];
    v = v * scd1[c1] + shd1[c1];
    Bs[c1][n] = v > 0.0 ? v : 0.0;
  }
  const int tx = t & 15, ty = t >> 4;   // n = n0 + tx + 16j ; o = ty*8 .. +7
  double acc[8][4] = {};
  for (int ch = 0; ch < 4; ++ch) {
    __syncthreads();
    {
      const int r = t >> 4, oo = (t & 15) * 8;
      const double* srcw = w2t + (size_t)(ch * 16 + r) * 128 + oo;
#pragma unroll
      for (int j = 0; j < 8; ++j) Ws[r][oo + j] = srcw[j];
    }
    __syncthreads();
#pragma unroll
    for (int kk = 0; kk < 16; ++kk) {
      double a[8], bv[4];
#pragma unroll
      for (int j = 0; j < 8; ++j) a[j] = Ws[kk][ty * 8 + j];
#pragma unroll
      for (int j = 0; j < 4; ++j) bv[j] = Bs[ch * 16 + kk][tx + 16 * j];
#pragma unroll
      for (int i = 0; i < 8; ++i)
#pragma unroll
        for (int j = 0; j < 4; ++j) acc[i][j] = fma(a[i], bv[j], acc[i][j]);
    }
  }
  const size_t hb = (size_t)b * 128 * NPTS;
#pragma unroll
  for (int i = 0; i < 8; ++i) {
    const int o = ty * 8 + i;
    double s = 0.0, q = 0.0;
#pragma unroll
    for (int j = 0; j < 4; ++j) {
      const double v = acc[i][j];
      h2d[hb + (size_t)o * NPTS + n0 + tx + 16 * j] = v;
      h2f[hb + (size_t)o * NPTS + n0 + tx + 16 * j] = (float)v;
      s += v; q += v * v;
    }
#pragma unroll
    for (int m = 1; m < 16; m <<= 1) { s += __shfl_xor(s, m, 64); q += __shfl_xor(q, m, 64); }
    if (tx == 0) {
      psd[(size_t)o * 1024 + b * 64 + nb] = s;
      psd[(size_t)128 * 1024 + (size_t)o * 1024 + b * 64 + nb] = q;
    }
  }
}

// ---------------- pack weights (O,Ctot) fp32 -> hi/lo bf16 A-frag order
__global__ __launch_bounds__(256) void pack_wmfma(const float* __restrict__ src,
                                                  u16* __restrict__ ph, u16* __restrict__ pl,
                                                  int O, int Ctot, int cOff, int Csub) {
  int i = blockIdx.x * 256 + threadIdx.x;
  if (i >= O * Csub) return;
  const int KS = Csub >> 4;
  int j    = i & 7;
  int lj   = (i >> 3) & 63;
  int mtks = i >> 9;
  int ks   = mtks % KS;
  int mt   = mtks / KS;
  int o = mt * 32 + (lj & 31);
  int c = ks * 16 + (lj >> 5) * 8 + j;
  float v = src[(size_t)o * Ctot + cOff + c];
  u16 h = f2bf(v);
  ph[i] = h;
  pl[i] = f2bf(v - bf2f(h));
}

// ---------------- MFMA 1x1-conv GEMM (conv3/4/5/6): split-bf16, dbuf LDS.
__global__ __launch_bounds__(256) void conv_mfma(
    const float* __restrict__ act, const u16* __restrict__ wh, const u16* __restrict__ wl,
    const float* __restrict__ rowbias,
    const float* __restrict__ inScale, const float* __restrict__ inShift,
    float* __restrict__ out, float* __restrict__ ps, int C, int O)
{
  __shared__ u16 Bh[2][4096];
  __shared__ u16 Bl[2][4096];
  const int b  = blockIdx.z;
  const int o0 = blockIdx.y * 128;
  const int n0 = blockIdx.x * 128;
  const int t  = threadIdx.x;
  const int l  = t & 63, wva = t >> 6;
  const int mt = blockIdx.y * 4 + wva;
  const int KS = C >> 4;
  const int NCH = C >> 5;
  const float* actb = act + ((size_t)b * C) * NPTS;

  float16 acc[4];
#pragma unroll
  for (int ns = 0; ns < 4; ++ns)
#pragma unroll
    for (int r = 0; r < 16; ++r) acc[ns][r] = 0.f;

  const int cq = t >> 5;
  const int nq = t & 31;
  const int nn = n0 + nq * 4;
  const int ksl = cq >> 2, oct = (cq >> 1) & 1, j0 = (cq & 1) * 4;

  float va[4][4];
  float4 scv = make_float4(1.f,1.f,1.f,1.f), shv = make_float4(0.f,0.f,0.f,0.f);

  auto loadChunk = [&](int ch) {
    const int cb = ch * 32 + cq * 4;
#pragma unroll
    for (int i2 = 0; i2 < 4; ++i2) {
      float4 v4 = *(const float4*)(actb + (size_t)(cb + i2) * NPTS + nn);
      va[i2][0] = v4.x; va[i2][1] = v4.y; va[i2][2] = v4.z; va[i2][3] = v4.w;
    }
    if (inScale) {
      scv = *(const float4*)&inScale[cb];
      shv = *(const float4*)&inShift[cb];
    }
  };
  auto applyBN = [&]() {
    if (!inScale) return;
#pragma unroll
    for (int d = 0; d < 4; ++d) {
      va[0][d] = fmaxf(fmaf(va[0][d], scv.x, shv.x), 0.f);
      va[1][d] = fmaxf(fmaf(va[1][d], scv.y, shv.y), 0.f);
      va[2][d] = fmaxf(fmaf(va[2][d], scv.z, shv.z), 0.f);
      va[3][d] = fmaxf(fmaf(va[3][d], scv.w, shv.w), 0.f);
    }
  };
  auto convWrite = [&](int buf) {
#pragma unroll
    for (int d = 0; d < 4; ++d) {
      const int nrel = nq * 4 + d;
      const int ns = nrel >> 5, li = nrel & 31;
      u16 h0 = f2bf(va[0][d]), h1 = f2bf(va[1][d]), h2 = f2bf(va[2][d]), h3 = f2bf(va[3][d]);
      u16 q0 = f2bf(va[0][d] - bf2f(h0));
      u16 q1 = f2bf(va[1][d] - bf2f(h1));
      u16 q2 = f2bf(va[2][d] - bf2f(h2));
      u16 q3 = f2bf(va[3][d] - bf2f(h3));
      const int idx = ((ksl * 4 + ns) * 64 + oct * 32 + li) * 8 + j0;
      *(ushort4*)&Bh[buf][idx] = make_ushort4(h0, h1, h2, h3);
      *(ushort4*)&Bl[buf][idx] = make_ushort4(q0, q1, q2, q3);
    }
  };

  loadChunk(0);
  applyBN();
  convWrite(0);
  __syncthreads();

  for (int ch = 0; ch < NCH; ++ch) {
    const size_t abase = (((size_t)mt * KS + ch * 2) * 64 + (size_t)l) * 8;
    short8 AH0 = *(const short8*)(wh + abase);
    short8 AH1 = *(const short8*)(wh + abase + 512);
    short8 AL0 = *(const short8*)(wl + abase);
    short8 AL1 = *(const short8*)(wl + abase + 512);
    const bool more = (ch + 1 < NCH);
    if (more) loadChunk(ch + 1);

    const u16* bh = Bh[ch & 1];
    const u16* bl = Bl[ch & 1];
#pragma unroll
    for (int ns = 0; ns < 4; ++ns) {
      short8 BH0 = *(const short8*)&bh[((0 * 4 + ns) * 64 + l) * 8];
      short8 BL0 = *(const short8*)&bl[((0 * 4 + ns) * 64 + l) * 8];
      acc[ns] = __builtin_amdgcn_mfma_f32_32x32x16_bf16(AL0, BH0, acc[ns], 0, 0, 0);
      acc[ns] = __builtin_amdgcn_mfma_f32_32x32x16_bf16(AH0, BL0, acc[ns], 0, 0, 0);
      acc[ns] = __builtin_amdgcn_mfma_f32_32x32x16_bf16(AH0, BH0, acc[ns], 0, 0, 0);
      short8 BH1 = *(const short8*)&bh[((4 + ns) * 64 + l) * 8];
      short8 BL1 = *(const short8*)&bl[((4 + ns) * 64 + l) * 8];
      acc[ns] = __builtin_amdgcn_mfma_f32_32x32x16_bf16(AL1, BH1, acc[ns], 0, 0, 0);
      acc[ns] = __builtin_amdgcn_mfma_f32_32x32x16_bf16(AH1, BL1, acc[ns], 0, 0, 0);
      acc[ns] = __builtin_amdgcn_mfma_f32_32x32x16_bf16(AH1, BH1, acc[ns], 0, 0, 0);
    }
    if (more) { applyBN(); convWrite((ch + 1) & 1); }
    __syncthreads();
  }

  const int col = l & 31, half = l >> 5;
  float sv[16], sq[16];
#pragma unroll
  for (int r = 0; r < 16; ++r) {
    const int o = o0 + wva * 32 + (r & 3) + 8 * (r >> 2) + 4 * half;
    const float base = rowbias ? rowbias[(size_t)b * O + o] : 0.f;
    float s = 0.f, q = 0.f;
#pragma unroll
    for (int ns = 0; ns < 4; ++ns) {
      float val = acc[ns][r] + base;
      out[((size_t)b * O + o) * NPTS + n0 + ns * 32 + col] = val;
      s += val; q += val * val;
    }
    sv[r] = s; sq[r] = q;
  }
  if (ps) {
#pragma unroll
    for (int r = 0; r < 16; ++r) {
#pragma unroll
      for (int m = 1; m < 32; m <<= 1) {
        sv[r] += __shfl_xor(sv[r], m, 64);
        sq[r] += __shfl_xor(sq[r], m, 64);
      }
    }
    if (col == 0) {
#pragma unroll
      for (int r = 0; r < 16; ++r) {
        const int o = o0 + wva * 32 + (r & 3) + 8 * (r >> 2) + 4 * half;
        ps[((size_t)b * O + o) * 32 + blockIdx.x] = sv[r];
        ps[(size_t)BATCH * O * 32 + ((size_t)b * O + o) * 32 + blockIdx.x] = sq[r];
      }
    }
  }
}

// ---------------- BN finalize (fp32)
__global__ __launch_bounds__(256) void bn_finalize(const float* __restrict__ ps,
                                                   const float* __restrict__ g, const float* __restrict__ be,
                                                   float* __restrict__ scale, float* __restrict__ shift,
                                                   int O, int NT) {
  const int c = blockIdx.x;
  const int total = BATCH * NT;
  const float* p2 = ps + (size_t)BATCH * O * NT;
  const int t = threadIdx.x;
  float s = 0.f, q = 0.f;
  for (int e = t; e < total; e += 256) {
    const int b = e / NT, nt = e - b * NT;
    const size_t a = ((size_t)b * O + c) * NT + nt;
    s += ps[a];
    q += p2[a];
  }
#pragma unroll
  for (int m = 32; m; m >>= 1) {
    s += __shfl_down(s, m, 64);
    q += __shfl_down(q, m, 64);
  }
  __shared__ float lsS[4], lsQ[4];
  const int wid = t >> 6;
  if ((t & 63) == 0) { lsS[wid] = s; lsQ[wid] = q; }
  __syncthreads();
  if (t == 0) {
    s = lsS[0] + lsS[1] + lsS[2] + lsS[3];
    q = lsQ[0] + lsQ[1] + lsQ[2] + lsQ[3];
    const float inv = 1.f / 65536.f;
    float m   = s * inv;
    float var = q * inv - m * m;
    float sc  = g[c] * rsqrtf(var + 1e-5f);
    scale[c] = sc;
    shift[c] = be[c] - m * sc;
  }
}

// ---------------- DPP wave64 max (no LDS/bpermute): result broadcast via readlane
__device__ __forceinline__ int wave_max_i32(int v) {
  v = max(v, __builtin_amdgcn_update_dpp(v, v, 0x111, 0xf, 0xf, false)); // row_shr:1
  v = max(v, __builtin_amdgcn_update_dpp(v, v, 0x112, 0xf, 0xf, false)); // row_shr:2
  v = max(v, __builtin_amdgcn_update_dpp(v, v, 0x114, 0xf, 0xf, false)); // row_shr:4
  v = max(v, __builtin_amdgcn_update_dpp(v, v, 0x118, 0xf, 0xf, false)); // row_shr:8
  v = max(v, __builtin_amdgcn_update_dpp(v, v, 0x142, 0xa, 0xf, false)); // row_bcast:15
  v = max(v, __builtin_amdgcn_update_dpp(v, v, 0x143, 0xc, 0xf, false)); // row_bcast:31
  return __builtin_amdgcn_readlane(v, 63);
}

// ---------------- ~top-40 fp32 candidates per (b,c): per-lane bitonic-sorted
// queue of index-embedded keys + DPP wave-max tournament (zero DS ops in loop).
#define NCAND 40
__global__ __launch_bounds__(256) void topk40_f32(const float* __restrict__ h3,
                                                  int* __restrict__ cand) {
  __shared__ u64 wl[4][NCAND];
  const int c = blockIdx.x, b = blockIdx.y;
  const float* src = h3 + ((size_t)b * 256 + c) * NPTS;
  const int t = threadIdx.x;
  const int l = t & 63, w = t >> 6;
  const int base = w * 1024;

  // load + pack keys (flipped for signed compare: sign-xor makes i32 order == u32 order)
  int k[16];
#pragma unroll
  for (int s = 0; s < 16; ++s) {
    const int loc = s * 64 + l;
    uint32 u = __float_as_uint(src[base + loc]);
    uint32 m32 = ((int)u < 0) ? ~u : (u | 0x80000000u);
    uint32 packed = (m32 & ~0x3FFu) | (uint32)(1023 - loc);
    k[s] = (int)(packed ^ 0x80000000u);
  }

  // bitonic sort ascending: k[15] = lane max
#pragma unroll
  for (int kk = 2; kk <= 16; kk <<= 1) {
#pragma unroll
    for (int j = kk >> 1; j > 0; j >>= 1) {
#pragma unroll
      for (int i = 0; i < 16; ++i) {
        const int ij = i ^ j;
        if (ij > i) {
          const bool up = ((i & kk) == 0);
          const int a = k[i], bb = k[ij];
          const bool sw = up ? (a > bb) : (a < bb);
          k[i]  = sw ? bb : a;
          k[ij] = sw ? a : bb;
        }
      }
    }
  }

  // 40 rounds: DPP wave-max of k[15]; unique winner shifts its queue
  for (int r = 0; r < NCAND; ++r) {
    const int m = wave_max_i32(k[15]);
    if (k[15] == m) {
      const uint32 m32 = (uint32)m ^ 0x80000000u;
      const int loc = 1023 - (int)(m32 & 0x3FFu);
      const int ri = base + loc;
      wl[w][r] = ((u64)m32 << 32) | (u64)(4095 - ri);
#pragma unroll
      for (int s = 15; s > 0; --s) k[s] = k[s - 1];
      k[0] = (int)0x80000000;  // -inf sentinel
    }
  }
  __syncthreads();

  // lanes 0-3 of wave 0: 4-way merge of the sorted per-wave u64 lists
  if (t < 4) {
    int* dst = cand + ((size_t)b * 256 + c) * NCAND;
    int cp = 0;
    u64 cv = wl[t][0];
    for (int r = 0; r < NCAND; ++r) {
      u64 mv = cv;
      u64 ov;
      ov = __shfl_xor((unsigned long long)mv, 1, 64); if (ov > mv) mv = ov;
      ov = __shfl_xor((unsigned long long)mv, 2, 64); if (ov > mv) mv = ov;
      if (t == 0) dst[r] = 4095 - (int)(mv & 0xFFFu);
      if (mv == cv) {
        ++cp;
        cv = (cp < NCAND) ? wl[t][cp] : 0;
      }
    }
  }
}

// ---------------- transpose h2d (b,c2,n) -> h2T (b,n,c2) f64 (for rerank gathers)
__global__ __launch_bounds__(256) void transpose_h2(const double* __restrict__ h2d,
                                                    double* __restrict__ h2T) {
  __shared__ double tile[32][33];
  const int b = blockIdx.z;
  const int n0 = blockIdx.x * 32, c0 = blockIdx.y * 32;
  const int tx = threadIdx.x & 31, ty = threadIdx.x >> 5;
  const double* src = h2d + (size_t)b * 128 * NPTS;
  for (int j = 0; j < 4; ++j)
    tile[ty + j * 8][tx] = src[(size_t)(c0 + ty + j * 8) * NPTS + n0 + tx];
  __syncthreads();
  double* dst = h2T + (size_t)b * NPTS * 128;
  for (int j = 0; j < 4; ++j)
    dst[(size_t)(n0 + ty + j * 8) * 128 + c0 + tx] = tile[tx][ty + j * 8];
}

// ---------------- f64 rerank: exact h3 values for the 40 candidates, emit
// top-32 by masked-f64 key (same semantics as the full-f64 build).
__global__ __launch_bounds__(64) void rerank_f64(const double* __restrict__ h2T,
                                                 const float* __restrict__ w3,
                                                 const double* __restrict__ scd2,
                                                 const double* __restrict__ shd2,
                                                 const int* __restrict__ cand,
                                                 int* __restrict__ idxp) {
  __shared__ u64 keys[NCAND];
  const int o = blockIdx.x, b = blockIdx.y;
  const int l = threadIdx.x;
  const double wA = (double)w3[(size_t)o * 128 + l];
  const double wB = (double)w3[(size_t)o * 128 + l + 64];
  const double sA = scd2[l],      hA = shd2[l];
  const double sB = scd2[l + 64], hB = shd2[l + 64];
  const int* cd = cand + ((size_t)b * 256 + o) * NCAND;
  const double* hb = h2T + (size_t)b * NPTS * 128;
  for (int kk = 0; kk < NCAND; ++kk) {
    const int n = cd[kk];
    const double* col = hb + (size_t)n * 128;
    double va = col[l] * sA + hA;       va = va > 0.0 ? va : 0.0;
    double vb = col[l + 64] * sB + hB;  vb = vb > 0.0 ? vb : 0.0;
    double p = wA * va + wB * vb;
#pragma unroll
    for (int off = 32; off; off >>= 1) p += __shfl_down(p, off, 64);
    if (l == 0) {
      u64 u = (u64)__double_as_longlong(p);
      u64 m = ((long long)u < 0) ? ~u : (u | 0x8000000000000000ULL);
      m = (m & ~0xFFFULL) | (u64)(4095 - n);
      keys[kk] = m;
    }
  }
  __syncthreads();
  u64 kv = (l < NCAND) ? keys[l] : 0;
  int* dst = idxp + ((size_t)b * 256 + o) * 32;
  for (int r = 0; r < 32; ++r) {
    u64 m = kv;
#pragma unroll
    for (int off = 1; off < 64; off <<= 1) {
      u64 o2 = __shfl_xor((unsigned long long)m, off, 64);
      if (o2 > m) m = o2;
    }
    if (l == 0) dst[r] = 4095 - (int)(m & 0xFFFULL);
    if (m == kv) kv = 0;   // keys unique -> winner invalidates itself
  }
}

// ---------------- transpose h3f (B,C,N fp32) -> h3T (B,N,C fp32), applying BN3
__global__ __launch_bounds__(256) void transpose_h3f(const float* __restrict__ h3,
                                                     float* __restrict__ h3T,
                                                     const float* __restrict__ sc,
                                                     const float* __restrict__ sh) {
  __shared__ float tile[32][33];
  const int b = blockIdx.z;
  const int n0 = blockIdx.x * 32, c0 = blockIdx.y * 32;
  const int tx = threadIdx.x & 31, ty = threadIdx.x >> 5;
  const float* src = h3 + (size_t)b * 256 * NPTS;
  for (int j = 0; j < 4; ++j)
    tile[ty + j * 8][tx] = src[(size_t)(c0 + ty + j * 8) * NPTS + n0 + tx];
  __syncthreads();
  float* dst = h3T + (size_t)b * NPTS * 256;
  const float scv = sc[c0 + tx], shv = sh[c0 + tx];
  for (int j = 0; j < 4; ++j)
    dst[(size_t)(n0 + ty + j * 8) * 256 + c0 + tx] = fmaf(tile[tx][ty + j * 8], scv, shv);
}

// ---------------- fused: w8 (o,c,w) -> hi/lo bf16 directly in MFMA A-frag order
__global__ __launch_bounds__(256) void transpack_w8(const float* __restrict__ w8,
                                                    u16* __restrict__ w8h, u16* __restrict__ w8l) {
  __shared__ float tile[64][65];
  const int m0 = blockIdx.x * 64, w0 = blockIdx.y * 64;
  const int tx = threadIdx.x & 63, ty = threadIdx.x >> 6;
#pragma unroll
  for (int j = 0; j < 16; ++j)
    tile[ty + j * 4][tx] = w8[(size_t)(m0 + ty + j * 4) * 256 + w0 + tx];
  __syncthreads();
  const int m = m0 + tx;
  const int o = m >> 8, c = m & 255;
  const int mt = (o >> 5) & 7;
  const int lane = (o & 31) + ((c >> 3) & 1) * 32;
  const int ks = (c >> 4) & 15;
  const int jj = c & 7;
#pragma unroll
  for (int j = 0; j < 16; ++j) {
    const int w = w0 + ty + j * 4;
    float v = tile[tx][ty + j * 4];
    size_t f = ((((size_t)w * 8 + mt) * 16 + ks) * 64 + lane) * 8 + jj;
    u16 h = f2bf(v);
    w8h[f] = h;
    w8l[f] = f2bf(v - bf2f(h));
  }
}

// ---------------- conv8 via MFMA: R10 grid (32 w-groups of 8) + ks-XOR G swizzle
#define Y8N (BATCH * 256 * 32)
__global__ __launch_bounds__(256, 1) void conv8_mfma(
    const float* __restrict__ h3T, const u16* __restrict__ w8h,
    const u16* __restrict__ w8l, const int* __restrict__ idxp,
    float* __restrict__ y8p)
{
  __shared__ u16 G[2][8192];
  const int wg = blockIdx.x;
  const int oq = blockIdx.y;
  const int bg = blockIdx.z;
  const int t  = threadIdx.x;
  const int l  = t & 63, wv = t >> 6;
  const int mt = oq * 4 + wv;

  float16 accH[4], accL[4];
  for (int i = 0; i < 4; ++i)
    for (int r = 0; r < 16; ++r) { accH[i][r] = 0.f; accL[i][r] = 0.f; }

  short8 ah[16], al[16];
  const int hrow  = t >> 3;
  const int cbase = (t & 7) * 32;
  float4 g4[8];

  auto issueG = [&](int step) {
    int wi = step >> 2, bi = step & 3;
    int w = wg * 8 + wi;
    int b = bg * 4 + bi;
    int n = idxp[((size_t)b * 256 + w) * 32 + hrow];
    const float* src = h3T + ((size_t)b * NPTS + n) * 256 + cbase;
#pragma unroll
    for (int j = 0; j < 8; ++j) g4[j] = *(const float4*)&src[j * 4];
  };
  auto writeG = [&](int buf) {
#pragma unroll
    for (int a = 0; a < 4; ++a) {
      int c8 = (cbase >> 3) + a;
      int ks = c8 >> 1;
      int lp = (hrow + (c8 & 1) * 32) ^ (ks & 7);   // ks-XOR bank swizzle
      float4 v0 = g4[a * 2], v1 = g4[a * 2 + 1];
      uint32 u0 = (uint32)f2bf(v0.x) | ((uint32)f2bf(v0.y) << 16);
      uint32 u1 = (uint32)f2bf(v0.z) | ((uint32)f2bf(v0.w) << 16);
      uint32 u2 = (uint32)f2bf(v1.x) | ((uint32)f2bf(v1.y) << 16);
      uint32 u3 = (uint32)f2bf(v1.z) | ((uint32)f2bf(v1.w) << 16);
      *(uint4*)&G[buf][((size_t)ks * 64 + lp) * 8] = make_uint4(u0, u1, u2, u3);
    }
  };

  issueG(0); writeG(0);
  __syncthreads();

  for (int wi = 0; wi < 8; ++wi) {
    const int w = wg * 8 + wi;
    {
      const size_t base = (((size_t)w * 8 + mt) * 16) * 512 + (size_t)l * 8;
#pragma unroll
      for (int ks = 0; ks < 16; ++ks) {
        ah[ks] = *(const short8*)(w8h + base + ks * 512);
        al[ks] = *(const short8*)(w8l + base + ks * 512);
      }
    }
#pragma unroll
    for (int bi = 0; bi < 4; ++bi) {
      const int step = wi * 4 + bi;
      const int cur = bi & 1;
      if (step < 31) issueG(step + 1);
      const u16* Gc = G[cur];
#pragma unroll
      for (int ks = 0; ks < 16; ++ks) {
        short8 bf = *(const short8*)&Gc[((size_t)ks * 64 + (l ^ (ks & 7))) * 8];
        accH[bi] = __builtin_amdgcn_mfma_f32_32x32x16_bf16(ah[ks], bf, accH[bi], 0, 0, 0);
        accL[bi] = __builtin_amdgcn_mfma_f32_32x32x16_bf16(al[ks], bf, accL[bi], 0, 0, 0);
      }
      if (step < 31) writeG(1 - cur);
      __syncthreads();
    }
  }

  const int h = l & 31;
  const int rbase = oq * 128 + wv * 32 + 4 * (l >> 5);
#pragma unroll
  for (int bi = 0; bi < 4; ++bi) {
    int b = bg * 4 + bi;
    float* dst = y8p + ((size_t)(wg * BATCH + b) * 256) * 32;
#pragma unroll
    for (int r = 0; r < 16; ++r) {
      int o = rbase + (r & 3) + 8 * (r >> 2);
      dst[(size_t)o * 32 + h] = accH[bi][r] + accL[bi][r];
    }
  }
}

// ---------------- y8 = b8 + fixed-order sum of 32 w-group partials
__global__ __launch_bounds__(256) void y8_reduce(const float* __restrict__ y8p,
                                                 const float* __restrict__ b8,
                                                 float* __restrict__ y8) {
  int i = blockIdx.x * 256 + threadIdx.x;
  float s = b8[(i >> 5) & 255];
#pragma unroll
  for (int p = 0; p < 32; ++p) s += y8p[(size_t)p * Y8N + i];
  y8[i] = s;
}

// ---------------- conv9
__global__ __launch_bounds__(256) void conv9_kernel(const float* __restrict__ y8,
                                                    const float* __restrict__ w9,
                                                    const float* __restrict__ b9,
                                                    float* __restrict__ y9) {
  const int o = blockIdx.x, b = blockIdx.y;
  const float* yb = y8 + (size_t)b * 8192;
  const float* wo = w9 + (size_t)o * 8192;
  float s = 0.f;
  for (int i = threadIdx.x * 4; i < 8192; i += 1024) {
    float4 v = *(const float4*)&yb[i];
    float4 u = *(const float4*)&wo[i];
    s += v.x * u.x + v.y * u.y + v.z * u.z + v.w * u.w;
  }
  for (int off = 32; off; off >>= 1) s += __shfl_down(s, off, 64);
  __shared__ float ls[4];
  const int wid = threadIdx.x >> 6;
  if ((threadIdx.x & 63) == 0) ls[wid] = s;
  __syncthreads();
  if (threadIdx.x == 0) y9[(size_t)b * 256 + o] = ls[0] + ls[1] + ls[2] + ls[3] + b9[o];
}

// ---------------- cvec[b,o] = sum_c w4[o,c] * y9[b,c]
__global__ __launch_bounds__(256) void cvec_kernel(const float* __restrict__ y9,
                                                   const float* __restrict__ w4,
                                                   float* __restrict__ cvec) {
  int tid = blockIdx.x * 256 + threadIdx.x;
  if (tid >= BATCH * 512) return;
  const int b = tid >> 9, o = tid & 511;
  const float* row = w4 + (size_t)o * 320;
  const float* yb  = y9 + (size_t)b * 256;
  float s = 0.f;
  for (int c = 0; c < 256; c += 4) {
    float4 u = *(const float4*)&row[c];
    s += u.x * yb[c] + u.y * yb[c + 1] + u.z * yb[c + 2] + u.w * yb[c + 3];
  }
  cvec[(size_t)b * 512 + o] = s;
}

// ---------------- small weight transpose (fp32 conv7 path)
__global__ __launch_bounds__(256) void transpose_w(const float* __restrict__ src,
                                                   float* __restrict__ dst,
                                                   int O, int Ctot, int cOff, int Csub) {
  int i = blockIdx.x * 256 + threadIdx.x;
  if (i >= O * Csub) return;
  int c = i / O, o = i - c * O;
  dst[(size_t)c * O + o] = src[(size_t)o * Ctot + cOff + c];
}

// ---------------- final tanh
__global__ __launch_bounds__(256) void tanh_out(const float* __restrict__ raw,
                                                float* __restrict__ out) {
  int i = blockIdx.x * 256 + threadIdx.x;
  if (i < BATCH * 3 * NPTS) out[i] = tanhf(raw[i]);
}

extern "C" void kernel_launch(void* const* d_in, const int* in_sizes, int n_in,
                              void* d_out, int out_size, void* d_ws, size_t ws_size,
                              hipStream_t stream) {
  (void)in_sizes; (void)n_in; (void)ws_size; (void)out_size;
  const float* x   = (const float*)d_in[0];
  const float* w1  = (const float*)d_in[1];
  const float* g1  = (const float*)d_in[3];
  const float* be1 = (const float*)d_in[4];
  const float* w2  = (const float*)d_in[5];
  const float* g2  = (const float*)d_in[7];
  const float* be2 = (const float*)d_in[8];
  const float* w3  = (const float*)d_in[9];
  const float* g3  = (const float*)d_in[11];
  const float* be3 = (const float*)d_in[12];
  const float* w4  = (const float*)d_in[13];
  const float* g4  = (const float*)d_in[15];
  const float* be4 = (const float*)d_in[16];
  const float* w5  = (const float*)d_in[17];
  const float* g5  = (const float*)d_in[19];
  const float* be5 = (const float*)d_in[20];
  const float* w6  = (const float*)d_in[21];
  const float* g6  = (const float*)d_in[23];
  const float* be6 = (const float*)d_in[24];
  const float* w7  = (const float*)d_in[25];
  const float* b7  = (const float*)d_in[26];
  const float* w8  = (const float*)d_in[27];
  const float* b8  = (const float*)d_in[28];
  const float* w9  = (const float*)d_in[29];
  const float* b9  = (const float*)d_in[30];

  char* ws = (char*)d_ws;
  size_t off = 0;
  auto alloc = [&](size_t bytes) -> void* {
    void* p = ws + off;
    off += (bytes + 255) & ~(size_t)255;
    return p;
  };
  float* Q1  = (float*)alloc((size_t)BATCH * 64  * NPTS * 4);  // h1f (conv1->conv4), then raw7
  float* Q2  = (float*)alloc((size_t)BATCH * 128 * NPTS * 4);  // y8p -> h4 head -> h6
  float* Q3  = (float*)alloc((size_t)BATCH * 256 * NPTS * 4);  // h2d (f64 64MB) -> h3T -> h4 mid
  float* Q4  = (float*)alloc((size_t)BATCH * 256 * NPTS * 4);  // h3f (fp32) -> w8h/w8l -> h4 tail
  float* Q5  = (float*)alloc((size_t)BATCH * 256 * NPTS * 4);  // h2f (fp32) -> h2T (f64) -> h5
  int*   idx  = (int*)alloc((size_t)BATCH * 256 * 32 * 4);
  int*   cand = (int*)alloc((size_t)BATCH * 256 * NCAND * 4);
  float* y8   = (float*)alloc((size_t)Y8N * 4);
  float* y9   = (float*)alloc((size_t)BATCH * 256 * 4);
  float* cvec = (float*)alloc((size_t)BATCH * 512 * 4);
  float* ps   = (float*)alloc((size_t)2 * BATCH * 512 * 32 * 4);   // fp32 BN partials (NT=32)
  double* psd = (double*)alloc((size_t)2 * 256 * 1024 * 8);        // f64 BN partials
  float* scb  = (float*)alloc((size_t)6 * 1024 * 4);
  double* scdb = (double*)alloc((size_t)1024 * 8);                 // f64 BN consts
  float* w7t  = (float*)alloc(128 * 3 * 4);
  u16* ph3 = (u16*)alloc(256 * 128 * 2);  u16* pl3 = (u16*)alloc(256 * 128 * 2);
  u16* ph4 = (u16*)alloc(512 * 64  * 2);  u16* pl4 = (u16*)alloc(512 * 64  * 2);
  u16* ph5 = (u16*)alloc(256 * 512 * 2);  u16* pl5 = (u16*)alloc(256 * 512 * 2);
  u16* ph6 = (u16*)alloc(128 * 256 * 2);  u16* pl6 = (u16*)alloc(128 * 256 * 2);
  double* w2t = (double*)alloc((size_t)64 * 128 * 8);   // (c x o) f64

  double* h2d = (double*)Q3;                  // f64, alive until transpose_h2
  float*  h2f = (float*)Q5;                   // fp32 copy, dies after conv3 MFMA
  double* h2T = (double*)Q5;                  // f64 (b,n,c), overwrites dead h2f
  float*  h3f = Q4;                           // fp32 raw h3, dies after transpose_h3f
  u16*   w8h = (u16*)Q4;                      // after h3f dies
  u16*   w8l = (u16*)Q4 + (size_t)16777216;
  float* y8p = Q2;                            // dead before h4
  float* h4  = Q2;                            // 134 MB spans Q2 + Q3 + Q4 head
  float* h5  = Q5;                            // after h2T dies (rerank done)
  float* h6  = Q2;

  float* sc[6]; float* sh[6];
  for (int i = 0; i < 6; ++i) { sc[i] = scb + i * 1024; sh[i] = scb + i * 1024 + 512; }
  double* scd1 = scdb;        double* shd1 = scdb + 64;
  double* scd2 = scdb + 128;  double* shd2 = scdb + 256;

  // ---- weight preprocessing
  transpose_w<<<(128 * 3 + 255) / 256, 256, 0, stream>>>(w7, w7t, 3, 128, 0, 128);
  pack_wmfma<<<(256 * 128 + 255) / 256, 256, 0, stream>>>(w3, ph3, pl3, 256, 128, 0,   128);
  pack_wmfma<<<(512 * 64  + 255) / 256, 256, 0, stream>>>(w4, ph4, pl4, 512, 320, 256, 64);
  pack_wmfma<<<(256 * 512 + 255) / 256, 256, 0, stream>>>(w5, ph5, pl5, 256, 512, 0,   512);
  pack_wmfma<<<(128 * 256 + 255) / 256, 256, 0, stream>>>(w6, ph6, pl6, 128, 256, 0,   256);
  pack_wtf64<<<(128 * 64 + 255) / 256,  256, 0, stream>>>(w2, w2t, 128, 64);

  // ---- rank chain: conv1,conv2 f64; conv3 fp32 MFMA
  conv1_f64<<<dim3(64, BATCH), 256, 0, stream>>>(x, w1, Q1, psd);
  bn_finalize_f64<<<64, 256, 0, stream>>>(psd, g1, be1, scd1, shd1, sc[0], sh[0], 16);
  conv2_f64v<<<dim3(64, BATCH), 256, 0, stream>>>(x, w1, w2t, scd1, shd1, h2d, h2f, psd);
  bn_finalize_f64<<<128, 256, 0, stream>>>(psd, g2, be2, scd2, shd2, sc[1], sh[1], 1024);
  conv_mfma<<<dim3(32, 2, BATCH), 256, 0, stream>>>(h2f, ph3, pl3, nullptr, sc[1], sh[1], h3f, ps, 128, 256);
  bn_finalize<<<256, 256, 0, stream>>>(ps, g3, be3, sc[2], sh[2], 256, 32);

  // ---- softpool: fp32 top-40 candidates -> f64 rerank -> exact top-32
  topk40_f32<<<dim3(256, BATCH), 256, 0, stream>>>(h3f, cand);
  transpose_h2<<<dim3(NPTS / 32, 4, BATCH), 256, 0, stream>>>(h2d, h2T);
  rerank_f64<<<dim3(256, BATCH), 64, 0, stream>>>(h2T, w3, scd2, shd2, cand, idx);
  transpose_h3f<<<dim3(NPTS / 32, 8, BATCH), 256, 0, stream>>>(h3f, Q3, sc[2], sh[2]);

  // ---- w8 pack AFTER h3f is dead (reuses Q4)
  transpack_w8<<<dim3(1024, 4), 256, 0, stream>>>(w8, w8h, w8l);

  // ---- conv8 -> conv9 -> cvec
  conv8_mfma<<<dim3(32, 2, 4), 256, 0, stream>>>(Q3, w8h, w8l, idx, y8p);
  y8_reduce<<<Y8N / 256, 256, 0, stream>>>(y8p, b8, y8);
  conv9_kernel<<<dim3(256, BATCH), 256, 0, stream>>>(y8, w9, b9, y9);
  cvec_kernel<<<(BATCH * 512 + 255) / 256, 256, 0, stream>>>(y9, w4, cvec);

  // ---- conv4 (MFMA dbuf, rowbias=cvec, input h1 raw + BN1+relu)
  conv_mfma<<<dim3(32, 4, BATCH), 256, 0, stream>>>(Q1, ph4, pl4, cvec, sc[0], sh[0], h4, ps, 64, 512);
  bn_finalize<<<512, 256, 0, stream>>>(ps, g4, be4, sc[3], sh[3], 512, 32);
  // ---- conv5 (MFMA dbuf)
  conv_mfma<<<dim3(32, 2, BATCH), 256, 0, stream>>>(h4, ph5, pl5, nullptr, sc[3], sh[3], h5, ps, 512, 256);
  bn_finalize<<<256, 256, 0, stream>>>(ps, g5, be5, sc[4], sh[4], 256, 32);
  // ---- conv6 (MFMA dbuf)
  conv_mfma<<<dim3(32, 1, BATCH), 256, 0, stream>>>(h5, ph6, pl6, nullptr, sc[4], sh[4], h6, ps, 256, 128);
  bn_finalize<<<128, 256, 0, stream>>>(ps, g6, be6, sc[5], sh[5], 128, 32);
  // ---- conv7 (fp32, +b7, fused BN6+relu) -> tanh
  conv_gemm<<<dim3(64, 1, BATCH), 256, 0, stream>>>(h6, w7t, nullptr, b7, sc[5], sh[5], Q1, nullptr, 128, 3);
  tanh_out<<<(BATCH * 3 * NPTS) / 256, 256, 0, stream>>>(Q1, (float*)d_out);
}

// Round 13
// 788.270 us; speedup vs baseline: 1.0369x; 1.0064x over previous
//
#include <hip/hip_runtime.h>
#include <cstdint>
#include <cstddef>

#define NPTS 4096
#define BATCH 16

typedef unsigned int uint32;
typedef unsigned long long u64;
typedef unsigned short u16;

typedef __attribute__((ext_vector_type(8))) short short8;
typedef __attribute__((ext_vector_type(16))) float float16;

__device__ __forceinline__ u16 f2bf(float f) {
  uint32 u = __float_as_uint(f);
  u = (u + 0x7fffu + ((u >> 16) & 1u)) >> 16;
  return (u16)u;
}
__device__ __forceinline__ float bf2f(u16 h) {
  return __uint_as_float(((uint32)h) << 16);
}

// ---------------- fp32 1x1-conv GEMM — used ONLY for conv7 (value path).
__global__ __launch_bounds__(256) void conv_gemm(
    const float* __restrict__ act, const float* __restrict__ wt,
    const float* __restrict__ rowbias, const float* __restrict__ obias,
    const float* __restrict__ inScale, const float* __restrict__ inShift,
    float* __restrict__ out, float* __restrict__ partials, int C, int O)
{
  __shared__ float As[16][68];
  __shared__ float Ws[16][68];
  __shared__ float redS[64][17];
  __shared__ float redQ[64][17];
  const int b  = blockIdx.z;
  const int o0 = blockIdx.y * 64;
  const int n0 = blockIdx.x * 64;
  const int t  = threadIdx.x;
  const int tx = t & 15, ty = t >> 4;
  float acc[4][4] = {};
  const float* actb = act + ((size_t)b * C) * NPTS;

  for (int k0 = 0; k0 < C; k0 += 16) {
    const int r  = ty;
    const int cs = tx * 4;
    const int k  = k0 + r;
    float4 av = make_float4(0.f, 0.f, 0.f, 0.f);
    if (k < C) {
      av = *(const float4*)(actb + (size_t)k * NPTS + n0 + cs);
      if (inScale) {
        const float scv = inScale[k], shv = inShift[k];
        av.x = fmaxf(fmaf(av.x, scv, shv), 0.f);
        av.y = fmaxf(fmaf(av.y, scv, shv), 0.f);
        av.z = fmaxf(fmaf(av.z, scv, shv), 0.f);
        av.w = fmaxf(fmaf(av.w, scv, shv), 0.f);
      }
    }
    *(float4*)&As[r][cs] = av;

    float4 wv = make_float4(0.f, 0.f, 0.f, 0.f);
    if (k < C) {
      const float* wp = wt + (size_t)k * O;
      const int o = o0 + cs;
      if (o + 3 < O) {
        wv = *(const float4*)&wp[o];
      } else {
        float tmp[4] = {0.f, 0.f, 0.f, 0.f};
        for (int j = 0; j < 4; ++j) if (o + j < O) tmp[j] = wp[o + j];
        wv = make_float4(tmp[0], tmp[1], tmp[2], tmp[3]);
      }
    }
    *(float4*)&Ws[r][cs] = wv;
    __syncthreads();

    const int kmax = (C - k0 < 16) ? (C - k0) : 16;
    for (int kk = 0; kk < kmax; ++kk) {
      float4 a = *(float4*)&As[kk][tx * 4];
      float4 w = *(float4*)&Ws[kk][ty * 4];
      acc[0][0] += w.x * a.x; acc[0][1] += w.x * a.y; acc[0][2] += w.x * a.z; acc[0][3] += w.x * a.w;
      acc[1][0] += w.y * a.x; acc[1][1] += w.y * a.y; acc[1][2] += w.y * a.z; acc[1][3] += w.y * a.w;
      acc[2][0] += w.z * a.x; acc[2][1] += w.z * a.y; acc[2][2] += w.z * a.z; acc[2][3] += w.z * a.w;
      acc[3][0] += w.w * a.x; acc[3][1] += w.w * a.y; acc[3][2] += w.w * a.z; acc[3][3] += w.w * a.w;
    }
    __syncthreads();
  }

  float s[4], q[4];
  for (int i = 0; i < 4; ++i) {
    const int o = o0 + ty * 4 + i;
    s[i] = 0.f; q[i] = 0.f;
    if (o >= O) continue;
    float base = 0.f;
    if (rowbias) base  = rowbias[(size_t)b * O + o];
    if (obias)   base += obias[o];
    float4 v = make_float4(acc[i][0] + base, acc[i][1] + base, acc[i][2] + base, acc[i][3] + base);
    *(float4*)&out[((size_t)b * O + o) * NPTS + n0 + tx * 4] = v;
    s[i] = v.x + v.y + v.z + v.w;
    q[i] = v.x * v.x + v.y * v.y + v.z * v.z + v.w * v.w;
  }

  if (partials) {
    for (int i = 0; i < 4; ++i) { redS[ty * 4 + i][tx] = s[i]; redQ[ty * 4 + i][tx] = q[i]; }
    __syncthreads();
    if (t < 64) {
      float a = 0.f;
      for (int j = 0; j < 16; ++j) a += redS[t][j];
      partials[((size_t)b * O + o0 + t) * 64 + blockIdx.x] = a;
    } else if (t < 128) {
      float a = 0.f;
      for (int j = 0; j < 16; ++j) a += redQ[t - 64][j];
      partials[(size_t)BATCH * O * 64 + ((size_t)b * O + o0 + t - 64) * 64 + blockIdx.x] = a;
    }
  }
}

// ================= rank-exact chain =================
// conv1,conv2 in f64 (VALU). conv3 in fp32 via split-bf16 MFMA (error ~4e-6).
// topk gets ~top-40 fp32 candidates (DPP wave-max tournament on index-embedded
// u32 keys), then a small f64 RERANK recomputes the 40 candidate values exactly
// from f64 h2 and emits the top-32 by masked-f64 key. True top-32 is inside
// the candidate set with large margin, so the final output is exact.

// ---- conv1 (C=4): writes raw h1 fp32 (for conv4 value path) + f64 BN1 partials
__global__ __launch_bounds__(256) void conv1_f64(const float* __restrict__ x,
                                                 const float* __restrict__ w1,
                                                 float* __restrict__ h1f,
                                                 double* __restrict__ psd) {
  const int c = blockIdx.x, b = blockIdx.y;
  const double wa = (double)w1[c * 4 + 0], wb = (double)w1[c * 4 + 1];
  const double wc = (double)w1[c * 4 + 2], wd = (double)w1[c * 4 + 3];
  const float* xb = x + (size_t)b * 4 * NPTS;
  float* dst = h1f + ((size_t)b * 64 + c) * NPTS;
  double s = 0.0, q = 0.0;
  for (int n = threadIdx.x; n < NPTS; n += 256) {
    double v = wa * (double)xb[n] + wb * (double)xb[NPTS + n]
             + wc * (double)xb[2 * NPTS + n] + wd * (double)xb[3 * NPTS + n];
    dst[n] = (float)v;
    s += v; q += v * v;
  }
  __shared__ double ls[4], lq[4];
  for (int off = 32; off; off >>= 1) { s += __shfl_down(s, off, 64); q += __shfl_down(q, off, 64); }
  const int wid = threadIdx.x >> 6;
  if ((threadIdx.x & 63) == 0) { ls[wid] = s; lq[wid] = q; }
  __syncthreads();
  if (threadIdx.x == 0) {
    s = ls[0] + ls[1] + ls[2] + ls[3];
    q = lq[0] + lq[1] + lq[2] + lq[3];
    psd[(size_t)c * 16 + b] = s;
    psd[(size_t)64 * 16 + (size_t)c * 16 + b] = q;
  }
}

// ---- generic f64 BN finalize: fixed-order chunked reduction (deterministic)
__global__ __launch_bounds__(256) void bn_finalize_f64(const double* __restrict__ psd,
                                                       const float* __restrict__ g,
                                                       const float* __restrict__ be,
                                                       double* __restrict__ scd, double* __restrict__ shd,
                                                       float* __restrict__ scf, float* __restrict__ shf,
                                                       int NT) {
  const int c = blockIdx.x;
  const int t = threadIdx.x;
  const double* p2 = psd + (size_t)gridDim.x * NT;
  const int k = (NT + 255) / 256;
  double s = 0.0, q = 0.0;
  for (int i = t * k; i < (t + 1) * k && i < NT; ++i) {
    s += psd[(size_t)c * NT + i];
    q += p2[(size_t)c * NT + i];
  }
  __shared__ double ss[256], qq[256];
  ss[t] = s; qq[t] = q;
  __syncthreads();
  if (t == 0) {
    double S = 0.0, Q = 0.0;
    for (int i = 0; i < 256; ++i) { S += ss[i]; Q += qq[i]; }
    const double m   = S * (1.0 / 65536.0);
    const double var = Q * (1.0 / 65536.0) - m * m;
    const double sc  = (double)g[c] / sqrt(var + 1e-5);
    const double sh  = (double)be[c] - m * sc;
    if (scd) { scd[c] = sc; shd[c] = sh; }
    scf[c] = (float)sc;
    shf[c] = (float)sh;
  }
}

// ---- pack fp32 weights (O x C) -> f64 transposed (C x O) for coalesced staging
__global__ __launch_bounds__(256) void pack_wtf64(const float* __restrict__ src,
                                                  double* __restrict__ dst,
                                                  int O, int C) {
  int i = blockIdx.x * 256 + threadIdx.x;
  if (i >= O * C) return;
  int c = i / O, o = i - c * O;
  dst[(size_t)c * O + o] = (double)src[(size_t)o * C + c];
}

// ---- conv2 VALU f64: 128o x 64n tile; also emits fp32 copy h2f for conv3 MFMA.
__global__ __launch_bounds__(256) void conv2_f64v(
    const float* __restrict__ x, const float* __restrict__ w1,
    const double* __restrict__ w2t,   // (64c x 128o) f64
    const double* __restrict__ scd1, const double* __restrict__ shd1,
    double* __restrict__ h2d, float* __restrict__ h2f, double* __restrict__ psd)
{
  __shared__ double Bs[64][65];     // h1 tile (c1 x n), bn1+relu
  __shared__ double Ws[16][132];    // w2 chunk (k x o)
  const int nb = blockIdx.x, b = blockIdx.y;
  const int n0 = nb * 64;
  const int t = threadIdx.x;
  const float* xb = x + (size_t)b * 4 * NPTS + n0;
  for (int i = t; i < 64 * 64; i += 256) {
    const int c1 = i >> 6, n = i & 63;
    double v = (double)w1[c1 * 4 + 0] * (double)xb[n]
             + (double)w1[c1 * 4 + 1] * (double)xb[NPTS + n]
             + (double)w1[c1 * 4 + 2] * (double)xb[2 * NPTS + n]
             + (double)w1[c1 * 4 + 3] * (double)xb[3 * NPTS + n];
    v = v * scd1[c1] + shd1[c1];
    Bs[c1][n] = v > 0.0 ? v : 0.0;
  }
  const int tx = t & 15, ty = t >> 4;   // n = n0 + tx + 16j ; o = ty*8 .. +7
  double acc[8][4] = {};
  for (int ch = 0; ch < 4; ++ch) {
    __syncthreads();
    {
      const int r = t >> 4, oo = (t & 15) * 8;
      const double* srcw = w2t + (size_t)(ch * 16 + r) * 128 + oo;
#pragma unroll
      for (int j = 0; j < 8; ++j) Ws[r][oo + j] = srcw[j];
    }
    __syncthreads();
#pragma unroll
    for (int kk = 0; kk < 16; ++kk) {
      double a[8], bv[4];
#pragma unroll
      for (int j = 0; j < 8; ++j) a[j] = Ws[kk][ty * 8 + j];
#pragma unroll
      for (int j = 0; j < 4; ++j) bv[j] = Bs[ch * 16 + kk][tx + 16 * j];
#pragma unroll
      for (int i = 0; i < 8; ++i)
#pragma unroll
        for (int j = 0; j < 4; ++j) acc[i][j] = fma(a[i], bv[j], acc[i][j]);
    }
  }
  const size_t hb = (size_t)b * 128 * NPTS;
#pragma unroll
  for (int i = 0; i < 8; ++i) {
    const int o = ty * 8 + i;
    double s = 0.0, q = 0.0;
#pragma unroll
    for (int j = 0; j < 4; ++j) {
      const double v = acc[i][j];
      h2d[hb + (size_t)o * NPTS + n0 + tx + 16 * j] = v;
      h2f[hb + (size_t)o * NPTS + n0 + tx + 16 * j] = (float)v;
      s += v; q += v * v;
    }
#pragma unroll
    for (int m = 1; m < 16; m <<= 1) { s += __shfl_xor(s, m, 64); q += __shfl_xor(q, m, 64); }
    if (tx == 0) {
      psd[(size_t)o * 1024 + b * 64 + nb] = s;
      psd[(size_t)128 * 1024 + (size_t)o * 1024 + b * 64 + nb] = q;
    }
  }
}

// ---------------- pack weights (O,Ctot) fp32 -> hi/lo bf16 A-frag order
__global__ __launch_bounds__(256) void pack_wmfma(const float* __restrict__ src,
                                                  u16* __restrict__ ph, u16* __restrict__ pl,
                                                  int O, int Ctot, int cOff, int Csub) {
  int i = blockIdx.x * 256 + threadIdx.x;
  if (i >= O * Csub) return;
  const int KS = Csub >> 4;
  int j    = i & 7;
  int lj   = (i >> 3) & 63;
  int mtks = i >> 9;
  int ks   = mtks % KS;
  int mt   = mtks / KS;
  int o = mt * 32 + (lj & 31);
  int c = ks * 16 + (lj >> 5) * 8 + j;
  float v = src[(size_t)o * Ctot + cOff + c];
  u16 h = f2bf(v);
  ph[i] = h;
  pl[i] = f2bf(v - bf2f(h));
}

// ---------------- MFMA 1x1-conv GEMM (conv3/4/5/6): split-bf16, dbuf LDS.
__global__ __launch_bounds__(256) void conv_mfma(
    const float* __restrict__ act, const u16* __restrict__ wh, const u16* __restrict__ wl,
    const float* __restrict__ rowbias,
    const float* __restrict__ inScale, const float* __restrict__ inShift,
    float* __restrict__ out, float* __restrict__ ps, int C, int O)
{
  __shared__ u16 Bh[2][4096];
  __shared__ u16 Bl[2][4096];
  const int b  = blockIdx.z;
  const int o0 = blockIdx.y * 128;
  const int n0 = blockIdx.x * 128;
  const int t  = threadIdx.x;
  const int l  = t & 63, wva = t >> 6;
  const int mt = blockIdx.y * 4 + wva;
  const int KS = C >> 4;
  const int NCH = C >> 5;
  const float* actb = act + ((size_t)b * C) * NPTS;

  float16 acc[4];
#pragma unroll
  for (int ns = 0; ns < 4; ++ns)
#pragma unroll
    for (int r = 0; r < 16; ++r) acc[ns][r] = 0.f;

  const int cq = t >> 5;
  const int nq = t & 31;
  const int nn = n0 + nq * 4;
  const int ksl = cq >> 2, oct = (cq >> 1) & 1, j0 = (cq & 1) * 4;

  float va[4][4];
  float4 scv = make_float4(1.f,1.f,1.f,1.f), shv = make_float4(0.f,0.f,0.f,0.f);

  auto loadChunk = [&](int ch) {
    const int cb = ch * 32 + cq * 4;
#pragma unroll
    for (int i2 = 0; i2 < 4; ++i2) {
      float4 v4 = *(const float4*)(actb + (size_t)(cb + i2) * NPTS + nn);
      va[i2][0] = v4.x; va[i2][1] = v4.y; va[i2][2] = v4.z; va[i2][3] = v4.w;
    }
    if (inScale) {
      scv = *(const float4*)&inScale[cb];
      shv = *(const float4*)&inShift[cb];
    }
  };
  auto applyBN = [&]() {
    if (!inScale) return;
#pragma unroll
    for (int d = 0; d < 4; ++d) {
      va[0][d] = fmaxf(fmaf(va[0][d], scv.x, shv.x), 0.f);
      va[1][d] = fmaxf(fmaf(va[1][d], scv.y, shv.y), 0.f);
      va[2][d] = fmaxf(fmaf(va[2][d], scv.z, shv.z), 0.f);
      va[3][d] = fmaxf(fmaf(va[3][d], scv.w, shv.w), 0.f);
    }
  };
  auto convWrite = [&](int buf) {
#pragma unroll
    for (int d = 0; d < 4; ++d) {
      const int nrel = nq * 4 + d;
      const int ns = nrel >> 5, li = nrel & 31;
      u16 h0 = f2bf(va[0][d]), h1 = f2bf(va[1][d]), h2 = f2bf(va[2][d]), h3 = f2bf(va[3][d]);
      u16 q0 = f2bf(va[0][d] - bf2f(h0));
      u16 q1 = f2bf(va[1][d] - bf2f(h1));
      u16 q2 = f2bf(va[2][d] - bf2f(h2));
      u16 q3 = f2bf(va[3][d] - bf2f(h3));
      const int idx = ((ksl * 4 + ns) * 64 + oct * 32 + li) * 8 + j0;
      *(ushort4*)&Bh[buf][idx] = make_ushort4(h0, h1, h2, h3);
      *(ushort4*)&Bl[buf][idx] = make_ushort4(q0, q1, q2, q3);
    }
  };

  loadChunk(0);
  applyBN();
  convWrite(0);
  __syncthreads();

  for (int ch = 0; ch < NCH; ++ch) {
    const size_t abase = (((size_t)mt * KS + ch * 2) * 64 + (size_t)l) * 8;
    short8 AH0 = *(const short8*)(wh + abase);
    short8 AH1 = *(const short8*)(wh + abase + 512);
    short8 AL0 = *(const short8*)(wl + abase);
    short8 AL1 = *(const short8*)(wl + abase + 512);
    const bool more = (ch + 1 < NCH);
    if (more) loadChunk(ch + 1);

    const u16* bh = Bh[ch & 1];
    const u16* bl = Bl[ch & 1];
#pragma unroll
    for (int ns = 0; ns < 4; ++ns) {
      short8 BH0 = *(const short8*)&bh[((0 * 4 + ns) * 64 + l) * 8];
      short8 BL0 = *(const short8*)&bl[((0 * 4 + ns) * 64 + l) * 8];
      acc[ns] = __builtin_amdgcn_mfma_f32_32x32x16_bf16(AL0, BH0, acc[ns], 0, 0, 0);
      acc[ns] = __builtin_amdgcn_mfma_f32_32x32x16_bf16(AH0, BL0, acc[ns], 0, 0, 0);
      acc[ns] = __builtin_amdgcn_mfma_f32_32x32x16_bf16(AH0, BH0, acc[ns], 0, 0, 0);
      short8 BH1 = *(const short8*)&bh[((4 + ns) * 64 + l) * 8];
      short8 BL1 = *(const short8*)&bl[((4 + ns) * 64 + l) * 8];
      acc[ns] = __builtin_amdgcn_mfma_f32_32x32x16_bf16(AL1, BH1, acc[ns], 0, 0, 0);
      acc[ns] = __builtin_amdgcn_mfma_f32_32x32x16_bf16(AH1, BL1, acc[ns], 0, 0, 0);
      acc[ns] = __builtin_amdgcn_mfma_f32_32x32x16_bf16(AH1, BH1, acc[ns], 0, 0, 0);
    }
    if (more) { applyBN(); convWrite((ch + 1) & 1); }
    __syncthreads();
  }

  const int col = l & 31, half = l >> 5;
  float sv[16], sq[16];
#pragma unroll
  for (int r = 0; r < 16; ++r) {
    const int o = o0 + wva * 32 + (r & 3) + 8 * (r >> 2) + 4 * half;
    const float base = rowbias ? rowbias[(size_t)b * O + o] : 0.f;
    float s = 0.f, q = 0.f;
#pragma unroll
    for (int ns = 0; ns < 4; ++ns) {
      float val = acc[ns][r] + base;
      out[((size_t)b * O + o) * NPTS + n0 + ns * 32 + col] = val;
      s += val; q += val * val;
    }
    sv[r] = s; sq[r] = q;
  }
  if (ps) {
#pragma unroll
    for (int r = 0; r < 16; ++r) {
#pragma unroll
      for (int m = 1; m < 32; m <<= 1) {
        sv[r] += __shfl_xor(sv[r], m, 64);
        sq[r] += __shfl_xor(sq[r], m, 64);
      }
    }
    if (col == 0) {
#pragma unroll
      for (int r = 0; r < 16; ++r) {
        const int o = o0 + wva * 32 + (r & 3) + 8 * (r >> 2) + 4 * half;
        ps[((size_t)b * O + o) * 32 + blockIdx.x] = sv[r];
        ps[(size_t)BATCH * O * 32 + ((size_t)b * O + o) * 32 + blockIdx.x] = sq[r];
      }
    }
  }
}

// ---------------- BN finalize (fp32)
__global__ __launch_bounds__(256) void bn_finalize(const float* __restrict__ ps,
                                                   const float* __restrict__ g, const float* __restrict__ be,
                                                   float* __restrict__ scale, float* __restrict__ shift,
                                                   int O, int NT) {
  const int c = blockIdx.x;
  const int total = BATCH * NT;
  const float* p2 = ps + (size_t)BATCH * O * NT;
  const int t = threadIdx.x;
  float s = 0.f, q = 0.f;
  for (int e = t; e < total; e += 256) {
    const int b = e / NT, nt = e - b * NT;
    const size_t a = ((size_t)b * O + c) * NT + nt;
    s += ps[a];
    q += p2[a];
  }
#pragma unroll
  for (int m = 32; m; m >>= 1) {
    s += __shfl_down(s, m, 64);
    q += __shfl_down(q, m, 64);
  }
  __shared__ float lsS[4], lsQ[4];
  const int wid = t >> 6;
  if ((t & 63) == 0) { lsS[wid] = s; lsQ[wid] = q; }
  __syncthreads();
  if (t == 0) {
    s = lsS[0] + lsS[1] + lsS[2] + lsS[3];
    q = lsQ[0] + lsQ[1] + lsQ[2] + lsQ[3];
    const float inv = 1.f / 65536.f;
    float m   = s * inv;
    float var = q * inv - m * m;
    float sc  = g[c] * rsqrtf(var + 1e-5f);
    scale[c] = sc;
    shift[c] = be[c] - m * sc;
  }
}

// ---------------- DPP wave64 max (no LDS/bpermute): result broadcast via readlane
__device__ __forceinline__ int wave_max_i32(int v) {
  v = max(v, __builtin_amdgcn_update_dpp(v, v, 0x111, 0xf, 0xf, false)); // row_shr:1
  v = max(v, __builtin_amdgcn_update_dpp(v, v, 0x112, 0xf, 0xf, false)); // row_shr:2
  v = max(v, __builtin_amdgcn_update_dpp(v, v, 0x114, 0xf, 0xf, false)); // row_shr:4
  v = max(v, __builtin_amdgcn_update_dpp(v, v, 0x118, 0xf, 0xf, false)); // row_shr:8
  v = max(v, __builtin_amdgcn_update_dpp(v, v, 0x142, 0xa, 0xf, false)); // row_bcast:15
  v = max(v, __builtin_amdgcn_update_dpp(v, v, 0x143, 0xc, 0xf, false)); // row_bcast:31
  return __builtin_amdgcn_readlane(v, 63);
}

// ---------------- ~top-40 fp32 candidates per (b,c): per-lane bitonic-sorted
// queue of index-embedded keys + DPP wave-max tournament (zero DS ops in loop).
#define NCAND 40
__global__ __launch_bounds__(256) void topk40_f32(const float* __restrict__ h3,
                                                  int* __restrict__ cand) {
  __shared__ u64 wl[4][NCAND];
  const int c = blockIdx.x, b = blockIdx.y;
  const float* src = h3 + ((size_t)b * 256 + c) * NPTS;
  const int t = threadIdx.x;
  const int l = t & 63, w = t >> 6;
  const int base = w * 1024;

  // load + pack keys (flipped for signed compare: sign-xor makes i32 order == u32 order)
  int k[16];
#pragma unroll
  for (int s = 0; s < 16; ++s) {
    const int loc = s * 64 + l;
    uint32 u = __float_as_uint(src[base + loc]);
    uint32 m32 = ((int)u < 0) ? ~u : (u | 0x80000000u);
    uint32 packed = (m32 & ~0x3FFu) | (uint32)(1023 - loc);
    k[s] = (int)(packed ^ 0x80000000u);
  }

  // bitonic sort ascending: k[15] = lane max
#pragma unroll
  for (int kk = 2; kk <= 16; kk <<= 1) {
#pragma unroll
    for (int j = kk >> 1; j > 0; j >>= 1) {
#pragma unroll
      for (int i = 0; i < 16; ++i) {
        const int ij = i ^ j;
        if (ij > i) {
          const bool up = ((i & kk) == 0);
          const int a = k[i], bb = k[ij];
          const bool sw = up ? (a > bb) : (a < bb);
          k[i]  = sw ? bb : a;
          k[ij] = sw ? a : bb;
        }
      }
    }
  }

  // 40 rounds: DPP wave-max of k[15]; unique winner shifts its queue
  for (int r = 0; r < NCAND; ++r) {
    const int m = wave_max_i32(k[15]);
    if (k[15] == m) {
      const uint32 m32 = (uint32)m ^ 0x80000000u;
      const int loc = 1023 - (int)(m32 & 0x3FFu);
      const int ri = base + loc;
      wl[w][r] = ((u64)m32 << 32) | (u64)(4095 - ri);
#pragma unroll
      for (int s = 15; s > 0; --s) k[s] = k[s - 1];
      k[0] = (int)0x80000000;  // -inf sentinel
    }
  }
  __syncthreads();

  // lanes 0-3 of wave 0: 4-way merge of the sorted per-wave u64 lists
  if (t < 4) {
    int* dst = cand + ((size_t)b * 256 + c) * NCAND;
    int cp = 0;
    u64 cv = wl[t][0];
    for (int r = 0; r < NCAND; ++r) {
      u64 mv = cv;
      u64 ov;
      ov = __shfl_xor((unsigned long long)mv, 1, 64); if (ov > mv) mv = ov;
      ov = __shfl_xor((unsigned long long)mv, 2, 64); if (ov > mv) mv = ov;
      if (t == 0) dst[r] = 4095 - (int)(mv & 0xFFFu);
      if (mv == cv) {
        ++cp;
        cv = (cp < NCAND) ? wl[t][cp] : 0;
      }
    }
  }
}

// ---------------- transpose h2d (b,c2,n) -> h2T (b,n,c2) f64 (for rerank gathers)
__global__ __launch_bounds__(256) void transpose_h2(const double* __restrict__ h2d,
                                                    double* __restrict__ h2T) {
  __shared__ double tile[32][33];
  const int b = blockIdx.z;
  const int n0 = blockIdx.x * 32, c0 = blockIdx.y * 32;
  const int tx = threadIdx.x & 31, ty = threadIdx.x >> 5;
  const double* src = h2d + (size_t)b * 128 * NPTS;
  for (int j = 0; j < 4; ++j)
    tile[ty + j * 8][tx] = src[(size_t)(c0 + ty + j * 8) * NPTS + n0 + tx];
  __syncthreads();
  double* dst = h2T + (size_t)b * NPTS * 128;
  for (int j = 0; j < 4; ++j)
    dst[(size_t)(n0 + ty + j * 8) * 128 + c0 + tx] = tile[tx][ty + j * 8];
}

// ---------------- f64 rerank: exact h3 values for the 40 candidates, emit
// top-32 by masked-f64 key (same semantics as the full-f64 build).
__global__ __launch_bounds__(64) void rerank_f64(const double* __restrict__ h2T,
                                                 const float* __restrict__ w3,
                                                 const double* __restrict__ scd2,
                                                 const double* __restrict__ shd2,
                                                 const int* __restrict__ cand,
                                                 int* __restrict__ idxp) {
  __shared__ u64 keys[NCAND];
  const int o = blockIdx.x, b = blockIdx.y;
  const int l = threadIdx.x;
  const double wA = (double)w3[(size_t)o * 128 + l];
  const double wB = (double)w3[(size_t)o * 128 + l + 64];
  const double sA = scd2[l],      hA = shd2[l];
  const double sB = scd2[l + 64], hB = shd2[l + 64];
  const int* cd = cand + ((size_t)b * 256 + o) * NCAND;
  const double* hb = h2T + (size_t)b * NPTS * 128;
  for (int kk = 0; kk < NCAND; ++kk) {
    const int n = cd[kk];
    const double* col = hb + (size_t)n * 128;
    double va = col[l] * sA + hA;       va = va > 0.0 ? va : 0.0;
    double vb = col[l + 64] * sB + hB;  vb = vb > 0.0 ? vb : 0.0;
    double p = wA * va + wB * vb;
#pragma unroll
    for (int off = 32; off; off >>= 1) p += __shfl_down(p, off, 64);
    if (l == 0) {
      u64 u = (u64)__double_as_longlong(p);
      u64 m = ((long long)u < 0) ? ~u : (u | 0x8000000000000000ULL);
      m = (m & ~0xFFFULL) | (u64)(4095 - n);
      keys[kk] = m;
    }
  }
  __syncthreads();
  u64 kv = (l < NCAND) ? keys[l] : 0;
  int* dst = idxp + ((size_t)b * 256 + o) * 32;
  for (int r = 0; r < 32; ++r) {
    u64 m = kv;
#pragma unroll
    for (int off = 1; off < 64; off <<= 1) {
      u64 o2 = __shfl_xor((unsigned long long)m, off, 64);
      if (o2 > m) m = o2;
    }
    if (l == 0) dst[r] = 4095 - (int)(m & 0xFFFULL);
    if (m == kv) kv = 0;   // keys unique -> winner invalidates itself
  }
}

// ---------------- transpose h3f (B,C,N fp32) -> h3T (B,N,C fp32), applying BN3
__global__ __launch_bounds__(256) void transpose_h3f(const float* __restrict__ h3,
                                                     float* __restrict__ h3T,
                                                     const float* __restrict__ sc,
                                                     const float* __restrict__ sh) {
  __shared__ float tile[32][33];
  const int b = blockIdx.z;
  const int n0 = blockIdx.x * 32, c0 = blockIdx.y * 32;
  const int tx = threadIdx.x & 31, ty = threadIdx.x >> 5;
  const float* src = h3 + (size_t)b * 256 * NPTS;
  for (int j = 0; j < 4; ++j)
    tile[ty + j * 8][tx] = src[(size_t)(c0 + ty + j * 8) * NPTS + n0 + tx];
  __syncthreads();
  float* dst = h3T + (size_t)b * NPTS * 256;
  const float scv = sc[c0 + tx], shv = sh[c0 + tx];
  for (int j = 0; j < 4; ++j)
    dst[(size_t)(n0 + ty + j * 8) * 256 + c0 + tx] = fmaf(tile[tx][ty + j * 8], scv, shv);
}

// ---------------- fused: w8 (o,c,w) -> hi/lo bf16 directly in MFMA A-frag order
__global__ __launch_bounds__(256) void transpack_w8(const float* __restrict__ w8,
                                                    u16* __restrict__ w8h, u16* __restrict__ w8l) {
  __shared__ float tile[64][65];
  const int m0 = blockIdx.x * 64, w0 = blockIdx.y * 64;
  const int tx = threadIdx.x & 63, ty = threadIdx.x >> 6;
#pragma unroll
  for (int j = 0; j < 16; ++j)
    tile[ty + j * 4][tx] = w8[(size_t)(m0 + ty + j * 4) * 256 + w0 + tx];
  __syncthreads();
  const int m = m0 + tx;
  const int o = m >> 8, c = m & 255;
  const int mt = (o >> 5) & 7;
  const int lane = (o & 31) + ((c >> 3) & 1) * 32;
  const int ks = (c >> 4) & 15;
  const int jj = c & 7;
#pragma unroll
  for (int j = 0; j < 16; ++j) {
    const int w = w0 + ty + j * 4;
    float v = tile[tx][ty + j * 4];
    size_t f = ((((size_t)w * 8 + mt) * 16 + ks) * 64 + lane) * 8 + jj;
    u16 h = f2bf(v);
    w8h[f] = h;
    w8l[f] = f2bf(v - bf2f(h));
  }
}

// ---------------- conv8 via MFMA (R10 structure: 32 w-groups of 8, no swizzle)
#define Y8N (BATCH * 256 * 32)
__global__ __launch_bounds__(256, 1) void conv8_mfma(
    const float* __restrict__ h3T, const u16* __restrict__ w8h,
    const u16* __restrict__ w8l, const int* __restrict__ idxp,
    float* __restrict__ y8p)
{
  __shared__ u16 G[2][8192];
  const int wg = blockIdx.x;
  const int oq = blockIdx.y;
  const int bg = blockIdx.z;
  const int t  = threadIdx.x;
  const int l  = t & 63, wv = t >> 6;
  const int mt = oq * 4 + wv;

  float16 accH[4], accL[4];
  for (int i = 0; i < 4; ++i)
    for (int r = 0; r < 16; ++r) { accH[i][r] = 0.f; accL[i][r] = 0.f; }

  short8 ah[16], al[16];
  const int hrow  = t >> 3;
  const int cbase = (t & 7) * 32;
  float4 g4[8];

  auto issueG = [&](int step) {
    int wi = step >> 2, bi = step & 3;
    int w = wg * 8 + wi;
    int b = bg * 4 + bi;
    int n = idxp[((size_t)b * 256 + w) * 32 + hrow];
    const float* src = h3T + ((size_t)b * NPTS + n) * 256 + cbase;
#pragma unroll
    for (int j = 0; j < 8; ++j) g4[j] = *(const float4*)&src[j * 4];
  };
  auto writeG = [&](int buf) {
#pragma unroll
    for (int a = 0; a < 4; ++a) {
      int c8 = (cbase >> 3) + a;
      int ks = c8 >> 1;
      int lp = hrow + (c8 & 1) * 32;
      float4 v0 = g4[a * 2], v1 = g4[a * 2 + 1];
      uint32 u0 = (uint32)f2bf(v0.x) | ((uint32)f2bf(v0.y) << 16);
      uint32 u1 = (uint32)f2bf(v0.z) | ((uint32)f2bf(v0.w) << 16);
      uint32 u2 = (uint32)f2bf(v1.x) | ((uint32)f2bf(v1.y) << 16);
      uint32 u3 = (uint32)f2bf(v1.z) | ((uint32)f2bf(v1.w) << 16);
      *(uint4*)&G[buf][((size_t)ks * 64 + lp) * 8] = make_uint4(u0, u1, u2, u3);
    }
  };

  issueG(0); writeG(0);
  __syncthreads();

  for (int wi = 0; wi < 8; ++wi) {
    const int w = wg * 8 + wi;
    {
      const size_t base = (((size_t)w * 8 + mt) * 16) * 512 + (size_t)l * 8;
#pragma unroll
      for (int ks = 0; ks < 16; ++ks) {
        ah[ks] = *(const short8*)(w8h + base + ks * 512);
        al[ks] = *(const short8*)(w8l + base + ks * 512);
      }
    }
#pragma unroll
    for (int bi = 0; bi < 4; ++bi) {
      const int step = wi * 4 + bi;
      const int cur = bi & 1;
      if (step < 31) issueG(step + 1);
      const u16* Gc = G[cur];
#pragma unroll
      for (int ks = 0; ks < 16; ++ks) {
        short8 bf = *(const short8*)&Gc[((size_t)ks * 64 + l) * 8];
        accH[bi] = __builtin_amdgcn_mfma_f32_32x32x16_bf16(ah[ks], bf, accH[bi], 0, 0, 0);
        accL[bi] = __builtin_amdgcn_mfma_f32_32x32x16_bf16(al[ks], bf, accL[bi], 0, 0, 0);
      }
      if (step < 31) writeG(1 - cur);
      __syncthreads();
    }
  }

  const int h = l & 31;
  const int rbase = oq * 128 + wv * 32 + 4 * (l >> 5);
#pragma unroll
  for (int bi = 0; bi < 4; ++bi) {
    int b = bg * 4 + bi;
    float* dst = y8p + ((size_t)(wg * BATCH + b) * 256) * 32;
#pragma unroll
    for (int r = 0; r < 16; ++r) {
      int o = rbase + (r & 3) + 8 * (r >> 2);
      dst[(size_t)o * 32 + h] = accH[bi][r] + accL[bi][r];
    }
  }
}

// ---------------- y8 = b8 + fixed-order sum of 32 w-group partials
__global__ __launch_bounds__(256) void y8_reduce(const float* __restrict__ y8p,
                                                 const float* __restrict__ b8,
                                                 float* __restrict__ y8) {
  int i = blockIdx.x * 256 + threadIdx.x;
  float s = b8[(i >> 5) & 255];
#pragma unroll
  for (int p = 0; p < 32; ++p) s += y8p[(size_t)p * Y8N + i];
  y8[i] = s;
}

// ---------------- conv9
__global__ __launch_bounds__(256) void conv9_kernel(const float* __restrict__ y8,
                                                    const float* __restrict__ w9,
                                                    const float* __restrict__ b9,
                                                    float* __restrict__ y9) {
  const int o = blockIdx.x, b = blockIdx.y;
  const float* yb = y8 + (size_t)b * 8192;
  const float* wo = w9 + (size_t)o * 8192;
  float s = 0.f;
  for (int i = threadIdx.x * 4; i < 8192; i += 1024) {
    float4 v = *(const float4*)&yb[i];
    float4 u = *(const float4*)&wo[i];
    s += v.x * u.x + v.y * u.y + v.z * u.z + v.w * u.w;
  }
  for (int off = 32; off; off >>= 1) s += __shfl_down(s, off, 64);
  __shared__ float ls[4];
  const int wid = threadIdx.x >> 6;
  if ((threadIdx.x & 63) == 0) ls[wid] = s;
  __syncthreads();
  if (threadIdx.x == 0) y9[(size_t)b * 256 + o] = ls[0] + ls[1] + ls[2] + ls[3] + b9[o];
}

// ---------------- cvec[b,o] = sum_c w4[o,c] * y9[b,c]
__global__ __launch_bounds__(256) void cvec_kernel(const float* __restrict__ y9,
                                                   const float* __restrict__ w4,
                                                   float* __restrict__ cvec) {
  int tid = blockIdx.x * 256 + threadIdx.x;
  if (tid >= BATCH * 512) return;
  const int b = tid >> 9, o = tid & 511;
  const float* row = w4 + (size_t)o * 320;
  const float* yb  = y9 + (size_t)b * 256;
  float s = 0.f;
  for (int c = 0; c < 256; c += 4) {
    float4 u = *(const float4*)&row[c];
    s += u.x * yb[c] + u.y * yb[c + 1] + u.z * yb[c + 2] + u.w * yb[c + 3];
  }
  cvec[(size_t)b * 512 + o] = s;
}

// ---------------- small weight transpose (fp32 conv7 path)
__global__ __launch_bounds__(256) void transpose_w(const float* __restrict__ src,
                                                   float* __restrict__ dst,
                                                   int O, int Ctot, int cOff, int Csub) {
  int i = blockIdx.x * 256 + threadIdx.x;
  if (i >= O * Csub) return;
  int c = i / O, o = i - c * O;
  dst[(size_t)c * O + o] = src[(size_t)o * Ctot + cOff + c];
}

// ---------------- final tanh
__global__ __launch_bounds__(256) void tanh_out(const float* __restrict__ raw,
                                                float* __restrict__ out) {
  int i = blockIdx.x * 256 + threadIdx.x;
  if (i < BATCH * 3 * NPTS) out[i] = tanhf(raw[i]);
}

extern "C" void kernel_launch(void* const* d_in, const int* in_sizes, int n_in,
                              void* d_out, int out_size, void* d_ws, size_t ws_size,
                              hipStream_t stream) {
  (void)in_sizes; (void)n_in; (void)ws_size; (void)out_size;
  const float* x   = (const float*)d_in[0];
  const float* w1  = (const float*)d_in[1];
  const float* g1  = (const float*)d_in[3];
  const float* be1 = (const float*)d_in[4];
  const float* w2  = (const float*)d_in[5];
  const float* g2  = (const float*)d_in[7];
  const float* be2 = (const float*)d_in[8];
  const float* w3  = (const float*)d_in[9];
  const float* g3  = (const float*)d_in[11];
  const float* be3 = (const float*)d_in[12];
  const float* w4  = (const float*)d_in[13];
  const float* g4  = (const float*)d_in[15];
  const float* be4 = (const float*)d_in[16];
  const float* w5  = (const float*)d_in[17];
  const float* g5  = (const float*)d_in[19];
  const float* be5 = (const float*)d_in[20];
  const float* w6  = (const float*)d_in[21];
  const float* g6  = (const float*)d_in[23];
  const float* be6 = (const float*)d_in[24];
  const float* w7  = (const float*)d_in[25];
  const float* b7  = (const float*)d_in[26];
  const float* w8  = (const float*)d_in[27];
  const float* b8  = (const float*)d_in[28];
  const float* w9  = (const float*)d_in[29];
  const float* b9  = (const float*)d_in[30];

  char* ws = (char*)d_ws;
  size_t off = 0;
  auto alloc = [&](size_t bytes) -> void* {
    void* p = ws + off;
    off += (bytes + 255) & ~(size_t)255;
    return p;
  };
  float* Q1  = (float*)alloc((size_t)BATCH * 64  * NPTS * 4);  // h1f (conv1->conv4), then raw7
  float* Q2  = (float*)alloc((size_t)BATCH * 128 * NPTS * 4);  // y8p -> h4 head -> h6
  float* Q3  = (float*)alloc((size_t)BATCH * 256 * NPTS * 4);  // h2d (f64 64MB) -> h3T -> h4 mid
  float* Q4  = (float*)alloc((size_t)BATCH * 256 * NPTS * 4);  // h3f (fp32) -> w8h/w8l -> h4 tail
  float* Q5  = (float*)alloc((size_t)BATCH * 256 * NPTS * 4);  // h2f (fp32) -> h2T (f64) -> h5
  int*   idx  = (int*)alloc((size_t)BATCH * 256 * 32 * 4);
  int*   cand = (int*)alloc((size_t)BATCH * 256 * NCAND * 4);
  float* y8   = (float*)alloc((size_t)Y8N * 4);
  float* y9   = (float*)alloc((size_t)BATCH * 256 * 4);
  float* cvec = (float*)alloc((size_t)BATCH * 512 * 4);
  float* ps   = (float*)alloc((size_t)2 * BATCH * 512 * 32 * 4);   // fp32 BN partials (NT=32)
  double* psd = (double*)alloc((size_t)2 * 256 * 1024 * 8);        // f64 BN partials
  float* scb  = (float*)alloc((size_t)6 * 1024 * 4);
  double* scdb = (double*)alloc((size_t)1024 * 8);                 // f64 BN consts
  float* w7t  = (float*)alloc(128 * 3 * 4);
  u16* ph3 = (u16*)alloc(256 * 128 * 2);  u16* pl3 = (u16*)alloc(256 * 128 * 2);
  u16* ph4 = (u16*)alloc(512 * 64  * 2);  u16* pl4 = (u16*)alloc(512 * 64  * 2);
  u16* ph5 = (u16*)alloc(256 * 512 * 2);  u16* pl5 = (u16*)alloc(256 * 512 * 2);
  u16* ph6 = (u16*)alloc(128 * 256 * 2);  u16* pl6 = (u16*)alloc(128 * 256 * 2);
  double* w2t = (double*)alloc((size_t)64 * 128 * 8);   // (c x o) f64

  double* h2d = (double*)Q3;                  // f64, alive until transpose_h2
  float*  h2f = (float*)Q5;                   // fp32 copy, dies after conv3 MFMA
  double* h2T = (double*)Q5;                  // f64 (b,n,c), overwrites dead h2f
  float*  h3f = Q4;                           // fp32 raw h3, dies after transpose_h3f
  u16*   w8h = (u16*)Q4;                      // after h3f dies
  u16*   w8l = (u16*)Q4 + (size_t)16777216;
  float* y8p = Q2;                            // dead before h4
  float* h4  = Q2;                            // 134 MB spans Q2 + Q3 + Q4 head
  float* h5  = Q5;                            // after h2T dies (rerank done)
  float* h6  = Q2;

  float* sc[6]; float* sh[6];
  for (int i = 0; i < 6; ++i) { sc[i] = scb + i * 1024; sh[i] = scb + i * 1024 + 512; }
  double* scd1 = scdb;        double* shd1 = scdb + 64;
  double* scd2 = scdb + 128;  double* shd2 = scdb + 256;

  // ---- weight preprocessing
  transpose_w<<<(128 * 3 + 255) / 256, 256, 0, stream>>>(w7, w7t, 3, 128, 0, 128);
  pack_wmfma<<<(256 * 128 + 255) / 256, 256, 0, stream>>>(w3, ph3, pl3, 256, 128, 0,   128);
  pack_wmfma<<<(512 * 64  + 255) / 256, 256, 0, stream>>>(w4, ph4, pl4, 512, 320, 256, 64);
  pack_wmfma<<<(256 * 512 + 255) / 256, 256, 0, stream>>>(w5, ph5, pl5, 256, 512, 0,   512);
  pack_wmfma<<<(128 * 256 + 255) / 256, 256, 0, stream>>>(w6, ph6, pl6, 128, 256, 0,   256);
  pack_wtf64<<<(128 * 64 + 255) / 256,  256, 0, stream>>>(w2, w2t, 128, 64);

  // ---- rank chain: conv1,conv2 f64; conv3 fp32 MFMA
  conv1_f64<<<dim3(64, BATCH), 256, 0, stream>>>(x, w1, Q1, psd);
  bn_finalize_f64<<<64, 256, 0, stream>>>(psd, g1, be1, scd1, shd1, sc[0], sh[0], 16);
  conv2_f64v<<<dim3(64, BATCH), 256, 0, stream>>>(x, w1, w2t, scd1, shd1, h2d, h2f, psd);
  bn_finalize_f64<<<128, 256, 0, stream>>>(psd, g2, be2, scd2, shd2, sc[1], sh[1], 1024);
  conv_mfma<<<dim3(32, 2, BATCH), 256, 0, stream>>>(h2f, ph3, pl3, nullptr, sc[1], sh[1], h3f, ps, 128, 256);
  bn_finalize<<<256, 256, 0, stream>>>(ps, g3, be3, sc[2], sh[2], 256, 32);

  // ---- softpool: fp32 top-40 candidates -> f64 rerank -> exact top-32
  topk40_f32<<<dim3(256, BATCH), 256, 0, stream>>>(h3f, cand);
  transpose_h2<<<dim3(NPTS / 32, 4, BATCH), 256, 0, stream>>>(h2d, h2T);
  rerank_f64<<<dim3(256, BATCH), 64, 0, stream>>>(h2T, w3, scd2, shd2, cand, idx);
  transpose_h3f<<<dim3(NPTS / 32, 8, BATCH), 256, 0, stream>>>(h3f, Q3, sc[2], sh[2]);

  // ---- w8 pack AFTER h3f is dead (reuses Q4)
  transpack_w8<<<dim3(1024, 4), 256, 0, stream>>>(w8, w8h, w8l);

  // ---- conv8 -> conv9 -> cvec
  conv8_mfma<<<dim3(32, 2, 4), 256, 0, stream>>>(Q3, w8h, w8l, idx, y8p);
  y8_reduce<<<Y8N / 256, 256, 0, stream>>>(y8p, b8, y8);
  conv9_kernel<<<dim3(256, BATCH), 256, 0, stream>>>(y8, w9, b9, y9);
  cvec_kernel<<<(BATCH * 512 + 255) / 256, 256, 0, stream>>>(y9, w4, cvec);

  // ---- conv4 (MFMA dbuf, rowbias=cvec, input h1 raw + BN1+relu)
  conv_mfma<<<dim3(32, 4, BATCH), 256, 0, stream>>>(Q1, ph4, pl4, cvec, sc[0], sh[0], h4, ps, 64, 512);
  bn_finalize<<<512, 256, 0, stream>>>(ps, g4, be4, sc[3], sh[3], 512, 32);
  // ---- conv5 (MFMA dbuf)
  conv_mfma<<<dim3(32, 2, BATCH), 256, 0, stream>>>(h4, ph5, pl5, nullptr, sc[3], sh[3], h5, ps, 512, 256);
  bn_finalize<<<256, 256, 0, stream>>>(ps, g5, be5, sc[4], sh[4], 256, 32);
  // ---- conv6 (MFMA dbuf)
  conv_mfma<<<dim3(32, 1, BATCH), 256, 0, stream>>>(h5, ph6, pl6, nullptr, sc[4], sh[4], h6, ps, 256, 128);
  bn_finalize<<<128, 256, 0, stream>>>(ps, g6, be6, sc[5], sh[5], 128, 32);
  // ---- conv7 (fp32, +b7, fused BN6+relu) -> tanh
  conv_gemm<<<dim3(64, 1, BATCH), 256, 0, stream>>>(h6, w7t, nullptr, b7, sc[5], sh[5], Q1, nullptr, 128, 3);
  tanh_out<<<(BATCH * 3 * NPTS) / 256, 256, 0, stream>>>(Q1, (float*)d_out);
}

// Round 14
// 781.509 us; speedup vs baseline: 1.0458x; 1.0087x over previous
//
#include <hip/hip_runtime.h>
#include <cstdint>
#include <cstddef>

#define NPTS 4096
#define BATCH 16

typedef unsigned int uint32;
typedef unsigned long long u64;
typedef unsigned short u16;

typedef __attribute__((ext_vector_type(8))) short short8;
typedef __attribute__((ext_vector_type(16))) float float16;

__device__ __forceinline__ u16 f2bf(float f) {
  uint32 u = __float_as_uint(f);
  u = (u + 0x7fffu + ((u >> 16) & 1u)) >> 16;
  return (u16)u;
}
__device__ __forceinline__ float bf2f(u16 h) {
  return __uint_as_float(((uint32)h) << 16);
}

// ---------------- fp32 1x1-conv GEMM — used ONLY for conv7 (value path).
__global__ __launch_bounds__(256) void conv_gemm(
    const float* __restrict__ act, const float* __restrict__ wt,
    const float* __restrict__ rowbias, const float* __restrict__ obias,
    const float* __restrict__ inScale, const float* __restrict__ inShift,
    float* __restrict__ out, float* __restrict__ partials, int C, int O)
{
  __shared__ float As[16][68];
  __shared__ float Ws[16][68];
  __shared__ float redS[64][17];
  __shared__ float redQ[64][17];
  const int b  = blockIdx.z;
  const int o0 = blockIdx.y * 64;
  const int n0 = blockIdx.x * 64;
  const int t  = threadIdx.x;
  const int tx = t & 15, ty = t >> 4;
  float acc[4][4] = {};
  const float* actb = act + ((size_t)b * C) * NPTS;

  for (int k0 = 0; k0 < C; k0 += 16) {
    const int r  = ty;
    const int cs = tx * 4;
    const int k  = k0 + r;
    float4 av = make_float4(0.f, 0.f, 0.f, 0.f);
    if (k < C) {
      av = *(const float4*)(actb + (size_t)k * NPTS + n0 + cs);
      if (inScale) {
        const float scv = inScale[k], shv = inShift[k];
        av.x = fmaxf(fmaf(av.x, scv, shv), 0.f);
        av.y = fmaxf(fmaf(av.y, scv, shv), 0.f);
        av.z = fmaxf(fmaf(av.z, scv, shv), 0.f);
        av.w = fmaxf(fmaf(av.w, scv, shv), 0.f);
      }
    }
    *(float4*)&As[r][cs] = av;

    float4 wv = make_float4(0.f, 0.f, 0.f, 0.f);
    if (k < C) {
      const float* wp = wt + (size_t)k * O;
      const int o = o0 + cs;
      if (o + 3 < O) {
        wv = *(const float4*)&wp[o];
      } else {
        float tmp[4] = {0.f, 0.f, 0.f, 0.f};
        for (int j = 0; j < 4; ++j) if (o + j < O) tmp[j] = wp[o + j];
        wv = make_float4(tmp[0], tmp[1], tmp[2], tmp[3]);
      }
    }
    *(float4*)&Ws[r][cs] = wv;
    __syncthreads();

    const int kmax = (C - k0 < 16) ? (C - k0) : 16;
    for (int kk = 0; kk < kmax; ++kk) {
      float4 a = *(float4*)&As[kk][tx * 4];
      float4 w = *(float4*)&Ws[kk][ty * 4];
      acc[0][0] += w.x * a.x; acc[0][1] += w.x * a.y; acc[0][2] += w.x * a.z; acc[0][3] += w.x * a.w;
      acc[1][0] += w.y * a.x; acc[1][1] += w.y * a.y; acc[1][2] += w.y * a.z; acc[1][3] += w.y * a.w;
      acc[2][0] += w.z * a.x; acc[2][1] += w.z * a.y; acc[2][2] += w.z * a.z; acc[2][3] += w.z * a.w;
      acc[3][0] += w.w * a.x; acc[3][1] += w.w * a.y; acc[3][2] += w.w * a.z; acc[3][3] += w.w * a.w;
    }
    __syncthreads();
  }

  float s[4], q[4];
  for (int i = 0; i < 4; ++i) {
    const int o = o0 + ty * 4 + i;
    s[i] = 0.f; q[i] = 0.f;
    if (o >= O) continue;
    float base = 0.f;
    if (rowbias) base  = rowbias[(size_t)b * O + o];
    if (obias)   base += obias[o];
    float4 v = make_float4(acc[i][0] + base, acc[i][1] + base, acc[i][2] + base, acc[i][3] + base);
    *(float4*)&out[((size_t)b * O + o) * NPTS + n0 + tx * 4] = v;
    s[i] = v.x + v.y + v.z + v.w;
    q[i] = v.x * v.x + v.y * v.y + v.z * v.z + v.w * v.w;
  }

  if (partials) {
    for (int i = 0; i < 4; ++i) { redS[ty * 4 + i][tx] = s[i]; redQ[ty * 4 + i][tx] = q[i]; }
    __syncthreads();
    if (t < 64) {
      float a = 0.f;
      for (int j = 0; j < 16; ++j) a += redS[t][j];
      partials[((size_t)b * O + o0 + t) * 64 + blockIdx.x] = a;
    } else if (t < 128) {
      float a = 0.f;
      for (int j = 0; j < 16; ++j) a += redQ[t - 64][j];
      partials[(size_t)BATCH * O * 64 + ((size_t)b * O + o0 + t - 64) * 64 + blockIdx.x] = a;
    }
  }
}

// ================= rank-exact chain =================
// conv1,conv2 in f64 (VALU). conv3 in fp32 via split-bf16 MFMA (error ~4e-6).
// topk gets ~top-40 fp32 candidates (DPP wave-max tournament on index-embedded
// u32 keys), then a small f64 RERANK recomputes the 40 candidate values exactly
// from f64 h2 and emits the top-32 by masked-f64 key. True top-32 is inside
// the candidate set with large margin, so the final output is exact.

// ---- conv1 (C=4): writes raw h1 fp32 (for conv4 value path) + f64 BN1 partials
__global__ __launch_bounds__(256) void conv1_f64(const float* __restrict__ x,
                                                 const float* __restrict__ w1,
                                                 float* __restrict__ h1f,
                                                 double* __restrict__ psd) {
  const int c = blockIdx.x, b = blockIdx.y;
  const double wa = (double)w1[c * 4 + 0], wb = (double)w1[c * 4 + 1];
  const double wc = (double)w1[c * 4 + 2], wd = (double)w1[c * 4 + 3];
  const float* xb = x + (size_t)b * 4 * NPTS;
  float* dst = h1f + ((size_t)b * 64 + c) * NPTS;
  double s = 0.0, q = 0.0;
  for (int n = threadIdx.x; n < NPTS; n += 256) {
    double v = wa * (double)xb[n] + wb * (double)xb[NPTS + n]
             + wc * (double)xb[2 * NPTS + n] + wd * (double)xb[3 * NPTS + n];
    dst[n] = (float)v;
    s += v; q += v * v;
  }
  __shared__ double ls[4], lq[4];
  for (int off = 32; off; off >>= 1) { s += __shfl_down(s, off, 64); q += __shfl_down(q, off, 64); }
  const int wid = threadIdx.x >> 6;
  if ((threadIdx.x & 63) == 0) { ls[wid] = s; lq[wid] = q; }
  __syncthreads();
  if (threadIdx.x == 0) {
    s = ls[0] + ls[1] + ls[2] + ls[3];
    q = lq[0] + lq[1] + lq[2] + lq[3];
    psd[(size_t)c * 16 + b] = s;
    psd[(size_t)64 * 16 + (size_t)c * 16 + b] = q;
  }
}

// ---- generic f64 BN finalize: fixed-order chunked reduction (deterministic)
__global__ __launch_bounds__(256) void bn_finalize_f64(const double* __restrict__ psd,
                                                       const float* __restrict__ g,
                                                       const float* __restrict__ be,
                                                       double* __restrict__ scd, double* __restrict__ shd,
                                                       float* __restrict__ scf, float* __restrict__ shf,
                                                       int NT) {
  const int c = blockIdx.x;
  const int t = threadIdx.x;
  const double* p2 = psd + (size_t)gridDim.x * NT;
  const int k = (NT + 255) / 256;
  double s = 0.0, q = 0.0;
  for (int i = t * k; i < (t + 1) * k && i < NT; ++i) {
    s += psd[(size_t)c * NT + i];
    q += p2[(size_t)c * NT + i];
  }
  __shared__ double ss[256], qq[256];
  ss[t] = s; qq[t] = q;
  __syncthreads();
  if (t == 0) {
    double S = 0.0, Q = 0.0;
    for (int i = 0; i < 256; ++i) { S += ss[i]; Q += qq[i]; }
    const double m   = S * (1.0 / 65536.0);
    const double var = Q * (1.0 / 65536.0) - m * m;
    const double sc  = (double)g[c] / sqrt(var + 1e-5);
    const double sh  = (double)be[c] - m * sc;
    if (scd) { scd[c] = sc; shd[c] = sh; }
    scf[c] = (float)sc;
    shf[c] = (float)sh;
  }
}

// ---- pack fp32 weights (O x C) -> f64 transposed (C x O) for coalesced staging
__global__ __launch_bounds__(256) void pack_wtf64(const float* __restrict__ src,
                                                  double* __restrict__ dst,
                                                  int O, int C) {
  int i = blockIdx.x * 256 + threadIdx.x;
  if (i >= O * C) return;
  int c = i / O, o = i - c * O;
  dst[(size_t)c * O + o] = (double)src[(size_t)o * C + c];
}

// ---- conv2 VALU f64: 128o x 64n tile; also emits fp32 copy h2f for conv3 MFMA.
__global__ __launch_bounds__(256) void conv2_f64v(
    const float* __restrict__ x, const float* __restrict__ w1,
    const double* __restrict__ w2t,   // (64c x 128o) f64
    const double* __restrict__ scd1, const double* __restrict__ shd1,
    double* __restrict__ h2d, float* __restrict__ h2f, double* __restrict__ psd)
{
  __shared__ double Bs[64][65];     // h1 tile (c1 x n), bn1+relu
  __shared__ double Ws[16][132];    // w2 chunk (k x o)
  const int nb = blockIdx.x, b = blockIdx.y;
  const int n0 = nb * 64;
  const int t = threadIdx.x;
  const float* xb = x + (size_t)b * 4 * NPTS + n0;
  for (int i = t; i < 64 * 64; i += 256) {
    const int c1 = i >> 6, n = i & 63;
    double v = (double)w1[c1 * 4 + 0] * (double)xb[n]
             + (double)w1[c1 * 4 + 1] * (double)xb[NPTS + n]
             + (double)w1[c1 * 4 + 2] * (double)xb[2 * NPTS + n]
             + (double)w1[c1 * 4 + 3] * (double)xb[3 * NPTS + n];
    v = v * scd1[c1] + shd1[c1];
    Bs[c1][n] = v > 0.0 ? v : 0.0;
  }
  const int tx = t & 15, ty = t >> 4;   // n = n0 + tx + 16j ; o = ty*8 .. +7
  double acc[8][4] = {};
  for (int ch = 0; ch < 4; ++ch) {
    __syncthreads();
    {
      const int r = t >> 4, oo = (t & 15) * 8;
      const double* srcw = w2t + (size_t)(ch * 16 + r) * 128 + oo;
#pragma unroll
      for (int j = 0; j < 8; ++j) Ws[r][oo + j] = srcw[j];
    }
    __syncthreads();
#pragma unroll
    for (int kk = 0; kk < 16; ++kk) {
      double a[8], bv[4];
#pragma unroll
      for (int j = 0; j < 8; ++j) a[j] = Ws[kk][ty * 8 + j];
#pragma unroll
      for (int j = 0; j < 4; ++j) bv[j] = Bs[ch * 16 + kk][tx + 16 * j];
#pragma unroll
      for (int i = 0; i < 8; ++i)
#pragma unroll
        for (int j = 0; j < 4; ++j) acc[i][j] = fma(a[i], bv[j], acc[i][j]);
    }
  }
  const size_t hb = (size_t)b * 128 * NPTS;
#pragma unroll
  for (int i = 0; i < 8; ++i) {
    const int o = ty * 8 + i;
    double s = 0.0, q = 0.0;
#pragma unroll
    for (int j = 0; j < 4; ++j) {
      const double v = acc[i][j];
      h2d[hb + (size_t)o * NPTS + n0 + tx + 16 * j] = v;
      h2f[hb + (size_t)o * NPTS + n0 + tx + 16 * j] = (float)v;
      s += v; q += v * v;
    }
#pragma unroll
    for (int m = 1; m < 16; m <<= 1) { s += __shfl_xor(s, m, 64); q += __shfl_xor(q, m, 64); }
    if (tx == 0) {
      psd[(size_t)o * 1024 + b * 64 + nb] = s;
      psd[(size_t)128 * 1024 + (size_t)o * 1024 + b * 64 + nb] = q;
    }
  }
}

// ---------------- pack weights (O,Ctot) fp32 -> hi/lo bf16 A-frag order
__global__ __launch_bounds__(256) void pack_wmfma(const float* __restrict__ src,
                                                  u16* __restrict__ ph, u16* __restrict__ pl,
                                                  int O, int Ctot, int cOff, int Csub) {
  int i = blockIdx.x * 256 + threadIdx.x;
  if (i >= O * Csub) return;
  const int KS = Csub >> 4;
  int j    = i & 7;
  int lj   = (i >> 3) & 63;
  int mtks = i >> 9;
  int ks   = mtks % KS;
  int mt   = mtks / KS;
  int o = mt * 32 + (lj & 31);
  int c = ks * 16 + (lj >> 5) * 8 + j;
  float v = src[(size_t)o * Ctot + cOff + c];
  u16 h = f2bf(v);
  ph[i] = h;
  pl[i] = f2bf(v - bf2f(h));
}

// ---------------- MFMA 1x1-conv GEMM (conv3/4/5/6): split-bf16, dbuf LDS.
// ntout=1: output stores bypass L2 (nontemporal) so reused A-tiles stay cached.
__global__ __launch_bounds__(256) void conv_mfma(
    const float* __restrict__ act, const u16* __restrict__ wh, const u16* __restrict__ wl,
    const float* __restrict__ rowbias,
    const float* __restrict__ inScale, const float* __restrict__ inShift,
    float* __restrict__ out, float* __restrict__ ps, int C, int O, int ntout)
{
  __shared__ u16 Bh[2][4096];
  __shared__ u16 Bl[2][4096];
  const int b  = blockIdx.z;
  const int o0 = blockIdx.y * 128;
  const int n0 = blockIdx.x * 128;
  const int t  = threadIdx.x;
  const int l  = t & 63, wva = t >> 6;
  const int mt = blockIdx.y * 4 + wva;
  const int KS = C >> 4;
  const int NCH = C >> 5;
  const float* actb = act + ((size_t)b * C) * NPTS;

  float16 acc[4];
#pragma unroll
  for (int ns = 0; ns < 4; ++ns)
#pragma unroll
    for (int r = 0; r < 16; ++r) acc[ns][r] = 0.f;

  const int cq = t >> 5;
  const int nq = t & 31;
  const int nn = n0 + nq * 4;
  const int ksl = cq >> 2, oct = (cq >> 1) & 1, j0 = (cq & 1) * 4;

  float va[4][4];
  float4 scv = make_float4(1.f,1.f,1.f,1.f), shv = make_float4(0.f,0.f,0.f,0.f);

  auto loadChunk = [&](int ch) {
    const int cb = ch * 32 + cq * 4;
#pragma unroll
    for (int i2 = 0; i2 < 4; ++i2) {
      float4 v4 = *(const float4*)(actb + (size_t)(cb + i2) * NPTS + nn);
      va[i2][0] = v4.x; va[i2][1] = v4.y; va[i2][2] = v4.z; va[i2][3] = v4.w;
    }
    if (inScale) {
      scv = *(const float4*)&inScale[cb];
      shv = *(const float4*)&inShift[cb];
    }
  };
  auto applyBN = [&]() {
    if (!inScale) return;
#pragma unroll
    for (int d = 0; d < 4; ++d) {
      va[0][d] = fmaxf(fmaf(va[0][d], scv.x, shv.x), 0.f);
      va[1][d] = fmaxf(fmaf(va[1][d], scv.y, shv.y), 0.f);
      va[2][d] = fmaxf(fmaf(va[2][d], scv.z, shv.z), 0.f);
      va[3][d] = fmaxf(fmaf(va[3][d], scv.w, shv.w), 0.f);
    }
  };
  auto convWrite = [&](int buf) {
#pragma unroll
    for (int d = 0; d < 4; ++d) {
      const int nrel = nq * 4 + d;
      const int ns = nrel >> 5, li = nrel & 31;
      u16 h0 = f2bf(va[0][d]), h1 = f2bf(va[1][d]), h2 = f2bf(va[2][d]), h3 = f2bf(va[3][d]);
      u16 q0 = f2bf(va[0][d] - bf2f(h0));
      u16 q1 = f2bf(va[1][d] - bf2f(h1));
      u16 q2 = f2bf(va[2][d] - bf2f(h2));
      u16 q3 = f2bf(va[3][d] - bf2f(h3));
      const int idx = ((ksl * 4 + ns) * 64 + oct * 32 + li) * 8 + j0;
      *(ushort4*)&Bh[buf][idx] = make_ushort4(h0, h1, h2, h3);
      *(ushort4*)&Bl[buf][idx] = make_ushort4(q0, q1, q2, q3);
    }
  };

  loadChunk(0);
  applyBN();
  convWrite(0);
  __syncthreads();

  for (int ch = 0; ch < NCH; ++ch) {
    const size_t abase = (((size_t)mt * KS + ch * 2) * 64 + (size_t)l) * 8;
    short8 AH0 = *(const short8*)(wh + abase);
    short8 AH1 = *(const short8*)(wh + abase + 512);
    short8 AL0 = *(const short8*)(wl + abase);
    short8 AL1 = *(const short8*)(wl + abase + 512);
    const bool more = (ch + 1 < NCH);
    if (more) loadChunk(ch + 1);

    const u16* bh = Bh[ch & 1];
    const u16* bl = Bl[ch & 1];
#pragma unroll
    for (int ns = 0; ns < 4; ++ns) {
      short8 BH0 = *(const short8*)&bh[((0 * 4 + ns) * 64 + l) * 8];
      short8 BL0 = *(const short8*)&bl[((0 * 4 + ns) * 64 + l) * 8];
      acc[ns] = __builtin_amdgcn_mfma_f32_32x32x16_bf16(AL0, BH0, acc[ns], 0, 0, 0);
      acc[ns] = __builtin_amdgcn_mfma_f32_32x32x16_bf16(AH0, BL0, acc[ns], 0, 0, 0);
      acc[ns] = __builtin_amdgcn_mfma_f32_32x32x16_bf16(AH0, BH0, acc[ns], 0, 0, 0);
      short8 BH1 = *(const short8*)&bh[((4 + ns) * 64 + l) * 8];
      short8 BL1 = *(const short8*)&bl[((4 + ns) * 64 + l) * 8];
      acc[ns] = __builtin_amdgcn_mfma_f32_32x32x16_bf16(AL1, BH1, acc[ns], 0, 0, 0);
      acc[ns] = __builtin_amdgcn_mfma_f32_32x32x16_bf16(AH1, BL1, acc[ns], 0, 0, 0);
      acc[ns] = __builtin_amdgcn_mfma_f32_32x32x16_bf16(AH1, BH1, acc[ns], 0, 0, 0);
    }
    if (more) { applyBN(); convWrite((ch + 1) & 1); }
    __syncthreads();
  }

  const int col = l & 31, half = l >> 5;
  float sv[16], sq[16];
#pragma unroll
  for (int r = 0; r < 16; ++r) {
    const int o = o0 + wva * 32 + (r & 3) + 8 * (r >> 2) + 4 * half;
    const float base = rowbias ? rowbias[(size_t)b * O + o] : 0.f;
    float s = 0.f, q = 0.f;
#pragma unroll
    for (int ns = 0; ns < 4; ++ns) {
      float val = acc[ns][r] + base;
      float* dst = &out[((size_t)b * O + o) * NPTS + n0 + ns * 32 + col];
      if (ntout) __builtin_nontemporal_store(val, dst);
      else       *dst = val;
      s += val; q += val * val;
    }
    sv[r] = s; sq[r] = q;
  }
  if (ps) {
#pragma unroll
    for (int r = 0; r < 16; ++r) {
#pragma unroll
      for (int m = 1; m < 32; m <<= 1) {
        sv[r] += __shfl_xor(sv[r], m, 64);
        sq[r] += __shfl_xor(sq[r], m, 64);
      }
    }
    if (col == 0) {
#pragma unroll
      for (int r = 0; r < 16; ++r) {
        const int o = o0 + wva * 32 + (r & 3) + 8 * (r >> 2) + 4 * half;
        ps[((size_t)b * O + o) * 32 + blockIdx.x] = sv[r];
        ps[(size_t)BATCH * O * 32 + ((size_t)b * O + o) * 32 + blockIdx.x] = sq[r];
      }
    }
  }
}

// ---------------- BN finalize (fp32)
__global__ __launch_bounds__(256) void bn_finalize(const float* __restrict__ ps,
                                                   const float* __restrict__ g, const float* __restrict__ be,
                                                   float* __restrict__ scale, float* __restrict__ shift,
                                                   int O, int NT) {
  const int c = blockIdx.x;
  const int total = BATCH * NT;
  const float* p2 = ps + (size_t)BATCH * O * NT;
  const int t = threadIdx.x;
  float s = 0.f, q = 0.f;
  for (int e = t; e < total; e += 256) {
    const int b = e / NT, nt = e - b * NT;
    const size_t a = ((size_t)b * O + c) * NT + nt;
    s += ps[a];
    q += p2[a];
  }
#pragma unroll
  for (int m = 32; m; m >>= 1) {
    s += __shfl_down(s, m, 64);
    q += __shfl_down(q, m, 64);
  }
  __shared__ float lsS[4], lsQ[4];
  const int wid = t >> 6;
  if ((t & 63) == 0) { lsS[wid] = s; lsQ[wid] = q; }
  __syncthreads();
  if (t == 0) {
    s = lsS[0] + lsS[1] + lsS[2] + lsS[3];
    q = lsQ[0] + lsQ[1] + lsQ[2] + lsQ[3];
    const float inv = 1.f / 65536.f;
    float m   = s * inv;
    float var = q * inv - m * m;
    float sc  = g[c] * rsqrtf(var + 1e-5f);
    scale[c] = sc;
    shift[c] = be[c] - m * sc;
  }
}

// ---------------- DPP wave64 max (no LDS/bpermute): result broadcast via readlane
__device__ __forceinline__ int wave_max_i32(int v) {
  v = max(v, __builtin_amdgcn_update_dpp(v, v, 0x111, 0xf, 0xf, false)); // row_shr:1
  v = max(v, __builtin_amdgcn_update_dpp(v, v, 0x112, 0xf, 0xf, false)); // row_shr:2
  v = max(v, __builtin_amdgcn_update_dpp(v, v, 0x114, 0xf, 0xf, false)); // row_shr:4
  v = max(v, __builtin_amdgcn_update_dpp(v, v, 0x118, 0xf, 0xf, false)); // row_shr:8
  v = max(v, __builtin_amdgcn_update_dpp(v, v, 0x142, 0xa, 0xf, false)); // row_bcast:15
  v = max(v, __builtin_amdgcn_update_dpp(v, v, 0x143, 0xc, 0xf, false)); // row_bcast:31
  return __builtin_amdgcn_readlane(v, 63);
}

// ---------------- ~top-40 fp32 candidates per (b,c): per-lane bitonic-sorted
// queue of index-embedded keys + DPP wave-max tournament (zero DS ops in loop).
#define NCAND 40
__global__ __launch_bounds__(256) void topk40_f32(const float* __restrict__ h3,
                                                  int* __restrict__ cand) {
  __shared__ u64 wl[4][NCAND];
  const int c = blockIdx.x, b = blockIdx.y;
  const float* src = h3 + ((size_t)b * 256 + c) * NPTS;
  const int t = threadIdx.x;
  const int l = t & 63, w = t >> 6;
  const int base = w * 1024;

  // load + pack keys (flipped for signed compare: sign-xor makes i32 order == u32 order)
  int k[16];
#pragma unroll
  for (int s = 0; s < 16; ++s) {
    const int loc = s * 64 + l;
    uint32 u = __float_as_uint(src[base + loc]);
    uint32 m32 = ((int)u < 0) ? ~u : (u | 0x80000000u);
    uint32 packed = (m32 & ~0x3FFu) | (uint32)(1023 - loc);
    k[s] = (int)(packed ^ 0x80000000u);
  }

  // bitonic sort ascending: k[15] = lane max
#pragma unroll
  for (int kk = 2; kk <= 16; kk <<= 1) {
#pragma unroll
    for (int j = kk >> 1; j > 0; j >>= 1) {
#pragma unroll
      for (int i = 0; i < 16; ++i) {
        const int ij = i ^ j;
        if (ij > i) {
          const bool up = ((i & kk) == 0);
          const int a = k[i], bb = k[ij];
          const bool sw = up ? (a > bb) : (a < bb);
          k[i]  = sw ? bb : a;
          k[ij] = sw ? a : bb;
        }
      }
    }
  }

  // 40 rounds: DPP wave-max of k[15]; unique winner shifts its queue
  for (int r = 0; r < NCAND; ++r) {
    const int m = wave_max_i32(k[15]);
    if (k[15] == m) {
      const uint32 m32 = (uint32)m ^ 0x80000000u;
      const int loc = 1023 - (int)(m32 & 0x3FFu);
      const int ri = base + loc;
      wl[w][r] = ((u64)m32 << 32) | (u64)(4095 - ri);
#pragma unroll
      for (int s = 15; s > 0; --s) k[s] = k[s - 1];
      k[0] = (int)0x80000000;  // -inf sentinel
    }
  }
  __syncthreads();

  // lanes 0-3 of wave 0: 4-way merge of the sorted per-wave u64 lists
  if (t < 4) {
    int* dst = cand + ((size_t)b * 256 + c) * NCAND;
    int cp = 0;
    u64 cv = wl[t][0];
    for (int r = 0; r < NCAND; ++r) {
      u64 mv = cv;
      u64 ov;
      ov = __shfl_xor((unsigned long long)mv, 1, 64); if (ov > mv) mv = ov;
      ov = __shfl_xor((unsigned long long)mv, 2, 64); if (ov > mv) mv = ov;
      if (t == 0) dst[r] = 4095 - (int)(mv & 0xFFFu);
      if (mv == cv) {
        ++cp;
        cv = (cp < NCAND) ? wl[t][cp] : 0;
      }
    }
  }
}

// ---------------- transpose h2d (b,c2,n) -> h2T (b,n,c2) f64 (for rerank gathers)
__global__ __launch_bounds__(256) void transpose_h2(const double* __restrict__ h2d,
                                                    double* __restrict__ h2T) {
  __shared__ double tile[32][33];
  const int b = blockIdx.z;
  const int n0 = blockIdx.x * 32, c0 = blockIdx.y * 32;
  const int tx = threadIdx.x & 31, ty = threadIdx.x >> 5;
  const double* src = h2d + (size_t)b * 128 * NPTS;
  for (int j = 0; j < 4; ++j)
    tile[ty + j * 8][tx] = src[(size_t)(c0 + ty + j * 8) * NPTS + n0 + tx];
  __syncthreads();
  double* dst = h2T + (size_t)b * NPTS * 128;
  for (int j = 0; j < 4; ++j)
    dst[(size_t)(n0 + ty + j * 8) * 128 + c0 + tx] = tile[tx][ty + j * 8];
}

// ---------------- f64 rerank: exact h3 values for the 40 candidates, emit
// top-32 by masked-f64 key (same semantics as the full-f64 build).
__global__ __launch_bounds__(64) void rerank_f64(const double* __restrict__ h2T,
                                                 const float* __restrict__ w3,
                                                 const double* __restrict__ scd2,
                                                 const double* __restrict__ shd2,
                                                 const int* __restrict__ cand,
                                                 int* __restrict__ idxp) {
  __shared__ u64 keys[NCAND];
  const int o = blockIdx.x, b = blockIdx.y;
  const int l = threadIdx.x;
  const double wA = (double)w3[(size_t)o * 128 + l];
  const double wB = (double)w3[(size_t)o * 128 + l + 64];
  const double sA = scd2[l],      hA = shd2[l];
  const double sB = scd2[l + 64], hB = shd2[l + 64];
  const int* cd = cand + ((size_t)b * 256 + o) * NCAND;
  const double* hb = h2T + (size_t)b * NPTS * 128;
  for (int kk = 0; kk < NCAND; ++kk) {
    const int n = cd[kk];
    const double* col = hb + (size_t)n * 128;
    double va = col[l] * sA + hA;       va = va > 0.0 ? va : 0.0;
    double vb = col[l + 64] * sB + hB;  vb = vb > 0.0 ? vb : 0.0;
    double p = wA * va + wB * vb;
#pragma unroll
    for (int off = 32; off; off >>= 1) p += __shfl_down(p, off, 64);
    if (l == 0) {
      u64 u = (u64)__double_as_longlong(p);
      u64 m = ((long long)u < 0) ? ~u : (u | 0x8000000000000000ULL);
      m = (m & ~0xFFFULL) | (u64)(4095 - n);
      keys[kk] = m;
    }
  }
  __syncthreads();
  u64 kv = (l < NCAND) ? keys[l] : 0;
  int* dst = idxp + ((size_t)b * 256 + o) * 32;
  for (int r = 0; r < 32; ++r) {
    u64 m = kv;
#pragma unroll
    for (int off = 1; off < 64; off <<= 1) {
      u64 o2 = __shfl_xor((unsigned long long)m, off, 64);
      if (o2 > m) m = o2;
    }
    if (l == 0) dst[r] = 4095 - (int)(m & 0xFFFULL);
    if (m == kv) kv = 0;   // keys unique -> winner invalidates itself
  }
}

// ---------------- transpose h3f (B,C,N fp32) -> h3T (B,N,C fp32), applying BN3
__global__ __launch_bounds__(256) void transpose_h3f(const float* __restrict__ h3,
                                                     float* __restrict__ h3T,
                                                     const float* __restrict__ sc,
                                                     const float* __restrict__ sh) {
  __shared__ float tile[32][33];
  const int b = blockIdx.z;
  const int n0 = blockIdx.x * 32, c0 = blockIdx.y * 32;
  const int tx = threadIdx.x & 31, ty = threadIdx.x >> 5;
  const float* src = h3 + (size_t)b * 256 * NPTS;
  for (int j = 0; j < 4; ++j)
    tile[ty + j * 8][tx] = src[(size_t)(c0 + ty + j * 8) * NPTS + n0 + tx];
  __syncthreads();
  float* dst = h3T + (size_t)b * NPTS * 256;
  const float scv = sc[c0 + tx], shv = sh[c0 + tx];
  for (int j = 0; j < 4; ++j)
    dst[(size_t)(n0 + ty + j * 8) * 256 + c0 + tx] = fmaf(tile[tx][ty + j * 8], scv, shv);
}

// ---------------- fused: w8 (o,c,w) -> hi/lo bf16 directly in MFMA A-frag order
__global__ __launch_bounds__(256) void transpack_w8(const float* __restrict__ w8,
                                                    u16* __restrict__ w8h, u16* __restrict__ w8l) {
  __shared__ float tile[64][65];
  const int m0 = blockIdx.x * 64, w0 = blockIdx.y * 64;
  const int tx = threadIdx.x & 63, ty = threadIdx.x >> 6;
#pragma unroll
  for (int j = 0; j < 16; ++j)
    tile[ty + j * 4][tx] = w8[(size_t)(m0 + ty + j * 4) * 256 + w0 + tx];
  __syncthreads();
  const int m = m0 + tx;
  const int o = m >> 8, c = m & 255;
  const int mt = (o >> 5) & 7;
  const int lane = (o & 31) + ((c >> 3) & 1) * 32;
  const int ks = (c >> 4) & 15;
  const int jj = c & 7;
#pragma unroll
  for (int j = 0; j < 16; ++j) {
    const int w = w0 + ty + j * 4;
    float v = tile[tx][ty + j * 4];
    size_t f = ((((size_t)w * 8 + mt) * 16 + ks) * 64 + lane) * 8 + jj;
    u16 h = f2bf(v);
    w8h[f] = h;
    w8l[f] = f2bf(v - bf2f(h));
  }
}

// ---------------- conv8 via MFMA (R10 structure: 32 w-groups of 8, no swizzle)
#define Y8N (BATCH * 256 * 32)
__global__ __launch_bounds__(256, 1) void conv8_mfma(
    const float* __restrict__ h3T, const u16* __restrict__ w8h,
    const u16* __restrict__ w8l, const int* __restrict__ idxp,
    float* __restrict__ y8p)
{
  __shared__ u16 G[2][8192];
  const int wg = blockIdx.x;
  const int oq = blockIdx.y;
  const int bg = blockIdx.z;
  const int t  = threadIdx.x;
  const int l  = t & 63, wv = t >> 6;
  const int mt = oq * 4 + wv;

  float16 accH[4], accL[4];
  for (int i = 0; i < 4; ++i)
    for (int r = 0; r < 16; ++r) { accH[i][r] = 0.f; accL[i][r] = 0.f; }

  short8 ah[16], al[16];
  const int hrow  = t >> 3;
  const int cbase = (t & 7) * 32;
  float4 g4[8];

  auto issueG = [&](int step) {
    int wi = step >> 2, bi = step & 3;
    int w = wg * 8 + wi;
    int b = bg * 4 + bi;
    int n = idxp[((size_t)b * 256 + w) * 32 + hrow];
    const float* src = h3T + ((size_t)b * NPTS + n) * 256 + cbase;
#pragma unroll
    for (int j = 0; j < 8; ++j) g4[j] = *(const float4*)&src[j * 4];
  };
  auto writeG = [&](int buf) {
#pragma unroll
    for (int a = 0; a < 4; ++a) {
      int c8 = (cbase >> 3) + a;
      int ks = c8 >> 1;
      int lp = hrow + (c8 & 1) * 32;
      float4 v0 = g4[a * 2], v1 = g4[a * 2 + 1];
      uint32 u0 = (uint32)f2bf(v0.x) | ((uint32)f2bf(v0.y) << 16);
      uint32 u1 = (uint32)f2bf(v0.z) | ((uint32)f2bf(v0.w) << 16);
      uint32 u2 = (uint32)f2bf(v1.x) | ((uint32)f2bf(v1.y) << 16);
      uint32 u3 = (uint32)f2bf(v1.z) | ((uint32)f2bf(v1.w) << 16);
      *(uint4*)&G[buf][((size_t)ks * 64 + lp) * 8] = make_uint4(u0, u1, u2, u3);
    }
  };

  issueG(0); writeG(0);
  __syncthreads();

  for (int wi = 0; wi < 8; ++wi) {
    const int w = wg * 8 + wi;
    {
      const size_t base = (((size_t)w * 8 + mt) * 16) * 512 + (size_t)l * 8;
#pragma unroll
      for (int ks = 0; ks < 16; ++ks) {
        ah[ks] = *(const short8*)(w8h + base + ks * 512);
        al[ks] = *(const short8*)(w8l + base + ks * 512);
      }
    }
#pragma unroll
    for (int bi = 0; bi < 4; ++bi) {
      const int step = wi * 4 + bi;
      const int cur = bi & 1;
      if (step < 31) issueG(step + 1);
      const u16* Gc = G[cur];
#pragma unroll
      for (int ks = 0; ks < 16; ++ks) {
        short8 bf = *(const short8*)&Gc[((size_t)ks * 64 + l) * 8];
        accH[bi] = __builtin_amdgcn_mfma_f32_32x32x16_bf16(ah[ks], bf, accH[bi], 0, 0, 0);
        accL[bi] = __builtin_amdgcn_mfma_f32_32x32x16_bf16(al[ks], bf, accL[bi], 0, 0, 0);
      }
      if (step < 31) writeG(1 - cur);
      __syncthreads();
    }
  }

  const int h = l & 31;
  const int rbase = oq * 128 + wv * 32 + 4 * (l >> 5);
#pragma unroll
  for (int bi = 0; bi < 4; ++bi) {
    int b = bg * 4 + bi;
    float* dst = y8p + ((size_t)(wg * BATCH + b) * 256) * 32;
#pragma unroll
    for (int r = 0; r < 16; ++r) {
      int o = rbase + (r & 3) + 8 * (r >> 2);
      dst[(size_t)o * 32 + h] = accH[bi][r] + accL[bi][r];
    }
  }
}

// ---------------- y8 = b8 + fixed-order sum of 32 w-group partials
__global__ __launch_bounds__(256) void y8_reduce(const float* __restrict__ y8p,
                                                 const float* __restrict__ b8,
                                                 float* __restrict__ y8) {
  int i = blockIdx.x * 256 + threadIdx.x;
  float s = b8[(i >> 5) & 255];
#pragma unroll
  for (int p = 0; p < 32; ++p) s += y8p[(size_t)p * Y8N + i];
  y8[i] = s;
}

// ---------------- conv9
__global__ __launch_bounds__(256) void conv9_kernel(const float* __restrict__ y8,
                                                    const float* __restrict__ w9,
                                                    const float* __restrict__ b9,
                                                    float* __restrict__ y9) {
  const int o = blockIdx.x, b = blockIdx.y;
  const float* yb = y8 + (size_t)b * 8192;
  const float* wo = w9 + (size_t)o * 8192;
  float s = 0.f;
  for (int i = threadIdx.x * 4; i < 8192; i += 1024) {
    float4 v = *(const float4*)&yb[i];
    float4 u = *(const float4*)&wo[i];
    s += v.x * u.x + v.y * u.y + v.z * u.z + v.w * u.w;
  }
  for (int off = 32; off; off >>= 1) s += __shfl_down(s, off, 64);
  __shared__ float ls[4];
  const int wid = threadIdx.x >> 6;
  if ((threadIdx.x & 63) == 0) ls[wid] = s;
  __syncthreads();
  if (threadIdx.x == 0) y9[(size_t)b * 256 + o] = ls[0] + ls[1] + ls[2] + ls[3] + b9[o];
}

// ---------------- cvec[b,o] = sum_c w4[o,c] * y9[b,c]
__global__ __launch_bounds__(256) void cvec_kernel(const float* __restrict__ y9,
                                                   const float* __restrict__ w4,
                                                   float* __restrict__ cvec) {
  int tid = blockIdx.x * 256 + threadIdx.x;
  if (tid >= BATCH * 512) return;
  const int b = tid >> 9, o = tid & 511;
  const float* row = w4 + (size_t)o * 320;
  const float* yb  = y9 + (size_t)b * 256;
  float s = 0.f;
  for (int c = 0; c < 256; c += 4) {
    float4 u = *(const float4*)&row[c];
    s += u.x * yb[c] + u.y * yb[c + 1] + u.z * yb[c + 2] + u.w * yb[c + 3];
  }
  cvec[(size_t)b * 512 + o] = s;
}

// ---------------- small weight transpose (fp32 conv7 path)
__global__ __launch_bounds__(256) void transpose_w(const float* __restrict__ src,
                                                   float* __restrict__ dst,
                                                   int O, int Ctot, int cOff, int Csub) {
  int i = blockIdx.x * 256 + threadIdx.x;
  if (i >= O * Csub) return;
  int c = i / O, o = i - c * O;
  dst[(size_t)c * O + o] = src[(size_t)o * Ctot + cOff + c];
}

// ---------------- final tanh
__global__ __launch_bounds__(256) void tanh_out(const float* __restrict__ raw,
                                                float* __restrict__ out) {
  int i = blockIdx.x * 256 + threadIdx.x;
  if (i < BATCH * 3 * NPTS) out[i] = tanhf(raw[i]);
}

extern "C" void kernel_launch(void* const* d_in, const int* in_sizes, int n_in,
                              void* d_out, int out_size, void* d_ws, size_t ws_size,
                              hipStream_t stream) {
  (void)in_sizes; (void)n_in; (void)ws_size; (void)out_size;
  const float* x   = (const float*)d_in[0];
  const float* w1  = (const float*)d_in[1];
  const float* g1  = (const float*)d_in[3];
  const float* be1 = (const float*)d_in[4];
  const float* w2  = (const float*)d_in[5];
  const float* g2  = (const float*)d_in[7];
  const float* be2 = (const float*)d_in[8];
  const float* w3  = (const float*)d_in[9];
  const float* g3  = (const float*)d_in[11];
  const float* be3 = (const float*)d_in[12];
  const float* w4  = (const float*)d_in[13];
  const float* g4  = (const float*)d_in[15];
  const float* be4 = (const float*)d_in[16];
  const float* w5  = (const float*)d_in[17];
  const float* g5  = (const float*)d_in[19];
  const float* be5 = (const float*)d_in[20];
  const float* w6  = (const float*)d_in[21];
  const float* g6  = (const float*)d_in[23];
  const float* be6 = (const float*)d_in[24];
  const float* w7  = (const float*)d_in[25];
  const float* b7  = (const float*)d_in[26];
  const float* w8  = (const float*)d_in[27];
  const float* b8  = (const float*)d_in[28];
  const float* w9  = (const float*)d_in[29];
  const float* b9  = (const float*)d_in[30];

  char* ws = (char*)d_ws;
  size_t off = 0;
  auto alloc = [&](size_t bytes) -> void* {
    void* p = ws + off;
    off += (bytes + 255) & ~(size_t)255;
    return p;
  };
  float* Q1  = (float*)alloc((size_t)BATCH * 64  * NPTS * 4);  // h1f (conv1->conv4), then raw7
  float* Q2  = (float*)alloc((size_t)BATCH * 128 * NPTS * 4);  // y8p -> h4 head -> h6
  float* Q3  = (float*)alloc((size_t)BATCH * 256 * NPTS * 4);  // h2d (f64 64MB) -> h3T -> h4 mid
  float* Q4  = (float*)alloc((size_t)BATCH * 256 * NPTS * 4);  // h3f (fp32) -> w8h/w8l -> h4 tail
  float* Q5  = (float*)alloc((size_t)BATCH * 256 * NPTS * 4);  // h2f (fp32) -> h2T (f64) -> h5
  int*   idx  = (int*)alloc((size_t)BATCH * 256 * 32 * 4);
  int*   cand = (int*)alloc((size_t)BATCH * 256 * NCAND * 4);
  float* y8   = (float*)alloc((size_t)Y8N * 4);
  float* y9   = (float*)alloc((size_t)BATCH * 256 * 4);
  float* cvec = (float*)alloc((size_t)BATCH * 512 * 4);
  float* ps   = (float*)alloc((size_t)2 * BATCH * 512 * 32 * 4);   // fp32 BN partials (NT=32)
  double* psd = (double*)alloc((size_t)2 * 256 * 1024 * 8);        // f64 BN partials
  float* scb  = (float*)alloc((size_t)6 * 1024 * 4);
  double* scdb = (double*)alloc((size_t)1024 * 8);                 // f64 BN consts
  float* w7t  = (float*)alloc(128 * 3 * 4);
  u16* ph3 = (u16*)alloc(256 * 128 * 2);  u16* pl3 = (u16*)alloc(256 * 128 * 2);
  u16* ph4 = (u16*)alloc(512 * 64  * 2);  u16* pl4 = (u16*)alloc(512 * 64  * 2);
  u16* ph5 = (u16*)alloc(256 * 512 * 2);  u16* pl5 = (u16*)alloc(256 * 512 * 2);
  u16* ph6 = (u16*)alloc(128 * 256 * 2);  u16* pl6 = (u16*)alloc(128 * 256 * 2);
  double* w2t = (double*)alloc((size_t)64 * 128 * 8);   // (c x o) f64

  double* h2d = (double*)Q3;                  // f64, alive until transpose_h2
  float*  h2f = (float*)Q5;                   // fp32 copy, dies after conv3 MFMA
  double* h2T = (double*)Q5;                  // f64 (b,n,c), overwrites dead h2f
  float*  h3f = Q4;                           // fp32 raw h3, dies after transpose_h3f
  u16*   w8h = (u16*)Q4;                      // after h3f dies
  u16*   w8l = (u16*)Q4 + (size_t)16777216;
  float* y8p = Q2;                            // dead before h4
  float* h4  = Q2;                            // 134 MB spans Q2 + Q3 + Q4 head
  float* h5  = Q5;                            // after h2T dies (rerank done)
  float* h6  = Q2;

  float* sc[6]; float* sh[6];
  for (int i = 0; i < 6; ++i) { sc[i] = scb + i * 1024; sh[i] = scb + i * 1024 + 512; }
  double* scd1 = scdb;        double* shd1 = scdb + 64;
  double* scd2 = scdb + 128;  double* shd2 = scdb + 256;

  // ---- weight preprocessing
  transpose_w<<<(128 * 3 + 255) / 256, 256, 0, stream>>>(w7, w7t, 3, 128, 0, 128);
  pack_wmfma<<<(256 * 128 + 255) / 256, 256, 0, stream>>>(w3, ph3, pl3, 256, 128, 0,   128);
  pack_wmfma<<<(512 * 64  + 255) / 256, 256, 0, stream>>>(w4, ph4, pl4, 512, 320, 256, 64);
  pack_wmfma<<<(256 * 512 + 255) / 256, 256, 0, stream>>>(w5, ph5, pl5, 256, 512, 0,   512);
  pack_wmfma<<<(128 * 256 + 255) / 256, 256, 0, stream>>>(w6, ph6, pl6, 128, 256, 0,   256);
  pack_wtf64<<<(128 * 64 + 255) / 256,  256, 0, stream>>>(w2, w2t, 128, 64);

  // ---- rank chain: conv1,conv2 f64; conv3 fp32 MFMA (nt stores: h3f is streamed)
  conv1_f64<<<dim3(64, BATCH), 256, 0, stream>>>(x, w1, Q1, psd);
  bn_finalize_f64<<<64, 256, 0, stream>>>(psd, g1, be1, scd1, shd1, sc[0], sh[0], 16);
  conv2_f64v<<<dim3(64, BATCH), 256, 0, stream>>>(x, w1, w2t, scd1, shd1, h2d, h2f, psd);
  bn_finalize_f64<<<128, 256, 0, stream>>>(psd, g2, be2, scd2, shd2, sc[1], sh[1], 1024);
  conv_mfma<<<dim3(32, 2, BATCH), 256, 0, stream>>>(h2f, ph3, pl3, nullptr, sc[1], sh[1], h3f, ps, 128, 256, 1);
  bn_finalize<<<256, 256, 0, stream>>>(ps, g3, be3, sc[2], sh[2], 256, 32);

  // ---- softpool: fp32 top-40 candidates -> f64 rerank -> exact top-32
  topk40_f32<<<dim3(256, BATCH), 256, 0, stream>>>(h3f, cand);
  transpose_h2<<<dim3(NPTS / 32, 4, BATCH), 256, 0, stream>>>(h2d, h2T);
  rerank_f64<<<dim3(256, BATCH), 64, 0, stream>>>(h2T, w3, scd2, shd2, cand, idx);
  transpose_h3f<<<dim3(NPTS / 32, 8, BATCH), 256, 0, stream>>>(h3f, Q3, sc[2], sh[2]);

  // ---- w8 pack AFTER h3f is dead (reuses Q4)
  transpack_w8<<<dim3(1024, 4), 256, 0, stream>>>(w8, w8h, w8l);

  // ---- conv8 -> conv9 -> cvec
  conv8_mfma<<<dim3(32, 2, 4), 256, 0, stream>>>(Q3, w8h, w8l, idx, y8p);
  y8_reduce<<<Y8N / 256, 256, 0, stream>>>(y8p, b8, y8);
  conv9_kernel<<<dim3(256, BATCH), 256, 0, stream>>>(y8, w9, b9, y9);
  cvec_kernel<<<(BATCH * 512 + 255) / 256, 256, 0, stream>>>(y9, w4, cvec);

  // ---- conv4 (MFMA dbuf, rowbias=cvec; nt stores: h4 streamed, preserve A in L2)
  conv_mfma<<<dim3(32, 4, BATCH), 256, 0, stream>>>(Q1, ph4, pl4, cvec, sc[0], sh[0], h4, ps, 64, 512, 1);
  bn_finalize<<<512, 256, 0, stream>>>(ps, g4, be4, sc[3], sh[3], 512, 32);
  // ---- conv5 (MFMA dbuf; nt stores)
  conv_mfma<<<dim3(32, 2, BATCH), 256, 0, stream>>>(h4, ph5, pl5, nullptr, sc[3], sh[3], h5, ps, 512, 256, 1);
  bn_finalize<<<256, 256, 0, stream>>>(ps, g5, be5, sc[4], sh[4], 256, 32);
  // ---- conv6 (MFMA dbuf; cached stores — h6 is small enough for conv7 L2 hits)
  conv_mfma<<<dim3(32, 1, BATCH), 256, 0, stream>>>(h5, ph6, pl6, nullptr, sc[4], sh[4], h6, ps, 256, 128, 0);
  bn_finalize<<<128, 256, 0, stream>>>(ps, g6, be6, sc[5], sh[5], 128, 32);
  // ---- conv7 (fp32, +b7, fused BN6+relu) -> tanh
  conv_gemm<<<dim3(64, 1, BATCH), 256, 0, stream>>>(h6, w7t, nullptr, b7, sc[5], sh[5], Q1, nullptr, 128, 3);
  tanh_out<<<(BATCH * 3 * NPTS) / 256, 256, 0, stream>>>(Q1, (float*)d_out);
}

// Round 15
// 767.510 us; speedup vs baseline: 1.0649x; 1.0182x over previous
//
#include <hip/hip_runtime.h>
#include <cstdint>
#include <cstddef>

#define NPTS 4096
#define BATCH 16

typedef unsigned int uint32;
typedef unsigned long long u64;
typedef unsigned short u16;

typedef __attribute__((ext_vector_type(8))) short short8;
typedef __attribute__((ext_vector_type(16))) float float16;

__device__ __forceinline__ u16 f2bf(float f) {
  uint32 u = __float_as_uint(f);
  u = (u + 0x7fffu + ((u >> 16) & 1u)) >> 16;
  return (u16)u;
}
__device__ __forceinline__ float bf2f(u16 h) {
  return __uint_as_float(((uint32)h) << 16);
}

// ---------------- fp32 1x1-conv GEMM — used ONLY for conv7 (value path).
__global__ __launch_bounds__(256) void conv_gemm(
    const float* __restrict__ act, const float* __restrict__ wt,
    const float* __restrict__ rowbias, const float* __restrict__ obias,
    const float* __restrict__ inScale, const float* __restrict__ inShift,
    float* __restrict__ out, float* __restrict__ partials, int C, int O)
{
  __shared__ float As[16][68];
  __shared__ float Ws[16][68];
  __shared__ float redS[64][17];
  __shared__ float redQ[64][17];
  const int b  = blockIdx.z;
  const int o0 = blockIdx.y * 64;
  const int n0 = blockIdx.x * 64;
  const int t  = threadIdx.x;
  const int tx = t & 15, ty = t >> 4;
  float acc[4][4] = {};
  const float* actb = act + ((size_t)b * C) * NPTS;

  for (int k0 = 0; k0 < C; k0 += 16) {
    const int r  = ty;
    const int cs = tx * 4;
    const int k  = k0 + r;
    float4 av = make_float4(0.f, 0.f, 0.f, 0.f);
    if (k < C) {
      av = *(const float4*)(actb + (size_t)k * NPTS + n0 + cs);
      if (inScale) {
        const float scv = inScale[k], shv = inShift[k];
        av.x = fmaxf(fmaf(av.x, scv, shv), 0.f);
        av.y = fmaxf(fmaf(av.y, scv, shv), 0.f);
        av.z = fmaxf(fmaf(av.z, scv, shv), 0.f);
        av.w = fmaxf(fmaf(av.w, scv, shv), 0.f);
      }
    }
    *(float4*)&As[r][cs] = av;

    float4 wv = make_float4(0.f, 0.f, 0.f, 0.f);
    if (k < C) {
      const float* wp = wt + (size_t)k * O;
      const int o = o0 + cs;
      if (o + 3 < O) {
        wv = *(const float4*)&wp[o];
      } else {
        float tmp[4] = {0.f, 0.f, 0.f, 0.f};
        for (int j = 0; j < 4; ++j) if (o + j < O) tmp[j] = wp[o + j];
        wv = make_float4(tmp[0], tmp[1], tmp[2], tmp[3]);
      }
    }
    *(float4*)&Ws[r][cs] = wv;
    __syncthreads();

    const int kmax = (C - k0 < 16) ? (C - k0) : 16;
    for (int kk = 0; kk < kmax; ++kk) {
      float4 a = *(float4*)&As[kk][tx * 4];
      float4 w = *(float4*)&Ws[kk][ty * 4];
      acc[0][0] += w.x * a.x; acc[0][1] += w.x * a.y; acc[0][2] += w.x * a.z; acc[0][3] += w.x * a.w;
      acc[1][0] += w.y * a.x; acc[1][1] += w.y * a.y; acc[1][2] += w.y * a.z; acc[1][3] += w.y * a.w;
      acc[2][0] += w.z * a.x; acc[2][1] += w.z * a.y; acc[2][2] += w.z * a.z; acc[2][3] += w.z * a.w;
      acc[3][0] += w.w * a.x; acc[3][1] += w.w * a.y; acc[3][2] += w.w * a.z; acc[3][3] += w.w * a.w;
    }
    __syncthreads();
  }

  float s[4], q[4];
  for (int i = 0; i < 4; ++i) {
    const int o = o0 + ty * 4 + i;
    s[i] = 0.f; q[i] = 0.f;
    if (o >= O) continue;
    float base = 0.f;
    if (rowbias) base  = rowbias[(size_t)b * O + o];
    if (obias)   base += obias[o];
    float4 v = make_float4(acc[i][0] + base, acc[i][1] + base, acc[i][2] + base, acc[i][3] + base);
    *(float4*)&out[((size_t)b * O + o) * NPTS + n0 + tx * 4] = v;
    s[i] = v.x + v.y + v.z + v.w;
    q[i] = v.x * v.x + v.y * v.y + v.z * v.z + v.w * v.w;
  }

  if (partials) {
    for (int i = 0; i < 4; ++i) { redS[ty * 4 + i][tx] = s[i]; redQ[ty * 4 + i][tx] = q[i]; }
    __syncthreads();
    if (t < 64) {
      float a = 0.f;
      for (int j = 0; j < 16; ++j) a += redS[t][j];
      partials[((size_t)b * O + o0 + t) * 64 + blockIdx.x] = a;
    } else if (t < 128) {
      float a = 0.f;
      for (int j = 0; j < 16; ++j) a += redQ[t - 64][j];
      partials[(size_t)BATCH * O * 64 + ((size_t)b * O + o0 + t - 64) * 64 + blockIdx.x] = a;
    }
  }
}

// ================= rank-exact chain =================
// conv1,conv2 in f64 (VALU). conv3 in fp32 via split-bf16 MFMA (error ~4e-6).
// topk gets ~top-40 fp32 candidates (DPP wave-max tournament), then a small f64
// RERANK recomputes the 40 candidate values exactly and emits the top-32.

// ---- conv1 (C=4): writes raw h1 fp32 (for conv4 value path) + f64 BN1 partials
__global__ __launch_bounds__(256) void conv1_f64(const float* __restrict__ x,
                                                 const float* __restrict__ w1,
                                                 float* __restrict__ h1f,
                                                 double* __restrict__ psd) {
  const int c = blockIdx.x, b = blockIdx.y;
  const double wa = (double)w1[c * 4 + 0], wb = (double)w1[c * 4 + 1];
  const double wc = (double)w1[c * 4 + 2], wd = (double)w1[c * 4 + 3];
  const float* xb = x + (size_t)b * 4 * NPTS;
  float* dst = h1f + ((size_t)b * 64 + c) * NPTS;
  double s = 0.0, q = 0.0;
  for (int n = threadIdx.x; n < NPTS; n += 256) {
    double v = wa * (double)xb[n] + wb * (double)xb[NPTS + n]
             + wc * (double)xb[2 * NPTS + n] + wd * (double)xb[3 * NPTS + n];
    dst[n] = (float)v;
    s += v; q += v * v;
  }
  __shared__ double ls[4], lq[4];
  for (int off = 32; off; off >>= 1) { s += __shfl_down(s, off, 64); q += __shfl_down(q, off, 64); }
  const int wid = threadIdx.x >> 6;
  if ((threadIdx.x & 63) == 0) { ls[wid] = s; lq[wid] = q; }
  __syncthreads();
  if (threadIdx.x == 0) {
    s = ls[0] + ls[1] + ls[2] + ls[3];
    q = lq[0] + lq[1] + lq[2] + lq[3];
    psd[(size_t)c * 16 + b] = s;
    psd[(size_t)64 * 16 + (size_t)c * 16 + b] = q;
  }
}

// ---- generic f64 BN finalize: fixed-order chunked reduction (deterministic)
__global__ __launch_bounds__(256) void bn_finalize_f64(const double* __restrict__ psd,
                                                       const float* __restrict__ g,
                                                       const float* __restrict__ be,
                                                       double* __restrict__ scd, double* __restrict__ shd,
                                                       float* __restrict__ scf, float* __restrict__ shf,
                                                       int NT) {
  const int c = blockIdx.x;
  const int t = threadIdx.x;
  const double* p2 = psd + (size_t)gridDim.x * NT;
  const int k = (NT + 255) / 256;
  double s = 0.0, q = 0.0;
  for (int i = t * k; i < (t + 1) * k && i < NT; ++i) {
    s += psd[(size_t)c * NT + i];
    q += p2[(size_t)c * NT + i];
  }
  __shared__ double ss[256], qq[256];
  ss[t] = s; qq[t] = q;
  __syncthreads();
  if (t == 0) {
    double S = 0.0, Q = 0.0;
    for (int i = 0; i < 256; ++i) { S += ss[i]; Q += qq[i]; }
    const double m   = S * (1.0 / 65536.0);
    const double var = Q * (1.0 / 65536.0) - m * m;
    const double sc  = (double)g[c] / sqrt(var + 1e-5);
    const double sh  = (double)be[c] - m * sc;
    if (scd) { scd[c] = sc; shd[c] = sh; }
    scf[c] = (float)sc;
    shf[c] = (float)sh;
  }
}

// ---- pack fp32 weights (O x C) -> f64 transposed (C x O) for coalesced staging
__global__ __launch_bounds__(256) void pack_wtf64(const float* __restrict__ src,
                                                  double* __restrict__ dst,
                                                  int O, int C) {
  int i = blockIdx.x * 256 + threadIdx.x;
  if (i >= O * C) return;
  int c = i / O, o = i - c * O;
  dst[(size_t)c * O + o] = (double)src[(size_t)o * C + c];
}

// ---- conv2 VALU f64: 128o x 64n tile; also emits fp32 copy h2f for conv3 MFMA.
__global__ __launch_bounds__(256) void conv2_f64v(
    const float* __restrict__ x, const float* __restrict__ w1,
    const double* __restrict__ w2t,   // (64c x 128o) f64
    const double* __restrict__ scd1, const double* __restrict__ shd1,
    double* __restrict__ h2d, float* __restrict__ h2f, double* __restrict__ psd)
{
  __shared__ double Bs[64][65];     // h1 tile (c1 x n), bn1+relu
  __shared__ double Ws[16][132];    // w2 chunk (k x o)
  const int nb = blockIdx.x, b = blockIdx.y;
  const int n0 = nb * 64;
  const int t = threadIdx.x;
  const float* xb = x + (size_t)b * 4 * NPTS + n0;
  for (int i = t; i < 64 * 64; i += 256) {
    const int c1 = i >> 6, n = i & 63;
    double v = (double)w1[c1 * 4 + 0] * (double)xb[n]
             + (double)w1[c1 * 4 + 1] * (double)xb[NPTS + n]
             + (double)w1[c1 * 4 + 2] * (double)xb[2 * NPTS + n]
             + (double)w1[c1 * 4 + 3] * (double)xb[3 * NPTS + n];
    v = v * scd1[c1] + shd1[c1];
    Bs[c1][n] = v > 0.0 ? v : 0.0;
  }
  const int tx = t & 15, ty = t >> 4;   // n = n0 + tx + 16j ; o = ty*8 .. +7
  double acc[8][4] = {};
  for (int ch = 0; ch < 4; ++ch) {
    __syncthreads();
    {
      const int r = t >> 4, oo = (t & 15) * 8;
      const double* srcw = w2t + (size_t)(ch * 16 + r) * 128 + oo;
#pragma unroll
      for (int j = 0; j < 8; ++j) Ws[r][oo + j] = srcw[j];
    }
    __syncthreads();
#pragma unroll
    for (int kk = 0; kk < 16; ++kk) {
      double a[8], bv[4];
#pragma unroll
      for (int j = 0; j < 8; ++j) a[j] = Ws[kk][ty * 8 + j];
#pragma unroll
      for (int j = 0; j < 4; ++j) bv[j] = Bs[ch * 16 + kk][tx + 16 * j];
#pragma unroll
      for (int i = 0; i < 8; ++i)
#pragma unroll
        for (int j = 0; j < 4; ++j) acc[i][j] = fma(a[i], bv[j], acc[i][j]);
    }
  }
  const size_t hb = (size_t)b * 128 * NPTS;
#pragma unroll
  for (int i = 0; i < 8; ++i) {
    const int o = ty * 8 + i;
    double s = 0.0, q = 0.0;
#pragma unroll
    for (int j = 0; j < 4; ++j) {
      const double v = acc[i][j];
      h2d[hb + (size_t)o * NPTS + n0 + tx + 16 * j] = v;
      h2f[hb + (size_t)o * NPTS + n0 + tx + 16 * j] = (float)v;
      s += v; q += v * v;
    }
#pragma unroll
    for (int m = 1; m < 16; m <<= 1) { s += __shfl_xor(s, m, 64); q += __shfl_xor(q, m, 64); }
    if (tx == 0) {
      psd[(size_t)o * 1024 + b * 64 + nb] = s;
      psd[(size_t)128 * 1024 + (size_t)o * 1024 + b * 64 + nb] = q;
    }
  }
}

// ---------------- pack weights (O,Ctot) fp32 -> hi/lo bf16 A-frag order
__global__ __launch_bounds__(256) void pack_wmfma(const float* __restrict__ src,
                                                  u16* __restrict__ ph, u16* __restrict__ pl,
                                                  int O, int Ctot, int cOff, int Csub) {
  int i = blockIdx.x * 256 + threadIdx.x;
  if (i >= O * Csub) return;
  const int KS = Csub >> 4;
  int j    = i & 7;
  int lj   = (i >> 3) & 63;
  int mtks = i >> 9;
  int ks   = mtks % KS;
  int mt   = mtks / KS;
  int o = mt * 32 + (lj & 31);
  int c = ks * 16 + (lj >> 5) * 8 + j;
  float v = src[(size_t)o * Ctot + cOff + c];
  u16 h = f2bf(v);
  ph[i] = h;
  pl[i] = f2bf(v - bf2f(h));
}

// ---------------- MFMA 1x1-conv GEMM (conv3/5/6): split-bf16, dbuf LDS.
// ntout=1: output stores bypass L2 (nontemporal).
__global__ __launch_bounds__(256) void conv_mfma(
    const float* __restrict__ act, const u16* __restrict__ wh, const u16* __restrict__ wl,
    const float* __restrict__ rowbias,
    const float* __restrict__ inScale, const float* __restrict__ inShift,
    float* __restrict__ out, float* __restrict__ ps, int C, int O, int ntout)
{
  __shared__ u16 Bh[2][4096];
  __shared__ u16 Bl[2][4096];
  const int b  = blockIdx.z;
  const int o0 = blockIdx.y * 128;
  const int n0 = blockIdx.x * 128;
  const int t  = threadIdx.x;
  const int l  = t & 63, wva = t >> 6;
  const int mt = blockIdx.y * 4 + wva;
  const int KS = C >> 4;
  const int NCH = C >> 5;
  const float* actb = act + ((size_t)b * C) * NPTS;

  float16 acc[4];
#pragma unroll
  for (int ns = 0; ns < 4; ++ns)
#pragma unroll
    for (int r = 0; r < 16; ++r) acc[ns][r] = 0.f;

  const int cq = t >> 5;
  const int nq = t & 31;
  const int nn = n0 + nq * 4;
  const int ksl = cq >> 2, oct = (cq >> 1) & 1, j0 = (cq & 1) * 4;

  float va[4][4];
  float4 scv = make_float4(1.f,1.f,1.f,1.f), shv = make_float4(0.f,0.f,0.f,0.f);

  auto loadChunk = [&](int ch) {
    const int cb = ch * 32 + cq * 4;
#pragma unroll
    for (int i2 = 0; i2 < 4; ++i2) {
      float4 v4 = *(const float4*)(actb + (size_t)(cb + i2) * NPTS + nn);
      va[i2][0] = v4.x; va[i2][1] = v4.y; va[i2][2] = v4.z; va[i2][3] = v4.w;
    }
    if (inScale) {
      scv = *(const float4*)&inScale[cb];
      shv = *(const float4*)&inShift[cb];
    }
  };
  auto applyBN = [&]() {
    if (!inScale) return;
#pragma unroll
    for (int d = 0; d < 4; ++d) {
      va[0][d] = fmaxf(fmaf(va[0][d], scv.x, shv.x), 0.f);
      va[1][d] = fmaxf(fmaf(va[1][d], scv.y, shv.y), 0.f);
      va[2][d] = fmaxf(fmaf(va[2][d], scv.z, shv.z), 0.f);
      va[3][d] = fmaxf(fmaf(va[3][d], scv.w, shv.w), 0.f);
    }
  };
  auto convWrite = [&](int buf) {
#pragma unroll
    for (int d = 0; d < 4; ++d) {
      const int nrel = nq * 4 + d;
      const int ns = nrel >> 5, li = nrel & 31;
      u16 h0 = f2bf(va[0][d]), h1 = f2bf(va[1][d]), h2 = f2bf(va[2][d]), h3 = f2bf(va[3][d]);
      u16 q0 = f2bf(va[0][d] - bf2f(h0));
      u16 q1 = f2bf(va[1][d] - bf2f(h1));
      u16 q2 = f2bf(va[2][d] - bf2f(h2));
      u16 q3 = f2bf(va[3][d] - bf2f(h3));
      const int idx = ((ksl * 4 + ns) * 64 + oct * 32 + li) * 8 + j0;
      *(ushort4*)&Bh[buf][idx] = make_ushort4(h0, h1, h2, h3);
      *(ushort4*)&Bl[buf][idx] = make_ushort4(q0, q1, q2, q3);
    }
  };

  loadChunk(0);
  applyBN();
  convWrite(0);
  __syncthreads();

  for (int ch = 0; ch < NCH; ++ch) {
    const size_t abase = (((size_t)mt * KS + ch * 2) * 64 + (size_t)l) * 8;
    short8 AH0 = *(const short8*)(wh + abase);
    short8 AH1 = *(const short8*)(wh + abase + 512);
    short8 AL0 = *(const short8*)(wl + abase);
    short8 AL1 = *(const short8*)(wl + abase + 512);
    const bool more = (ch + 1 < NCH);
    if (more) loadChunk(ch + 1);

    const u16* bh = Bh[ch & 1];
    const u16* bl = Bl[ch & 1];
#pragma unroll
    for (int ns = 0; ns < 4; ++ns) {
      short8 BH0 = *(const short8*)&bh[((0 * 4 + ns) * 64 + l) * 8];
      short8 BL0 = *(const short8*)&bl[((0 * 4 + ns) * 64 + l) * 8];
      acc[ns] = __builtin_amdgcn_mfma_f32_32x32x16_bf16(AL0, BH0, acc[ns], 0, 0, 0);
      acc[ns] = __builtin_amdgcn_mfma_f32_32x32x16_bf16(AH0, BL0, acc[ns], 0, 0, 0);
      acc[ns] = __builtin_amdgcn_mfma_f32_32x32x16_bf16(AH0, BH0, acc[ns], 0, 0, 0);
      short8 BH1 = *(const short8*)&bh[((4 + ns) * 64 + l) * 8];
      short8 BL1 = *(const short8*)&bl[((4 + ns) * 64 + l) * 8];
      acc[ns] = __builtin_amdgcn_mfma_f32_32x32x16_bf16(AL1, BH1, acc[ns], 0, 0, 0);
      acc[ns] = __builtin_amdgcn_mfma_f32_32x32x16_bf16(AH1, BL1, acc[ns], 0, 0, 0);
      acc[ns] = __builtin_amdgcn_mfma_f32_32x32x16_bf16(AH1, BH1, acc[ns], 0, 0, 0);
    }
    if (more) { applyBN(); convWrite((ch + 1) & 1); }
    __syncthreads();
  }

  const int col = l & 31, half = l >> 5;
  float sv[16], sq[16];
#pragma unroll
  for (int r = 0; r < 16; ++r) {
    const int o = o0 + wva * 32 + (r & 3) + 8 * (r >> 2) + 4 * half;
    const float base = rowbias ? rowbias[(size_t)b * O + o] : 0.f;
    float s = 0.f, q = 0.f;
#pragma unroll
    for (int ns = 0; ns < 4; ++ns) {
      float val = acc[ns][r] + base;
      float* dst = &out[((size_t)b * O + o) * NPTS + n0 + ns * 32 + col];
      if (ntout) __builtin_nontemporal_store(val, dst);
      else       *dst = val;
      s += val; q += val * val;
    }
    sv[r] = s; sq[r] = q;
  }
  if (ps) {
#pragma unroll
    for (int r = 0; r < 16; ++r) {
#pragma unroll
      for (int m = 1; m < 32; m <<= 1) {
        sv[r] += __shfl_xor(sv[r], m, 64);
        sq[r] += __shfl_xor(sq[r], m, 64);
      }
    }
    if (col == 0) {
#pragma unroll
      for (int r = 0; r < 16; ++r) {
        const int o = o0 + wva * 32 + (r & 3) + 8 * (r >> 2) + 4 * half;
        ps[((size_t)b * O + o) * 32 + blockIdx.x] = sv[r];
        ps[(size_t)BATCH * O * 32 + ((size_t)b * O + o) * 32 + blockIdx.x] = sq[r];
      }
    }
  }
}

// ---------------- conv4 specialized MFMA: C=64, O=512. Full B-tile (32KB LDS)
// staged ONCE per block; all 4 o-tiles computed in-block -> A fetched exactly
// once from HBM regardless of XCD dispatch policy. Per-accumulator MFMA order
// (k-slices 0..3, AL*BH / AH*BL / AH*BH per slice) identical to conv_mfma ->
// h4 bits unchanged. nt stores (h4 streamed).
__global__ __launch_bounds__(256) void conv4_mfma(
    const float* __restrict__ act, const u16* __restrict__ wh, const u16* __restrict__ wl,
    const float* __restrict__ rowbias,
    const float* __restrict__ inScale, const float* __restrict__ inShift,
    float* __restrict__ out, float* __restrict__ ps)
{
  __shared__ u16 Bh[8192];
  __shared__ u16 Bl[8192];
  const int b  = blockIdx.z;
  const int n0 = blockIdx.x * 128;
  const int t  = threadIdx.x;
  const int l  = t & 63, wva = t >> 6;
  const float* actb = act + ((size_t)b * 64) * NPTS;

  const int cq = t >> 5;
  const int nq = t & 31;
  const int nn = n0 + nq * 4;
  const int ksl = cq >> 2, oct = (cq >> 1) & 1, j0 = (cq & 1) * 4;

  // stage full B (C=64): same per-element BN1+relu+split math as conv_mfma
  for (int ch = 0; ch < 2; ++ch) {
    const int cb = ch * 32 + cq * 4;
    float va[4][4];
#pragma unroll
    for (int i2 = 0; i2 < 4; ++i2) {
      float4 v4 = *(const float4*)(actb + (size_t)(cb + i2) * NPTS + nn);
      va[i2][0] = v4.x; va[i2][1] = v4.y; va[i2][2] = v4.z; va[i2][3] = v4.w;
    }
    const float4 scv = *(const float4*)&inScale[cb];
    const float4 shv = *(const float4*)&inShift[cb];
#pragma unroll
    for (int d = 0; d < 4; ++d) {
      va[0][d] = fmaxf(fmaf(va[0][d], scv.x, shv.x), 0.f);
      va[1][d] = fmaxf(fmaf(va[1][d], scv.y, shv.y), 0.f);
      va[2][d] = fmaxf(fmaf(va[2][d], scv.z, shv.z), 0.f);
      va[3][d] = fmaxf(fmaf(va[3][d], scv.w, shv.w), 0.f);
    }
#pragma unroll
    for (int d = 0; d < 4; ++d) {
      const int nrel = nq * 4 + d;
      const int ns = nrel >> 5, li = nrel & 31;
      u16 h0 = f2bf(va[0][d]), h1 = f2bf(va[1][d]), h2 = f2bf(va[2][d]), h3 = f2bf(va[3][d]);
      u16 q0 = f2bf(va[0][d] - bf2f(h0));
      u16 q1 = f2bf(va[1][d] - bf2f(h1));
      u16 q2 = f2bf(va[2][d] - bf2f(h2));
      u16 q3 = f2bf(va[3][d] - bf2f(h3));
      const int idx = (((ch * 2 + ksl) * 4 + ns) * 64 + oct * 32 + li) * 8 + j0;
      *(ushort4*)&Bh[idx] = make_ushort4(h0, h1, h2, h3);
      *(ushort4*)&Bl[idx] = make_ushort4(q0, q1, q2, q3);
    }
  }
  __syncthreads();

  const int col = l & 31, half = l >> 5;
  for (int ot = 0; ot < 4; ++ot) {
    const int mt = ot * 4 + wva;
    float16 acc[4];
#pragma unroll
    for (int ns = 0; ns < 4; ++ns)
#pragma unroll
      for (int r = 0; r < 16; ++r) acc[ns][r] = 0.f;

#pragma unroll
    for (int ks2 = 0; ks2 < 4; ++ks2) {
      const size_t abase = (((size_t)mt * 4 + ks2) * 64 + (size_t)l) * 8;
      short8 AH = *(const short8*)(wh + abase);
      short8 AL = *(const short8*)(wl + abase);
#pragma unroll
      for (int ns = 0; ns < 4; ++ns) {
        short8 BH = *(const short8*)&Bh[((ks2 * 4 + ns) * 64 + l) * 8];
        short8 BL = *(const short8*)&Bl[((ks2 * 4 + ns) * 64 + l) * 8];
        acc[ns] = __builtin_amdgcn_mfma_f32_32x32x16_bf16(AL, BH, acc[ns], 0, 0, 0);
        acc[ns] = __builtin_amdgcn_mfma_f32_32x32x16_bf16(AH, BL, acc[ns], 0, 0, 0);
        acc[ns] = __builtin_amdgcn_mfma_f32_32x32x16_bf16(AH, BH, acc[ns], 0, 0, 0);
      }
    }

    const int o0t = ot * 128;
    float sv[16], sq[16];
#pragma unroll
    for (int r = 0; r < 16; ++r) {
      const int o = o0t + wva * 32 + (r & 3) + 8 * (r >> 2) + 4 * half;
      const float base = rowbias[(size_t)b * 512 + o];
      float s = 0.f, q = 0.f;
#pragma unroll
      for (int ns = 0; ns < 4; ++ns) {
        float val = acc[ns][r] + base;
        __builtin_nontemporal_store(val, &out[((size_t)b * 512 + o) * NPTS + n0 + ns * 32 + col]);
        s += val; q += val * val;
      }
      sv[r] = s; sq[r] = q;
    }
#pragma unroll
    for (int r = 0; r < 16; ++r) {
#pragma unroll
      for (int m = 1; m < 32; m <<= 1) {
        sv[r] += __shfl_xor(sv[r], m, 64);
        sq[r] += __shfl_xor(sq[r], m, 64);
      }
    }
    if (col == 0) {
#pragma unroll
      for (int r = 0; r < 16; ++r) {
        const int o = o0t + wva * 32 + (r & 3) + 8 * (r >> 2) + 4 * half;
        ps[((size_t)b * 512 + o) * 32 + blockIdx.x] = sv[r];
        ps[(size_t)BATCH * 512 * 32 + ((size_t)b * 512 + o) * 32 + blockIdx.x] = sq[r];
      }
    }
  }
}

// ---------------- BN finalize (fp32)
__global__ __launch_bounds__(256) void bn_finalize(const float* __restrict__ ps,
                                                   const float* __restrict__ g, const float* __restrict__ be,
                                                   float* __restrict__ scale, float* __restrict__ shift,
                                                   int O, int NT) {
  const int c = blockIdx.x;
  const int total = BATCH * NT;
  const float* p2 = ps + (size_t)BATCH * O * NT;
  const int t = threadIdx.x;
  float s = 0.f, q = 0.f;
  for (int e = t; e < total; e += 256) {
    const int b = e / NT, nt = e - b * NT;
    const size_t a = ((size_t)b * O + c) * NT + nt;
    s += ps[a];
    q += p2[a];
  }
#pragma unroll
  for (int m = 32; m; m >>= 1) {
    s += __shfl_down(s, m, 64);
    q += __shfl_down(q, m, 64);
  }
  __shared__ float lsS[4], lsQ[4];
  const int wid = t >> 6;
  if ((t & 63) == 0) { lsS[wid] = s; lsQ[wid] = q; }
  __syncthreads();
  if (t == 0) {
    s = lsS[0] + lsS[1] + lsS[2] + lsS[3];
    q = lsQ[0] + lsQ[1] + lsQ[2] + lsQ[3];
    const float inv = 1.f / 65536.f;
    float m   = s * inv;
    float var = q * inv - m * m;
    float sc  = g[c] * rsqrtf(var + 1e-5f);
    scale[c] = sc;
    shift[c] = be[c] - m * sc;
  }
}

// ---------------- DPP wave64 max (no LDS/bpermute): result broadcast via readlane
__device__ __forceinline__ int wave_max_i32(int v) {
  v = max(v, __builtin_amdgcn_update_dpp(v, v, 0x111, 0xf, 0xf, false)); // row_shr:1
  v = max(v, __builtin_amdgcn_update_dpp(v, v, 0x112, 0xf, 0xf, false)); // row_shr:2
  v = max(v, __builtin_amdgcn_update_dpp(v, v, 0x114, 0xf, 0xf, false)); // row_shr:4
  v = max(v, __builtin_amdgcn_update_dpp(v, v, 0x118, 0xf, 0xf, false)); // row_shr:8
  v = max(v, __builtin_amdgcn_update_dpp(v, v, 0x142, 0xa, 0xf, false)); // row_bcast:15
  v = max(v, __builtin_amdgcn_update_dpp(v, v, 0x143, 0xc, 0xf, false)); // row_bcast:31
  return __builtin_amdgcn_readlane(v, 63);
}

// ---------------- ~top-40 fp32 candidates per (b,c): per-lane bitonic-sorted
// queue of index-embedded keys + DPP wave-max tournament (zero DS ops in loop).
#define NCAND 40
__global__ __launch_bounds__(256) void topk40_f32(const float* __restrict__ h3,
                                                  int* __restrict__ cand) {
  __shared__ u64 wl[4][NCAND];
  const int c = blockIdx.x, b = blockIdx.y;
  const float* src = h3 + ((size_t)b * 256 + c) * NPTS;
  const int t = threadIdx.x;
  const int l = t & 63, w = t >> 6;
  const int base = w * 1024;

  // load + pack keys (flipped for signed compare: sign-xor makes i32 order == u32 order)
  int k[16];
#pragma unroll
  for (int s = 0; s < 16; ++s) {
    const int loc = s * 64 + l;
    uint32 u = __float_as_uint(src[base + loc]);
    uint32 m32 = ((int)u < 0) ? ~u : (u | 0x80000000u);
    uint32 packed = (m32 & ~0x3FFu) | (uint32)(1023 - loc);
    k[s] = (int)(packed ^ 0x80000000u);
  }

  // bitonic sort ascending: k[15] = lane max
#pragma unroll
  for (int kk = 2; kk <= 16; kk <<= 1) {
#pragma unroll
    for (int j = kk >> 1; j > 0; j >>= 1) {
#pragma unroll
      for (int i = 0; i < 16; ++i) {
        const int ij = i ^ j;
        if (ij > i) {
          const bool up = ((i & kk) == 0);
          const int a = k[i], bb = k[ij];
          const bool sw = up ? (a > bb) : (a < bb);
          k[i]  = sw ? bb : a;
          k[ij] = sw ? a : bb;
        }
      }
    }
  }

  // 40 rounds: DPP wave-max of k[15]; unique winner shifts its queue
  for (int r = 0; r < NCAND; ++r) {
    const int m = wave_max_i32(k[15]);
    if (k[15] == m) {
      const uint32 m32 = (uint32)m ^ 0x80000000u;
      const int loc = 1023 - (int)(m32 & 0x3FFu);
      const int ri = base + loc;
      wl[w][r] = ((u64)m32 << 32) | (u64)(4095 - ri);
#pragma unroll
      for (int s = 15; s > 0; --s) k[s] = k[s - 1];
      k[0] = (int)0x80000000;  // -inf sentinel
    }
  }
  __syncthreads();

  // lanes 0-3 of wave 0: 4-way merge of the sorted per-wave u64 lists
  if (t < 4) {
    int* dst = cand + ((size_t)b * 256 + c) * NCAND;
    int cp = 0;
    u64 cv = wl[t][0];
    for (int r = 0; r < NCAND; ++r) {
      u64 mv = cv;
      u64 ov;
      ov = __shfl_xor((unsigned long long)mv, 1, 64); if (ov > mv) mv = ov;
      ov = __shfl_xor((unsigned long long)mv, 2, 64); if (ov > mv) mv = ov;
      if (t == 0) dst[r] = 4095 - (int)(mv & 0xFFFu);
      if (mv == cv) {
        ++cp;
        cv = (cp < NCAND) ? wl[t][cp] : 0;
      }
    }
  }
}

// ---------------- transpose h2d (b,c2,n) -> h2T (b,n,c2) f64 (for rerank gathers)
__global__ __launch_bounds__(256) void transpose_h2(const double* __restrict__ h2d,
                                                    double* __restrict__ h2T) {
  __shared__ double tile[32][33];
  const int b = blockIdx.z;
  const int n0 = blockIdx.x * 32, c0 = blockIdx.y * 32;
  const int tx = threadIdx.x & 31, ty = threadIdx.x >> 5;
  const double* src = h2d + (size_t)b * 128 * NPTS;
  for (int j = 0; j < 4; ++j)
    tile[ty + j * 8][tx] = src[(size_t)(c0 + ty + j * 8) * NPTS + n0 + tx];
  __syncthreads();
  double* dst = h2T + (size_t)b * NPTS * 128;
  for (int j = 0; j < 4; ++j)
    dst[(size_t)(n0 + ty + j * 8) * 128 + c0 + tx] = tile[tx][ty + j * 8];
}

// ---------------- f64 rerank: exact h3 values for the 40 candidates, emit
// top-32 by masked-f64 key (same semantics as the full-f64 build).
__global__ __launch_bounds__(64) void rerank_f64(const double* __restrict__ h2T,
                                                 const float* __restrict__ w3,
                                                 const double* __restrict__ scd2,
                                                 const double* __restrict__ shd2,
                                                 const int* __restrict__ cand,
                                                 int* __restrict__ idxp) {
  __shared__ u64 keys[NCAND];
  const int o = blockIdx.x, b = blockIdx.y;
  const int l = threadIdx.x;
  const double wA = (double)w3[(size_t)o * 128 + l];
  const double wB = (double)w3[(size_t)o * 128 + l + 64];
  const double sA = scd2[l],      hA = shd2[l];
  const double sB = scd2[l + 64], hB = shd2[l + 64];
  const int* cd = cand + ((size_t)b * 256 + o) * NCAND;
  const double* hb = h2T + (size_t)b * NPTS * 128;
  for (int kk = 0; kk < NCAND; ++kk) {
    const int n = cd[kk];
    const double* col = hb + (size_t)n * 128;
    double va = col[l] * sA + hA;       va = va > 0.0 ? va : 0.0;
    double vb = col[l + 64] * sB + hB;  vb = vb > 0.0 ? vb : 0.0;
    double p = wA * va + wB * vb;
#pragma unroll
    for (int off = 32; off; off >>= 1) p += __shfl_down(p, off, 64);
    if (l == 0) {
      u64 u = (u64)__double_as_longlong(p);
      u64 m = ((long long)u < 0) ? ~u : (u | 0x8000000000000000ULL);
      m = (m & ~0xFFFULL) | (u64)(4095 - n);
      keys[kk] = m;
    }
  }
  __syncthreads();
  u64 kv = (l < NCAND) ? keys[l] : 0;
  int* dst = idxp + ((size_t)b * 256 + o) * 32;
  for (int r = 0; r < 32; ++r) {
    u64 m = kv;
#pragma unroll
    for (int off = 1; off < 64; off <<= 1) {
      u64 o2 = __shfl_xor((unsigned long long)m, off, 64);
      if (o2 > m) m = o2;
    }
    if (l == 0) dst[r] = 4095 - (int)(m & 0xFFFULL);
    if (m == kv) kv = 0;   // keys unique -> winner invalidates itself
  }
}

// ---------------- transpose h3f (B,C,N fp32) -> h3T (B,N,C fp32), applying BN3
__global__ __launch_bounds__(256) void transpose_h3f(const float* __restrict__ h3,
                                                     float* __restrict__ h3T,
                                                     const float* __restrict__ sc,
                                                     const float* __restrict__ sh) {
  __shared__ float tile[32][33];
  const int b = blockIdx.z;
  const int n0 = blockIdx.x * 32, c0 = blockIdx.y * 32;
  const int tx = threadIdx.x & 31, ty = threadIdx.x >> 5;
  const float* src = h3 + (size_t)b * 256 * NPTS;
  for (int j = 0; j < 4; ++j)
    tile[ty + j * 8][tx] = src[(size_t)(c0 + ty + j * 8) * NPTS + n0 + tx];
  __syncthreads();
  float* dst = h3T + (size_t)b * NPTS * 256;
  const float scv = sc[c0 + tx], shv = sh[c0 + tx];
  for (int j = 0; j < 4; ++j)
    dst[(size_t)(n0 + ty + j * 8) * 256 + c0 + tx] = fmaf(tile[tx][ty + j * 8], scv, shv);
}

// ---------------- fused: w8 (o,c,w) -> hi/lo bf16 directly in MFMA A-frag order
__global__ __launch_bounds__(256) void transpack_w8(const float* __restrict__ w8,
                                                    u16* __restrict__ w8h, u16* __restrict__ w8l) {
  __shared__ float tile[64][65];
  const int m0 = blockIdx.x * 64, w0 = blockIdx.y * 64;
  const int tx = threadIdx.x & 63, ty = threadIdx.x >> 6;
#pragma unroll
  for (int j = 0; j < 16; ++j)
    tile[ty + j * 4][tx] = w8[(size_t)(m0 + ty + j * 4) * 256 + w0 + tx];
  __syncthreads();
  const int m = m0 + tx;
  const int o = m >> 8, c = m & 255;
  const int mt = (o >> 5) & 7;
  const int lane = (o & 31) + ((c >> 3) & 1) * 32;
  const int ks = (c >> 4) & 15;
  const int jj = c & 7;
#pragma unroll
  for (int j = 0; j < 16; ++j) {
    const int w = w0 + ty + j * 4;
    float v = tile[tx][ty + j * 4];
    size_t f = ((((size_t)w * 8 + mt) * 16 + ks) * 64 + lane) * 8 + jj;
    u16 h = f2bf(v);
    w8h[f] = h;
    w8l[f] = f2bf(v - bf2f(h));
  }
}

// ---------------- conv8 via MFMA (R10 structure: 32 w-groups of 8, no swizzle)
#define Y8N (BATCH * 256 * 32)
__global__ __launch_bounds__(256, 1) void conv8_mfma(
    const float* __restrict__ h3T, const u16* __restrict__ w8h,
    const u16* __restrict__ w8l, const int* __restrict__ idxp,
    float* __restrict__ y8p)
{
  __shared__ u16 G[2][8192];
  const int wg = blockIdx.x;
  const int oq = blockIdx.y;
  const int bg = blockIdx.z;
  const int t  = threadIdx.x;
  const int l  = t & 63, wv = t >> 6;
  const int mt = oq * 4 + wv;

  float16 accH[4], accL[4];
  for (int i = 0; i < 4; ++i)
    for (int r = 0; r < 16; ++r) { accH[i][r] = 0.f; accL[i][r] = 0.f; }

  short8 ah[16], al[16];
  const int hrow  = t >> 3;
  const int cbase = (t & 7) * 32;
  float4 g4[8];

  auto issueG = [&](int step) {
    int wi = step >> 2, bi = step & 3;
    int w = wg * 8 + wi;
    int b = bg * 4 + bi;
    int n = idxp[((size_t)b * 256 + w) * 32 + hrow];
    const float* src = h3T + ((size_t)b * NPTS + n) * 256 + cbase;
#pragma unroll
    for (int j = 0; j < 8; ++j) g4[j] = *(const float4*)&src[j * 4];
  };
  auto writeG = [&](int buf) {
#pragma unroll
    for (int a = 0; a < 4; ++a) {
      int c8 = (cbase >> 3) + a;
      int ks = c8 >> 1;
      int lp = hrow + (c8 & 1) * 32;
      float4 v0 = g4[a * 2], v1 = g4[a * 2 + 1];
      uint32 u0 = (uint32)f2bf(v0.x) | ((uint32)f2bf(v0.y) << 16);
      uint32 u1 = (uint32)f2bf(v0.z) | ((uint32)f2bf(v0.w) << 16);
      uint32 u2 = (uint32)f2bf(v1.x) | ((uint32)f2bf(v1.y) << 16);
      uint32 u3 = (uint32)f2bf(v1.z) | ((uint32)f2bf(v1.w) << 16);
      *(uint4*)&G[buf][((size_t)ks * 64 + lp) * 8] = make_uint4(u0, u1, u2, u3);
    }
  };

  issueG(0); writeG(0);
  __syncthreads();

  for (int wi = 0; wi < 8; ++wi) {
    const int w = wg * 8 + wi;
    {
      const size_t base = (((size_t)w * 8 + mt) * 16) * 512 + (size_t)l * 8;
#pragma unroll
      for (int ks = 0; ks < 16; ++ks) {
        ah[ks] = *(const short8*)(w8h + base + ks * 512);
        al[ks] = *(const short8*)(w8l + base + ks * 512);
      }
    }
#pragma unroll
    for (int bi = 0; bi < 4; ++bi) {
      const int step = wi * 4 + bi;
      const int cur = bi & 1;
      if (step < 31) issueG(step + 1);
      const u16* Gc = G[cur];
#pragma unroll
      for (int ks = 0; ks < 16; ++ks) {
        short8 bf = *(const short8*)&Gc[((size_t)ks * 64 + l) * 8];
        accH[bi] = __builtin_amdgcn_mfma_f32_32x32x16_bf16(ah[ks], bf, accH[bi], 0, 0, 0);
        accL[bi] = __builtin_amdgcn_mfma_f32_32x32x16_bf16(al[ks], bf, accL[bi], 0, 0, 0);
      }
      if (step < 31) writeG(1 - cur);
      __syncthreads();
    }
  }

  const int h = l & 31;
  const int rbase = oq * 128 + wv * 32 + 4 * (l >> 5);
#pragma unroll
  for (int bi = 0; bi < 4; ++bi) {
    int b = bg * 4 + bi;
    float* dst = y8p + ((size_t)(wg * BATCH + b) * 256) * 32;
#pragma unroll
    for (int r = 0; r < 16; ++r) {
      int o = rbase + (r & 3) + 8 * (r >> 2);
      dst[(size_t)o * 32 + h] = accH[bi][r] + accL[bi][r];
    }
  }
}

// ---------------- y8 = b8 + fixed-order sum of 32 w-group partials
__global__ __launch_bounds__(256) void y8_reduce(const float* __restrict__ y8p,
                                                 const float* __restrict__ b8,
                                                 float* __restrict__ y8) {
  int i = blockIdx.x * 256 + threadIdx.x;
  float s = b8[(i >> 5) & 255];
#pragma unroll
  for (int p = 0; p < 32; ++p) s += y8p[(size_t)p * Y8N + i];
  y8[i] = s;
}

// ---------------- conv9
__global__ __launch_bounds__(256) void conv9_kernel(const float* __restrict__ y8,
                                                    const float* __restrict__ w9,
                                                    const float* __restrict__ b9,
                                                    float* __restrict__ y9) {
  const int o = blockIdx.x, b = blockIdx.y;
  const float* yb = y8 + (size_t)b * 8192;
  const float* wo = w9 + (size_t)o * 8192;
  float s = 0.f;
  for (int i = threadIdx.x * 4; i < 8192; i += 1024) {
    float4 v = *(const float4*)&yb[i];
    float4 u = *(const float4*)&wo[i];
    s += v.x * u.x + v.y * u.y + v.z * u.z + v.w * u.w;
  }
  for (int off = 32; off; off >>= 1) s += __shfl_down(s, off, 64);
  __shared__ float ls[4];
  const int wid = threadIdx.x >> 6;
  if ((threadIdx.x & 63) == 0) ls[wid] = s;
  __syncthreads();
  if (threadIdx.x == 0) y9[(size_t)b * 256 + o] = ls[0] + ls[1] + ls[2] + ls[3] + b9[o];
}

// ---------------- cvec[b,o] = sum_c w4[o,c] * y9[b,c]
__global__ __launch_bounds__(256) void cvec_kernel(const float* __restrict__ y9,
                                                   const float* __restrict__ w4,
                                                   float* __restrict__ cvec) {
  int tid = blockIdx.x * 256 + threadIdx.x;
  if (tid >= BATCH * 512) return;
  const int b = tid >> 9, o = tid & 511;
  const float* row = w4 + (size_t)o * 320;
  const float* yb  = y9 + (size_t)b * 256;
  float s = 0.f;
  for (int c = 0; c < 256; c += 4) {
    float4 u = *(const float4*)&row[c];
    s += u.x * yb[c] + u.y * yb[c + 1] + u.z * yb[c + 2] + u.w * yb[c + 3];
  }
  cvec[(size_t)b * 512 + o] = s;
}

// ---------------- small weight transpose (fp32 conv7 path)
__global__ __launch_bounds__(256) void transpose_w(const float* __restrict__ src,
                                                   float* __restrict__ dst,
                                                   int O, int Ctot, int cOff, int Csub) {
  int i = blockIdx.x * 256 + threadIdx.x;
  if (i >= O * Csub) return;
  int c = i / O, o = i - c * O;
  dst[(size_t)c * O + o] = src[(size_t)o * Ctot + cOff + c];
}

// ---------------- final tanh
__global__ __launch_bounds__(256) void tanh_out(const float* __restrict__ raw,
                                                float* __restrict__ out) {
  int i = blockIdx.x * 256 + threadIdx.x;
  if (i < BATCH * 3 * NPTS) out[i] = tanhf(raw[i]);
}

extern "C" void kernel_launch(void* const* d_in, const int* in_sizes, int n_in,
                              void* d_out, int out_size, void* d_ws, size_t ws_size,
                              hipStream_t stream) {
  (void)in_sizes; (void)n_in; (void)ws_size; (void)out_size;
  const float* x   = (const float*)d_in[0];
  const float* w1  = (const float*)d_in[1];
  const float* g1  = (const float*)d_in[3];
  const float* be1 = (const float*)d_in[4];
  const float* w2  = (const float*)d_in[5];
  const float* g2  = (const float*)d_in[7];
  const float* be2 = (const float*)d_in[8];
  const float* w3  = (const float*)d_in[9];
  const float* g3  = (const float*)d_in[11];
  const float* be3 = (const float*)d_in[12];
  const float* w4  = (const float*)d_in[13];
  const float* g4  = (const float*)d_in[15];
  const float* be4 = (const float*)d_in[16];
  const float* w5  = (const float*)d_in[17];
  const float* g5  = (const float*)d_in[19];
  const float* be5 = (const float*)d_in[20];
  const float* w6  = (const float*)d_in[21];
  const float* g6  = (const float*)d_in[23];
  const float* be6 = (const float*)d_in[24];
  const float* w7  = (const float*)d_in[25];
  const float* b7  = (const float*)d_in[26];
  const float* w8  = (const float*)d_in[27];
  const float* b8  = (const float*)d_in[28];
  const float* w9  = (const float*)d_in[29];
  const float* b9  = (const float*)d_in[30];

  char* ws = (char*)d_ws;
  size_t off = 0;
  auto alloc = [&](size_t bytes) -> void* {
    void* p = ws + off;
    off += (bytes + 255) & ~(size_t)255;
    return p;
  };
  float* Q1  = (float*)alloc((size_t)BATCH * 64  * NPTS * 4);  // h1f (conv1->conv4), then raw7
  float* Q2  = (float*)alloc((size_t)BATCH * 128 * NPTS * 4);  // y8p -> h4 head -> h6
  float* Q3  = (float*)alloc((size_t)BATCH * 256 * NPTS * 4);  // h2d (f64 64MB) -> h3T -> h4 mid
  float* Q4  = (float*)alloc((size_t)BATCH * 256 * NPTS * 4);  // h3f (fp32) -> w8h/w8l -> h4 tail
  float* Q5  = (float*)alloc((size_t)BATCH * 256 * NPTS * 4);  // h2f (fp32) -> h2T (f64) -> h5
  int*   idx  = (int*)alloc((size_t)BATCH * 256 * 32 * 4);
  int*   cand = (int*)alloc((size_t)BATCH * 256 * NCAND * 4);
  float* y8   = (float*)alloc((size_t)Y8N * 4);
  float* y9   = (float*)alloc((size_t)BATCH * 256 * 4);
  float* cvec = (float*)alloc((size_t)BATCH * 512 * 4);
  float* ps   = (float*)alloc((size_t)2 * BATCH * 512 * 32 * 4);   // fp32 BN partials (NT=32)
  double* psd = (double*)alloc((size_t)2 * 256 * 1024 * 8);        // f64 BN partials
  float* scb  = (float*)alloc((size_t)6 * 1024 * 4);
  double* scdb = (double*)alloc((size_t)1024 * 8);                 // f64 BN consts
  float* w7t  = (float*)alloc(128 * 3 * 4);
  u16* ph3 = (u16*)alloc(256 * 128 * 2);  u16* pl3 = (u16*)alloc(256 * 128 * 2);
  u16* ph4 = (u16*)alloc(512 * 64  * 2);  u16* pl4 = (u16*)alloc(512 * 64  * 2);
  u16* ph5 = (u16*)alloc(256 * 512 * 2);  u16* pl5 = (u16*)alloc(256 * 512 * 2);
  u16* ph6 = (u16*)alloc(128 * 256 * 2);  u16* pl6 = (u16*)alloc(128 * 256 * 2);
  double* w2t = (double*)alloc((size_t)64 * 128 * 8);   // (c x o) f64

  double* h2d = (double*)Q3;                  // f64, alive until transpose_h2
  float*  h2f = (float*)Q5;                   // fp32 copy, dies after conv3 MFMA
  double* h2T = (double*)Q5;                  // f64 (b,n,c), overwrites dead h2f
  float*  h3f = Q4;                           // fp32 raw h3, dies after transpose_h3f
  u16*   w8h = (u16*)Q4;                      // after h3f dies
  u16*   w8l = (u16*)Q4 + (size_t)16777216;
  float* y8p = Q2;                            // dead before h4
  float* h4  = Q2;                            // 134 MB spans Q2 + Q3 + Q4 head
  float* h5  = Q5;                            // after h2T dies (rerank done)
  float* h6  = Q2;

  float* sc[6]; float* sh[6];
  for (int i = 0; i < 6; ++i) { sc[i] = scb + i * 1024; sh[i] = scb + i * 1024 + 512; }
  double* scd1 = scdb;        double* shd1 = scdb + 64;
  double* scd2 = scdb + 128;  double* shd2 = scdb + 256;

  // ---- weight preprocessing
  transpose_w<<<(128 * 3 + 255) / 256, 256, 0, stream>>>(w7, w7t, 3, 128, 0, 128);
  pack_wmfma<<<(256 * 128 + 255) / 256, 256, 0, stream>>>(w3, ph3, pl3, 256, 128, 0,   128);
  pack_wmfma<<<(512 * 64  + 255) / 256, 256, 0, stream>>>(w4, ph4, pl4, 512, 320, 256, 64);
  pack_wmfma<<<(256 * 512 + 255) / 256, 256, 0, stream>>>(w5, ph5, pl5, 256, 512, 0,   512);
  pack_wmfma<<<(128 * 256 + 255) / 256, 256, 0, stream>>>(w6, ph6, pl6, 128, 256, 0,   256);
  pack_wtf64<<<(128 * 64 + 255) / 256,  256, 0, stream>>>(w2, w2t, 128, 64);

  // ---- rank chain: conv1,conv2 f64; conv3 fp32 MFMA (nt stores: h3f is streamed)
  conv1_f64<<<dim3(64, BATCH), 256, 0, stream>>>(x, w1, Q1, psd);
  bn_finalize_f64<<<64, 256, 0, stream>>>(psd, g1, be1, scd1, shd1, sc[0], sh[0], 16);
  conv2_f64v<<<dim3(64, BATCH), 256, 0, stream>>>(x, w1, w2t, scd1, shd1, h2d, h2f, psd);
  bn_finalize_f64<<<128, 256, 0, stream>>>(psd, g2, be2, scd2, shd2, sc[1], sh[1], 1024);
  conv_mfma<<<dim3(32, 2, BATCH), 256, 0, stream>>>(h2f, ph3, pl3, nullptr, sc[1], sh[1], h3f, ps, 128, 256, 1);
  bn_finalize<<<256, 256, 0, stream>>>(ps, g3, be3, sc[2], sh[2], 256, 32);

  // ---- softpool: fp32 top-40 candidates -> f64 rerank -> exact top-32
  topk40_f32<<<dim3(256, BATCH), 256, 0, stream>>>(h3f, cand);
  transpose_h2<<<dim3(NPTS / 32, 4, BATCH), 256, 0, stream>>>(h2d, h2T);
  rerank_f64<<<dim3(256, BATCH), 64, 0, stream>>>(h2T, w3, scd2, shd2, cand, idx);
  transpose_h3f<<<dim3(NPTS / 32, 8, BATCH), 256, 0, stream>>>(h3f, Q3, sc[2], sh[2]);

  // ---- w8 pack AFTER h3f is dead (reuses Q4)
  transpack_w8<<<dim3(1024, 4), 256, 0, stream>>>(w8, w8h, w8l);

  // ---- conv8 -> conv9 -> cvec
  conv8_mfma<<<dim3(32, 2, 4), 256, 0, stream>>>(Q3, w8h, w8l, idx, y8p);
  y8_reduce<<<Y8N / 256, 256, 0, stream>>>(y8p, b8, y8);
  conv9_kernel<<<dim3(256, BATCH), 256, 0, stream>>>(y8, w9, b9, y9);
  cvec_kernel<<<(BATCH * 512 + 255) / 256, 256, 0, stream>>>(y9, w4, cvec);

  // ---- conv4 (specialized: full-B LDS, 4 o-tiles per block -> A fetched once)
  conv4_mfma<<<dim3(32, 1, BATCH), 256, 0, stream>>>(Q1, ph4, pl4, cvec, sc[0], sh[0], h4, ps);
  bn_finalize<<<512, 256, 0, stream>>>(ps, g4, be4, sc[3], sh[3], 512, 32);
  // ---- conv5 (MFMA dbuf; nt stores)
  conv_mfma<<<dim3(32, 2, BATCH), 256, 0, stream>>>(h4, ph5, pl5, nullptr, sc[3], sh[3], h5, ps, 512, 256, 1);
  bn_finalize<<<256, 256, 0, stream>>>(ps, g5, be5, sc[4], sh[4], 256, 32);
  // ---- conv6 (MFMA dbuf; cached stores — h6 is small enough for conv7 L2 hits)
  conv_mfma<<<dim3(32, 1, BATCH), 256, 0, stream>>>(h5, ph6, pl6, nullptr, sc[4], sh[4], h6, ps, 256, 128, 0);
  bn_finalize<<<128, 256, 0, stream>>>(ps, g6, be6, sc[5], sh[5], 128, 32);
  // ---- conv7 (fp32, +b7, fused BN6+relu) -> tanh
  conv_gemm<<<dim3(64, 1, BATCH), 256, 0, stream>>>(h6, w7t, nullptr, b7, sc[5], sh[5], Q1, nullptr, 128, 3);
  tanh_out<<<(BATCH * 3 * NPTS) / 256, 256, 0, stream>>>(Q1, (float*)d_out);
}